// Round 1
// baseline (797.878 us; speedup 1.0000x reference)
//
#include <hip/hip_runtime.h>

// ---------------------------------------------------------------------------
// GCN 4-layer forward on MI355X.
// Pipeline per call:
//   1. memset degree counters
//   2. degree histogram (src + dst) via int atomics
//   3. norms: out_norm = rsqrt(max(deg_src,1)), in_norm = rsqrt(max(deg_dst,1))
//   4. single-block exclusive scan of dst-degrees -> row_ptr, cursor
//   5. CSR bucket fill: eidx[] = src ids grouped by dst
//   6. per layer: fp32 matmul (out_norm folded into epilogue)
//                 -> wave-per-node CSR gather-sum (+in_norm, +bias, relu fused)
// ---------------------------------------------------------------------------

__global__ void k_degrees(const int* __restrict__ src, const int* __restrict__ dst,
                          int ne, int* __restrict__ degs, int* __restrict__ degd) {
    int i = blockIdx.x * blockDim.x + threadIdx.x;
    if (i < ne) {
        atomicAdd(&degs[src[i]], 1);
        atomicAdd(&degd[dst[i]], 1);
    }
}

__global__ void k_norms(const int* __restrict__ degs, const int* __restrict__ degd,
                        float* __restrict__ onrm, float* __restrict__ inrm, int n) {
    int i = blockIdx.x * blockDim.x + threadIdx.x;
    if (i < n) {
        onrm[i] = rsqrtf((float)max(degs[i], 1));
        inrm[i] = rsqrtf((float)max(degd[i], 1));
    }
}

// Single-block exclusive scan (wave shuffle scan, 1024 threads = 16 waves).
__global__ __launch_bounds__(1024) void k_scan(const int* __restrict__ deg, int n,
                                               int* __restrict__ row_ptr,
                                               int* __restrict__ cursor) {
    __shared__ int wsum[16];
    __shared__ int carry;
    int tid = threadIdx.x;
    int lane = tid & 63;
    int wid = tid >> 6;
    if (tid == 0) carry = 0;
    __syncthreads();
    for (int base = 0; base < n; base += 1024) {
        int i = base + tid;
        int v = (i < n) ? deg[i] : 0;
        int x = v;
#pragma unroll
        for (int off = 1; off < 64; off <<= 1) {
            int y = __shfl_up(x, off, 64);
            if (lane >= off) x += y;
        }
        if (lane == 63) wsum[wid] = x;
        __syncthreads();
        if (wid == 0 && lane < 16) {
            int w = wsum[lane];
#pragma unroll
            for (int off = 1; off < 16; off <<= 1) {
                int y = __shfl_up(w, off, 16);
                if (lane >= off) w += y;
            }
            wsum[lane] = w;
        }
        __syncthreads();
        int excl = x - v + carry + (wid > 0 ? wsum[wid - 1] : 0);
        if (i < n) { row_ptr[i] = excl; cursor[i] = excl; }
        __syncthreads();             // all reads of carry/wsum done
        if (tid == 0) carry += wsum[15];
        __syncthreads();
    }
    if (threadIdx.x == 0) row_ptr[n] = carry;
}

__global__ void k_build_csr(const int* __restrict__ src, const int* __restrict__ dst,
                            int ne, int* __restrict__ cursor, int* __restrict__ eidx) {
    int i = blockIdx.x * blockDim.x + threadIdx.x;
    if (i < ne) {
        int p = atomicAdd(&cursor[dst[i]], 1);
        eidx[p] = src[i];
    }
}

// Tiled fp32 matmul: H[row][c] = onrm[row] * sum_k X[row][k] * W[k][c]
// Block covers TY*RPT rows x FO cols with 256 threads; X tile staged in LDS
// (+1 pad breaks the 8-way bank conflict from same-k different-row reads).
template <int K, int FO, int TX, int TY, int RPT>
__global__ __launch_bounds__(256) void k_matmul(const float* __restrict__ X,
                                                const float* __restrict__ W,
                                                const float* __restrict__ onrm,
                                                float* __restrict__ H, int n) {
    constexpr int BROWS = TY * RPT;
    constexpr int LDK = K + 1;
    __shared__ float xs[BROWS * LDK];
    int tx = threadIdx.x, ty = threadIdx.y;
    int tid = ty * TX + tx;
    int row0 = blockIdx.x * BROWS;

    for (int idx = tid; idx < BROWS * K; idx += 256) {
        int r = idx / K;            // K is power of two -> shift
        int k = idx - r * K;
        int row = row0 + r;
        xs[r * LDK + k] = (row < n) ? X[(size_t)row * K + k] : 0.f;
    }
    __syncthreads();

    float4 acc[RPT];
#pragma unroll
    for (int r = 0; r < RPT; ++r) acc[r] = make_float4(0.f, 0.f, 0.f, 0.f);

    const float4* W4 = (const float4*)W;
#pragma unroll 4
    for (int k = 0; k < K; ++k) {
        float4 w = W4[k * (FO / 4) + tx];
#pragma unroll
        for (int r = 0; r < RPT; ++r) {
            float xv = xs[(ty * RPT + r) * LDK + k];
            acc[r].x += xv * w.x;
            acc[r].y += xv * w.y;
            acc[r].z += xv * w.z;
            acc[r].w += xv * w.w;
        }
    }

#pragma unroll
    for (int r = 0; r < RPT; ++r) {
        int row = row0 + ty * RPT + r;
        if (row < n) {
            float s = onrm[row];
            float4 o = make_float4(acc[r].x * s, acc[r].y * s, acc[r].z * s, acc[r].w * s);
            ((float4*)H)[(size_t)row * (FO / 4) + tx] = o;
        }
    }
}

// One wave per node: gather-sum incoming h[src] rows (coalesced 512B/row),
// fused epilogue: *in_norm + bias (+relu). FO=128, lane holds float2.
__global__ __launch_bounds__(256) void k_agg128(const float* __restrict__ h,
                                                const int* __restrict__ row_ptr,
                                                const int* __restrict__ eidx,
                                                const float* __restrict__ inrm,
                                                const float* __restrict__ bias,
                                                float* __restrict__ out, int n, int relu) {
    int node = blockIdx.x * 4 + (threadIdx.x >> 6);
    int lane = threadIdx.x & 63;
    if (node >= n) return;
    int beg = row_ptr[node], end = row_ptr[node + 1];
    const float2* h2 = (const float2*)h;
    float ax = 0.f, ay = 0.f;
    for (int j = beg; j < end; ++j) {
        int s = eidx[j];
        float2 v = h2[(size_t)s * 64 + lane];
        ax += v.x;
        ay += v.y;
    }
    float nrm = inrm[node];
    float2 b2 = ((const float2*)bias)[lane];
    float ox = ax * nrm + b2.x;
    float oy = ay * nrm + b2.y;
    if (relu) { ox = fmaxf(ox, 0.f); oy = fmaxf(oy, 0.f); }
    float2 o; o.x = ox; o.y = oy;
    ((float2*)out)[(size_t)node * 64 + lane] = o;
}

// FO=64 variant (final layer, no relu), lane holds one float.
__global__ __launch_bounds__(256) void k_agg64(const float* __restrict__ h,
                                               const int* __restrict__ row_ptr,
                                               const int* __restrict__ eidx,
                                               const float* __restrict__ inrm,
                                               const float* __restrict__ bias,
                                               float* __restrict__ out, int n) {
    int node = blockIdx.x * 4 + (threadIdx.x >> 6);
    int lane = threadIdx.x & 63;
    if (node >= n) return;
    int beg = row_ptr[node], end = row_ptr[node + 1];
    float acc = 0.f;
    for (int j = beg; j < end; ++j) {
        int s = eidx[j];
        acc += h[(size_t)s * 64 + lane];
    }
    out[(size_t)node * 64 + lane] = acc * inrm[node] + bias[lane];
}

static inline size_t align_up(size_t v, size_t a) { return (v + a - 1) & ~(a - 1); }

extern "C" void kernel_launch(void* const* d_in, const int* in_sizes, int n_in,
                              void* d_out, int out_size, void* d_ws, size_t ws_size,
                              hipStream_t stream) {
    const float* x  = (const float*)d_in[0];
    const int* ei   = (const int*)d_in[1];
    const float* W0 = (const float*)d_in[2];
    const float* b0 = (const float*)d_in[3];
    const float* W1 = (const float*)d_in[4];
    const float* b1 = (const float*)d_in[5];
    const float* W2 = (const float*)d_in[6];
    const float* b2 = (const float*)d_in[7];
    const float* W3 = (const float*)d_in[8];
    const float* b3 = (const float*)d_in[9];

    const int n  = in_sizes[0] / 256;   // 50000
    const int ne = in_sizes[1] / 2;     // 800000
    const int* src = ei;
    const int* dst = ei + ne;

    // workspace layout
    char* ws = (char*)d_ws;
    size_t off = 0;
    auto take = [&](size_t bytes) { void* p = ws + off; off = align_up(off + bytes, 256); return p; };
    int* deg_s   = (int*)take((size_t)n * 4);
    int* deg_d   = (int*)take((size_t)n * 4);
    int* row_ptr = (int*)take((size_t)(n + 1) * 4);
    int* cursor  = (int*)take((size_t)n * 4);
    int* eidx    = (int*)take((size_t)ne * 4);
    float* onrm  = (float*)take((size_t)n * 4);
    float* inrm  = (float*)take((size_t)n * 4);
    float* hbuf  = (float*)take((size_t)n * 128 * 4);
    float* xnext = (float*)take((size_t)n * 128 * 4);
    (void)ws_size;

    // 1. zero degree counters (deg_s and deg_d are adjacent allocations)
    hipMemsetAsync(deg_s, 0, (size_t)n * 4, stream);
    hipMemsetAsync(deg_d, 0, (size_t)n * 4, stream);

    // 2. degree histogram
    k_degrees<<<(ne + 255) / 256, 256, 0, stream>>>(src, dst, ne, deg_s, deg_d);

    // 3. norms
    k_norms<<<(n + 255) / 256, 256, 0, stream>>>(deg_s, deg_d, onrm, inrm, n);

    // 4. scan dst degrees -> row_ptr + cursor
    k_scan<<<1, 1024, 0, stream>>>(deg_d, n, row_ptr, cursor);

    // 5. CSR bucket fill
    k_build_csr<<<(ne + 255) / 256, 256, 0, stream>>>(src, dst, ne, cursor, eidx);

    const int aggGrid = (n + 3) / 4;

    // Layer 0: 256 -> 128
    k_matmul<256, 128, 32, 8, 4><<<(n + 31) / 32, dim3(32, 8), 0, stream>>>(x, W0, onrm, hbuf, n);
    k_agg128<<<aggGrid, 256, 0, stream>>>(hbuf, row_ptr, eidx, inrm, b0, xnext, n, 1);

    // Layer 1: 128 -> 128
    k_matmul<128, 128, 32, 8, 4><<<(n + 31) / 32, dim3(32, 8), 0, stream>>>(xnext, W1, onrm, hbuf, n);
    k_agg128<<<aggGrid, 256, 0, stream>>>(hbuf, row_ptr, eidx, inrm, b1, xnext, n, 1);

    // Layer 2: 128 -> 128
    k_matmul<128, 128, 32, 8, 4><<<(n + 31) / 32, dim3(32, 8), 0, stream>>>(xnext, W2, onrm, hbuf, n);
    k_agg128<<<aggGrid, 256, 0, stream>>>(hbuf, row_ptr, eidx, inrm, b2, xnext, n, 1);

    // Layer 3: 128 -> 64, epilogue straight to d_out (fp32)
    k_matmul<128, 64, 16, 16, 4><<<(n + 63) / 64, dim3(16, 16), 0, stream>>>(xnext, W3, onrm, hbuf, n);
    k_agg64<<<aggGrid, 256, 0, stream>>>(hbuf, row_ptr, eidx, inrm, b3, (float*)d_out, n);
}

// Round 2
// 751.875 us; speedup vs baseline: 1.0612x; 1.0612x over previous
//
#include <hip/hip_runtime.h>

// ---------------------------------------------------------------------------
// GCN 4-layer forward on MI355X (gfx950).
//   Preprocess: degree histogram -> norms -> scan -> CSR (by dst).
//   Per layer : bf16-split MFMA matmul (3-term, ~fp32 precision)
//               -> wave-per-node CSR gather-sum, epilogue fused:
//                  *in_norm + bias, relu, *next-layer out_norm, bf16 hi/lo split.
// Fallback fp32 path (round-1 kernels) if workspace is too small.
// ---------------------------------------------------------------------------

typedef __attribute__((ext_vector_type(8))) short short8;
typedef __attribute__((ext_vector_type(4))) float f32x4;

__device__ inline unsigned short bf16_rne(float v) {
    union { float f; unsigned u; } c; c.f = v;
    unsigned u = c.u;
    unsigned lsb = (u >> 16) & 1u;
    u += 0x7fffu + lsb;
    return (unsigned short)(u >> 16);
}
__device__ inline float bf16_to_f(unsigned short h) {
    union { unsigned u; float f; } c; c.u = ((unsigned)h) << 16;
    return c.f;
}
__device__ inline void split_bf16(float v, unsigned short& hi, unsigned short& lo) {
    hi = bf16_rne(v);
    lo = bf16_rne(v - bf16_to_f(hi));
}

// ---------------------------------------------------------------------------
// Preprocessing
// ---------------------------------------------------------------------------

__global__ void k_degrees(const int* __restrict__ src, const int* __restrict__ dst,
                          int ne, int* __restrict__ degs, int* __restrict__ degd) {
    int i = blockIdx.x * blockDim.x + threadIdx.x;
    if (i < ne) {
        atomicAdd(&degs[src[i]], 1);
        atomicAdd(&degd[dst[i]], 1);
    }
}

__global__ void k_norms(const int* __restrict__ degs, const int* __restrict__ degd,
                        float* __restrict__ onrm, float* __restrict__ inrm, int n) {
    int i = blockIdx.x * blockDim.x + threadIdx.x;
    if (i < n) {
        onrm[i] = rsqrtf((float)max(degs[i], 1));
        inrm[i] = rsqrtf((float)max(degd[i], 1));
    }
}

// Single-block exclusive scan, int4 per thread (n assumed padded to x4 capacity;
// deg buffer must have n rounded-up-to-4 ints, extras zeroed by memset).
__global__ __launch_bounds__(1024) void k_scan(const int* __restrict__ deg, int n,
                                               int* __restrict__ row_ptr,
                                               int* __restrict__ cursor) {
    __shared__ int wsum[16];
    __shared__ int carry;
    int tid = threadIdx.x;
    int lane = tid & 63;
    int wid = tid >> 6;
    if (tid == 0) carry = 0;
    __syncthreads();
    int n4 = (n + 3) >> 2;
    for (int base = 0; base < n4; base += 1024) {
        int i4 = base + tid;
        int4 v = make_int4(0, 0, 0, 0);
        if (i4 < n4) v = ((const int4*)deg)[i4];
        int s = v.x + v.y + v.z + v.w;
        int x = s;
#pragma unroll
        for (int off = 1; off < 64; off <<= 1) {
            int y = __shfl_up(x, off, 64);
            if (lane >= off) x += y;
        }
        if (lane == 63) wsum[wid] = x;
        __syncthreads();
        if (wid == 0 && lane < 16) {
            int w = wsum[lane];
#pragma unroll
            for (int off = 1; off < 16; off <<= 1) {
                int y = __shfl_up(w, off, 16);
                if (lane >= off) w += y;
            }
            wsum[lane] = w;
        }
        __syncthreads();
        int excl = x - s + carry + (wid > 0 ? wsum[wid - 1] : 0);
        if (i4 < n4) {
            int e0 = excl, e1 = e0 + v.x, e2 = e1 + v.y, e3 = e2 + v.z;
            int4 o = make_int4(e0, e1, e2, e3);
            ((int4*)row_ptr)[i4] = o;
            ((int4*)cursor)[i4] = o;
        }
        __syncthreads();
        if (tid == 0) carry += wsum[15];
        __syncthreads();
    }
    if (tid == 0) row_ptr[n] = carry;
}

__global__ void k_build_csr(const int* __restrict__ src, const int* __restrict__ dst,
                            int ne, int* __restrict__ cursor, int* __restrict__ eidx) {
    int i = blockIdx.x * blockDim.x + threadIdx.x;
    if (i < ne) {
        int p = atomicAdd(&cursor[dst[i]], 1);
        eidx[p] = src[i];
    }
}

// ---------------------------------------------------------------------------
// bf16 split helpers (MFMA path)
// ---------------------------------------------------------------------------

// x (fp32 [n][256]) * onrm -> Ah/Al bf16 [.][256]
__global__ __launch_bounds__(256) void k_split_x(const float* __restrict__ x,
                                                 const float* __restrict__ onrm,
                                                 unsigned short* __restrict__ Ah,
                                                 unsigned short* __restrict__ Al, int n) {
    int i4 = blockIdx.x * blockDim.x + threadIdx.x;  // float4 index, 64 per row
    int row = i4 >> 6;
    if (row >= n) return;
    float4 v = ((const float4*)x)[i4];
    float s = onrm[row];
    unsigned short h0, l0, h1, l1, h2, l2, h3, l3;
    split_bf16(v.x * s, h0, l0);
    split_bf16(v.y * s, h1, l1);
    split_bf16(v.z * s, h2, l2);
    split_bf16(v.w * s, h3, l3);
    ushort4 hv, lv;
    hv.x = h0; hv.y = h1; hv.z = h2; hv.w = h3;
    lv.x = l0; lv.y = l1; lv.z = l2; lv.w = l3;
    ((ushort4*)Ah)[i4] = hv;
    ((ushort4*)Al)[i4] = lv;
}

// All 4 layers' W -> transposed split bf16 (Wt[c][k]); one thread per element.
__global__ void k_split_w_all(const float* __restrict__ W0, const float* __restrict__ W1,
                              const float* __restrict__ W2, const float* __restrict__ W3,
                              unsigned short* __restrict__ Wh0, unsigned short* __restrict__ Wl0,
                              unsigned short* __restrict__ Wh1, unsigned short* __restrict__ Wl1,
                              unsigned short* __restrict__ Wh2, unsigned short* __restrict__ Wl2,
                              unsigned short* __restrict__ Wh3, unsigned short* __restrict__ Wl3) {
    int i = blockIdx.x * blockDim.x + threadIdx.x;
    const float* W; unsigned short *Wh, *Wl; int K, F, off;
    if (i < 32768)                    { W = W0; Wh = Wh0; Wl = Wl0; K = 256; F = 128; off = i; }
    else if (i < 32768 + 16384)       { W = W1; Wh = Wh1; Wl = Wl1; K = 128; F = 128; off = i - 32768; }
    else if (i < 32768 + 32768)       { W = W2; Wh = Wh2; Wl = Wl2; K = 128; F = 128; off = i - 49152; }
    else if (i < 32768 + 32768 + 8192){ W = W3; Wh = Wh3; Wl = Wl3; K = 128; F = 64;  off = i - 65536; }
    else return;
    int k = off / F, c = off % F;
    unsigned short h, l;
    split_bf16(W[k * F + c], h, l);
    Wh[c * K + k] = h;
    Wl[c * K + k] = l;
}

// ---------------------------------------------------------------------------
// MFMA GEMM: H[m][c] = sum_k A[m][k]*W[k][c], A = Ah+Al (bf16 split),
// B given transposed [N][K] split. 3-term product. Block: 4 waves, 64 rows.
// ---------------------------------------------------------------------------
template <int K, int N>
__global__ __launch_bounds__(256) void k_mm(const unsigned short* __restrict__ Ah,
                                            const unsigned short* __restrict__ Al,
                                            const unsigned short* __restrict__ Bh,
                                            const unsigned short* __restrict__ Bl,
                                            float* __restrict__ H, int n) {
    constexpr int NT = N / 16;
    int w = threadIdx.x >> 6, lane = threadIdx.x & 63;
    int quad = lane >> 4, l16 = lane & 15;
    int row0 = blockIdx.x * 64 + w * 16;
    int arow = row0 + l16;
    if (arow >= n) arow = n - 1;   // clamp; result rows >= n are masked at store

    const short8* ahp = (const short8*)(Ah + (size_t)arow * K);
    const short8* alp = (const short8*)(Al + (size_t)arow * K);

    f32x4 acc[NT];
#pragma unroll
    for (int t = 0; t < NT; ++t) acc[t] = (f32x4){0.f, 0.f, 0.f, 0.f};

    for (int k0 = 0; k0 < K; k0 += 32) {
        int koff = (k0 >> 3) + quad;          // short8 index within row
        short8 av = ahp[koff];
        short8 av2 = alp[koff];
#pragma unroll
        for (int t = 0; t < NT; ++t) {
            const short8* bhp = (const short8*)(Bh + (size_t)(t * 16 + l16) * K);
            const short8* blp = (const short8*)(Bl + (size_t)(t * 16 + l16) * K);
            short8 bv = bhp[koff];
            short8 bv2 = blp[koff];
            acc[t] = __builtin_amdgcn_mfma_f32_16x16x32_bf16(av, bv, acc[t], 0, 0, 0);
            acc[t] = __builtin_amdgcn_mfma_f32_16x16x32_bf16(av2, bv, acc[t], 0, 0, 0);
            acc[t] = __builtin_amdgcn_mfma_f32_16x16x32_bf16(av, bv2, acc[t], 0, 0, 0);
        }
    }

    int orow0 = row0 + quad * 4;
#pragma unroll
    for (int t = 0; t < NT; ++t) {
#pragma unroll
        for (int r = 0; r < 4; ++r) {
            int grow = orow0 + r;
            if (grow < n) H[(size_t)grow * N + t * 16 + l16] = acc[t][r];
        }
    }
}

// ---------------------------------------------------------------------------
// Aggregation kernels (wave per node)
// ---------------------------------------------------------------------------

// FO=128, epilogue: relu(agg*inrm + b) * onrm -> bf16 hi/lo split (next layer A)
__global__ __launch_bounds__(256) void k_agg128_split(const float* __restrict__ h,
                                                      const int* __restrict__ row_ptr,
                                                      const int* __restrict__ eidx,
                                                      const float* __restrict__ inrm,
                                                      const float* __restrict__ onrm,
                                                      const float* __restrict__ bias,
                                                      unsigned short* __restrict__ Ah,
                                                      unsigned short* __restrict__ Al, int n) {
    int node = blockIdx.x * 4 + (threadIdx.x >> 6);
    int lane = threadIdx.x & 63;
    if (node >= n) return;
    int beg = row_ptr[node], end = row_ptr[node + 1];
    const float2* h2 = (const float2*)h;
    float ax = 0.f, ay = 0.f;
    for (int j = beg; j < end; ++j) {
        int s = eidx[j];
        float2 v = h2[(size_t)s * 64 + lane];
        ax += v.x;
        ay += v.y;
    }
    float nrm = inrm[node];
    float on = onrm[node];
    float2 b2 = ((const float2*)bias)[lane];
    float ox = fmaxf(ax * nrm + b2.x, 0.f) * on;
    float oy = fmaxf(ay * nrm + b2.y, 0.f) * on;
    unsigned short hx, lx, hy, ly;
    split_bf16(ox, hx, lx);
    split_bf16(oy, hy, ly);
    ushort2 hv, lv;
    hv.x = hx; hv.y = hy;
    lv.x = lx; lv.y = ly;
    ((ushort2*)Ah)[(size_t)node * 64 + lane] = hv;
    ((ushort2*)Al)[(size_t)node * 64 + lane] = lv;
}

// FO=128, fp32 output (fallback path)
__global__ __launch_bounds__(256) void k_agg128(const float* __restrict__ h,
                                                const int* __restrict__ row_ptr,
                                                const int* __restrict__ eidx,
                                                const float* __restrict__ inrm,
                                                const float* __restrict__ bias,
                                                float* __restrict__ out, int n, int relu) {
    int node = blockIdx.x * 4 + (threadIdx.x >> 6);
    int lane = threadIdx.x & 63;
    if (node >= n) return;
    int beg = row_ptr[node], end = row_ptr[node + 1];
    const float2* h2 = (const float2*)h;
    float ax = 0.f, ay = 0.f;
    for (int j = beg; j < end; ++j) {
        int s = eidx[j];
        float2 v = h2[(size_t)s * 64 + lane];
        ax += v.x;
        ay += v.y;
    }
    float nrm = inrm[node];
    float2 b2 = ((const float2*)bias)[lane];
    float ox = ax * nrm + b2.x;
    float oy = ay * nrm + b2.y;
    if (relu) { ox = fmaxf(ox, 0.f); oy = fmaxf(oy, 0.f); }
    float2 o; o.x = ox; o.y = oy;
    ((float2*)out)[(size_t)node * 64 + lane] = o;
}

// FO=64 final layer, fp32 to d_out
__global__ __launch_bounds__(256) void k_agg64(const float* __restrict__ h,
                                               const int* __restrict__ row_ptr,
                                               const int* __restrict__ eidx,
                                               const float* __restrict__ inrm,
                                               const float* __restrict__ bias,
                                               float* __restrict__ out, int n) {
    int node = blockIdx.x * 4 + (threadIdx.x >> 6);
    int lane = threadIdx.x & 63;
    if (node >= n) return;
    int beg = row_ptr[node], end = row_ptr[node + 1];
    float acc = 0.f;
    for (int j = beg; j < end; ++j) {
        int s = eidx[j];
        acc += h[(size_t)s * 64 + lane];
    }
    out[(size_t)node * 64 + lane] = acc * inrm[node] + bias[lane];
}

// ---------------------------------------------------------------------------
// Fallback fp32 matmul (round-1, known-good)
// ---------------------------------------------------------------------------
template <int K, int FO, int TX, int TY, int RPT>
__global__ __launch_bounds__(256) void k_matmul(const float* __restrict__ X,
                                                const float* __restrict__ W,
                                                const float* __restrict__ onrm,
                                                float* __restrict__ H, int n) {
    constexpr int BROWS = TY * RPT;
    constexpr int LDK = K + 1;
    __shared__ float xs[BROWS * LDK];
    int tx = threadIdx.x, ty = threadIdx.y;
    int tid = ty * TX + tx;
    int row0 = blockIdx.x * BROWS;

    for (int idx = tid; idx < BROWS * K; idx += 256) {
        int r = idx / K;
        int k = idx - r * K;
        int row = row0 + r;
        xs[r * LDK + k] = (row < n) ? X[(size_t)row * K + k] : 0.f;
    }
    __syncthreads();

    float4 acc[RPT];
#pragma unroll
    for (int r = 0; r < RPT; ++r) acc[r] = make_float4(0.f, 0.f, 0.f, 0.f);

    const float4* W4 = (const float4*)W;
#pragma unroll 4
    for (int k = 0; k < K; ++k) {
        float4 w = W4[k * (FO / 4) + tx];
#pragma unroll
        for (int r = 0; r < RPT; ++r) {
            float xv = xs[(ty * RPT + r) * LDK + k];
            acc[r].x += xv * w.x;
            acc[r].y += xv * w.y;
            acc[r].z += xv * w.z;
            acc[r].w += xv * w.w;
        }
    }

#pragma unroll
    for (int r = 0; r < RPT; ++r) {
        int row = row0 + ty * RPT + r;
        if (row < n) {
            float s = onrm[row];
            float4 o = make_float4(acc[r].x * s, acc[r].y * s, acc[r].z * s, acc[r].w * s);
            ((float4*)H)[(size_t)row * (FO / 4) + tx] = o;
        }
    }
}

static inline size_t align_up(size_t v, size_t a) { return (v + a - 1) & ~(a - 1); }

extern "C" void kernel_launch(void* const* d_in, const int* in_sizes, int n_in,
                              void* d_out, int out_size, void* d_ws, size_t ws_size,
                              hipStream_t stream) {
    const float* x  = (const float*)d_in[0];
    const int* ei   = (const int*)d_in[1];
    const float* W0 = (const float*)d_in[2];
    const float* b0 = (const float*)d_in[3];
    const float* W1 = (const float*)d_in[4];
    const float* b1 = (const float*)d_in[5];
    const float* W2 = (const float*)d_in[6];
    const float* b2 = (const float*)d_in[7];
    const float* W3 = (const float*)d_in[8];
    const float* b3 = (const float*)d_in[9];

    const int n  = in_sizes[0] / 256;   // 50000
    const int ne = in_sizes[1] / 2;     // 800000
    const int n_pad = (n + 63) & ~63;
    const int* src = ei;
    const int* dst = ei + ne;

    // ---- shared preprocessing layout ----
    char* ws = (char*)d_ws;
    size_t off = 0;
    auto take = [&](size_t bytes) { void* p = ws + off; off = align_up(off + bytes, 256); return p; };
    int* deg_s   = (int*)take((size_t)n_pad * 4);
    int* deg_d   = (int*)take((size_t)n_pad * 4);
    int* row_ptr = (int*)take((size_t)(n_pad + 4) * 4);
    int* cursor  = (int*)take((size_t)n_pad * 4);
    int* eidx    = (int*)take((size_t)ne * 4);
    float* onrm  = (float*)take((size_t)n * 4);
    float* inrm  = (float*)take((size_t)n * 4);

    // ---- MFMA-path layout (tentative) ----
    size_t off_save = off;
    unsigned short* Ah  = (unsigned short*)take((size_t)n_pad * 256 * 2);
    unsigned short* Al  = (unsigned short*)take((size_t)n_pad * 256 * 2);
    float* hbuf         = (float*)take((size_t)n * 128 * 4);
    unsigned short* Wh0 = (unsigned short*)take(256 * 128 * 2);
    unsigned short* Wl0 = (unsigned short*)take(256 * 128 * 2);
    unsigned short* Wh1 = (unsigned short*)take(128 * 128 * 2);
    unsigned short* Wl1 = (unsigned short*)take(128 * 128 * 2);
    unsigned short* Wh2 = (unsigned short*)take(128 * 128 * 2);
    unsigned short* Wl2 = (unsigned short*)take(128 * 128 * 2);
    unsigned short* Wh3 = (unsigned short*)take(128 * 64 * 2);
    unsigned short* Wl3 = (unsigned short*)take(128 * 64 * 2);
    bool use_mfma = (off <= ws_size);

    // ---- preprocessing (both paths) ----
    hipMemsetAsync(deg_s, 0, (size_t)n_pad * 4, stream);
    hipMemsetAsync(deg_d, 0, (size_t)n_pad * 4, stream);
    k_degrees<<<(ne + 255) / 256, 256, 0, stream>>>(src, dst, ne, deg_s, deg_d);
    k_norms<<<(n + 255) / 256, 256, 0, stream>>>(deg_s, deg_d, onrm, inrm, n);
    k_scan<<<1, 1024, 0, stream>>>(deg_d, n, row_ptr, cursor);
    k_build_csr<<<(ne + 255) / 256, 256, 0, stream>>>(src, dst, ne, cursor, eidx);

    const int aggGrid = (n + 3) / 4;

    if (use_mfma) {
        k_split_w_all<<<(73728 + 255) / 256, 256, 0, stream>>>(
            W0, W1, W2, W3, Wh0, Wl0, Wh1, Wl1, Wh2, Wl2, Wh3, Wl3);
        k_split_x<<<((n * 64) + 255) / 256, 256, 0, stream>>>(x, onrm, Ah, Al, n);

        const int mmGrid = n_pad / 64;
        // L0: 256 -> 128
        k_mm<256, 128><<<mmGrid, 256, 0, stream>>>(Ah, Al, Wh0, Wl0, hbuf, n);
        k_agg128_split<<<aggGrid, 256, 0, stream>>>(hbuf, row_ptr, eidx, inrm, onrm, b0, Ah, Al, n);
        // L1
        k_mm<128, 128><<<mmGrid, 256, 0, stream>>>(Ah, Al, Wh1, Wl1, hbuf, n);
        k_agg128_split<<<aggGrid, 256, 0, stream>>>(hbuf, row_ptr, eidx, inrm, onrm, b1, Ah, Al, n);
        // L2
        k_mm<128, 128><<<mmGrid, 256, 0, stream>>>(Ah, Al, Wh2, Wl2, hbuf, n);
        k_agg128_split<<<aggGrid, 256, 0, stream>>>(hbuf, row_ptr, eidx, inrm, onrm, b2, Ah, Al, n);
        // L3: 128 -> 64
        k_mm<128, 64><<<mmGrid, 256, 0, stream>>>(Ah, Al, Wh3, Wl3, hbuf, n);
        k_agg64<<<aggGrid, 256, 0, stream>>>(hbuf, row_ptr, eidx, inrm, b3, (float*)d_out, n);
    } else {
        // fp32 fallback (round-1 structure)
        off = off_save;
        float* hbufF  = (float*)take((size_t)n * 128 * 4);
        float* xnextF = (float*)take((size_t)n * 128 * 4);

        k_matmul<256, 128, 32, 8, 4><<<(n + 31) / 32, dim3(32, 8), 0, stream>>>(x, W0, onrm, hbufF, n);
        k_agg128<<<aggGrid, 256, 0, stream>>>(hbufF, row_ptr, eidx, inrm, b0, xnextF, n, 1);
        k_matmul<128, 128, 32, 8, 4><<<(n + 31) / 32, dim3(32, 8), 0, stream>>>(xnextF, W1, onrm, hbufF, n);
        k_agg128<<<aggGrid, 256, 0, stream>>>(hbufF, row_ptr, eidx, inrm, b1, xnextF, n, 1);
        k_matmul<128, 128, 32, 8, 4><<<(n + 31) / 32, dim3(32, 8), 0, stream>>>(xnextF, W2, onrm, hbufF, n);
        k_agg128<<<aggGrid, 256, 0, stream>>>(hbufF, row_ptr, eidx, inrm, b2, xnextF, n, 1);
        k_matmul<128, 64, 16, 16, 4><<<(n + 63) / 64, dim3(16, 16), 0, stream>>>(xnextF, W3, onrm, hbufF, n);
        k_agg64<<<aggGrid, 256, 0, stream>>>(hbufF, row_ptr, eidx, inrm, b3, (float*)d_out, n);
    }
}

// Round 3
// 562.291 us; speedup vs baseline: 1.4190x; 1.3372x over previous
//
#include <hip/hip_runtime.h>
#include <hip/hip_fp16.h>

// ---------------------------------------------------------------------------
// GCN 4-layer forward on MI355X (gfx950).
//   Preprocess: degree histogram -> norms -> scan -> CSR (by dst).
//   Per layer : bf16-split MFMA matmul (3-term, ~fp32 precision) -> h in fp16
//               -> wave-per-node CSR gather-sum (x4 unrolled, fp32 accum),
//                  epilogue fused: *in_norm + bias, relu, *out_norm,
//                  bf16 hi/lo split for next layer's MFMA A operand.
// Fallback fp32 path (round-1 kernels) if workspace is too small.
// ---------------------------------------------------------------------------

typedef __attribute__((ext_vector_type(8))) short short8;
typedef __attribute__((ext_vector_type(4))) float f32x4;

__device__ inline unsigned short bf16_rne(float v) {
    union { float f; unsigned u; } c; c.f = v;
    unsigned u = c.u;
    unsigned lsb = (u >> 16) & 1u;
    u += 0x7fffu + lsb;
    return (unsigned short)(u >> 16);
}
__device__ inline float bf16_to_f(unsigned short h) {
    union { unsigned u; float f; } c; c.u = ((unsigned)h) << 16;
    return c.f;
}
__device__ inline void split_bf16(float v, unsigned short& hi, unsigned short& lo) {
    hi = bf16_rne(v);
    lo = bf16_rne(v - bf16_to_f(hi));
}

// ---------------------------------------------------------------------------
// Preprocessing
// ---------------------------------------------------------------------------

__global__ void k_degrees(const int* __restrict__ src, const int* __restrict__ dst,
                          int ne, int* __restrict__ degs, int* __restrict__ degd) {
    int i = blockIdx.x * blockDim.x + threadIdx.x;
    if (i < ne) {
        atomicAdd(&degs[src[i]], 1);
        atomicAdd(&degd[dst[i]], 1);
    }
}

__global__ void k_norms(const int* __restrict__ degs, const int* __restrict__ degd,
                        float* __restrict__ onrm, float* __restrict__ inrm, int n) {
    int i = blockIdx.x * blockDim.x + threadIdx.x;
    if (i < n) {
        onrm[i] = rsqrtf((float)max(degs[i], 1));
        inrm[i] = rsqrtf((float)max(degd[i], 1));
    }
}

// Single-block exclusive scan, int4 per thread.
__global__ __launch_bounds__(1024) void k_scan(const int* __restrict__ deg, int n,
                                               int* __restrict__ row_ptr,
                                               int* __restrict__ cursor) {
    __shared__ int wsum[16];
    __shared__ int carry;
    int tid = threadIdx.x;
    int lane = tid & 63;
    int wid = tid >> 6;
    if (tid == 0) carry = 0;
    __syncthreads();
    int n4 = (n + 3) >> 2;
    for (int base = 0; base < n4; base += 1024) {
        int i4 = base + tid;
        int4 v = make_int4(0, 0, 0, 0);
        if (i4 < n4) v = ((const int4*)deg)[i4];
        int s = v.x + v.y + v.z + v.w;
        int x = s;
#pragma unroll
        for (int off = 1; off < 64; off <<= 1) {
            int y = __shfl_up(x, off, 64);
            if (lane >= off) x += y;
        }
        if (lane == 63) wsum[wid] = x;
        __syncthreads();
        if (wid == 0 && lane < 16) {
            int w = wsum[lane];
#pragma unroll
            for (int off = 1; off < 16; off <<= 1) {
                int y = __shfl_up(w, off, 16);
                if (lane >= off) w += y;
            }
            wsum[lane] = w;
        }
        __syncthreads();
        int excl = x - s + carry + (wid > 0 ? wsum[wid - 1] : 0);
        if (i4 < n4) {
            int e0 = excl, e1 = e0 + v.x, e2 = e1 + v.y, e3 = e2 + v.z;
            int4 o = make_int4(e0, e1, e2, e3);
            ((int4*)row_ptr)[i4] = o;
            ((int4*)cursor)[i4] = o;
        }
        __syncthreads();
        if (tid == 0) carry += wsum[15];
        __syncthreads();
    }
    if (tid == 0) row_ptr[n] = carry;
}

__global__ void k_build_csr(const int* __restrict__ src, const int* __restrict__ dst,
                            int ne, int* __restrict__ cursor, int* __restrict__ eidx) {
    int i = blockIdx.x * blockDim.x + threadIdx.x;
    if (i < ne) {
        int p = atomicAdd(&cursor[dst[i]], 1);
        eidx[p] = src[i];
    }
}

// ---------------------------------------------------------------------------
// bf16 split helpers (MFMA path)
// ---------------------------------------------------------------------------

__global__ __launch_bounds__(256) void k_split_x(const float* __restrict__ x,
                                                 const float* __restrict__ onrm,
                                                 unsigned short* __restrict__ Ah,
                                                 unsigned short* __restrict__ Al, int n) {
    int i4 = blockIdx.x * blockDim.x + threadIdx.x;  // float4 index, 64 per row
    int row = i4 >> 6;
    if (row >= n) return;
    float4 v = ((const float4*)x)[i4];
    float s = onrm[row];
    unsigned short h0, l0, h1, l1, h2, l2, h3, l3;
    split_bf16(v.x * s, h0, l0);
    split_bf16(v.y * s, h1, l1);
    split_bf16(v.z * s, h2, l2);
    split_bf16(v.w * s, h3, l3);
    ushort4 hv, lv;
    hv.x = h0; hv.y = h1; hv.z = h2; hv.w = h3;
    lv.x = l0; lv.y = l1; lv.z = l2; lv.w = l3;
    ((ushort4*)Ah)[i4] = hv;
    ((ushort4*)Al)[i4] = lv;
}

__global__ void k_split_w_all(const float* __restrict__ W0, const float* __restrict__ W1,
                              const float* __restrict__ W2, const float* __restrict__ W3,
                              unsigned short* __restrict__ Wh0, unsigned short* __restrict__ Wl0,
                              unsigned short* __restrict__ Wh1, unsigned short* __restrict__ Wl1,
                              unsigned short* __restrict__ Wh2, unsigned short* __restrict__ Wl2,
                              unsigned short* __restrict__ Wh3, unsigned short* __restrict__ Wl3) {
    int i = blockIdx.x * blockDim.x + threadIdx.x;
    const float* W; unsigned short *Wh, *Wl; int K, F, off;
    if (i < 32768)                    { W = W0; Wh = Wh0; Wl = Wl0; K = 256; F = 128; off = i; }
    else if (i < 32768 + 16384)       { W = W1; Wh = Wh1; Wl = Wl1; K = 128; F = 128; off = i - 32768; }
    else if (i < 32768 + 32768)       { W = W2; Wh = Wh2; Wl = Wl2; K = 128; F = 128; off = i - 49152; }
    else if (i < 32768 + 32768 + 8192){ W = W3; Wh = Wh3; Wl = Wl3; K = 128; F = 64;  off = i - 65536; }
    else return;
    int k = off / F, c = off % F;
    unsigned short h, l;
    split_bf16(W[k * F + c], h, l);
    Wh[c * K + k] = h;
    Wl[c * K + k] = l;
}

// ---------------------------------------------------------------------------
// MFMA GEMM: H[m][c] = sum_k A[m][k]*W[k][c]; H stored fp16.
// ---------------------------------------------------------------------------
template <int K, int N>
__global__ __launch_bounds__(256) void k_mm(const unsigned short* __restrict__ Ah,
                                            const unsigned short* __restrict__ Al,
                                            const unsigned short* __restrict__ Bh,
                                            const unsigned short* __restrict__ Bl,
                                            __half* __restrict__ H, int n) {
    constexpr int NT = N / 16;
    int w = threadIdx.x >> 6, lane = threadIdx.x & 63;
    int quad = lane >> 4, l16 = lane & 15;
    int row0 = blockIdx.x * 64 + w * 16;
    int arow = row0 + l16;
    if (arow >= n) arow = n - 1;

    const short8* ahp = (const short8*)(Ah + (size_t)arow * K);
    const short8* alp = (const short8*)(Al + (size_t)arow * K);

    f32x4 acc[NT];
#pragma unroll
    for (int t = 0; t < NT; ++t) acc[t] = (f32x4){0.f, 0.f, 0.f, 0.f};

    for (int k0 = 0; k0 < K; k0 += 32) {
        int koff = (k0 >> 3) + quad;
        short8 av = ahp[koff];
        short8 av2 = alp[koff];
#pragma unroll
        for (int t = 0; t < NT; ++t) {
            const short8* bhp = (const short8*)(Bh + (size_t)(t * 16 + l16) * K);
            const short8* blp = (const short8*)(Bl + (size_t)(t * 16 + l16) * K);
            short8 bv = bhp[koff];
            short8 bv2 = blp[koff];
            acc[t] = __builtin_amdgcn_mfma_f32_16x16x32_bf16(av, bv, acc[t], 0, 0, 0);
            acc[t] = __builtin_amdgcn_mfma_f32_16x16x32_bf16(av2, bv, acc[t], 0, 0, 0);
            acc[t] = __builtin_amdgcn_mfma_f32_16x16x32_bf16(av, bv2, acc[t], 0, 0, 0);
        }
    }

    int orow0 = row0 + quad * 4;
#pragma unroll
    for (int t = 0; t < NT; ++t) {
#pragma unroll
        for (int r = 0; r < 4; ++r) {
            int grow = orow0 + r;
            if (grow < n) H[(size_t)grow * N + t * 16 + l16] = __float2half(acc[t][r]);
        }
    }
}

// ---------------------------------------------------------------------------
// Aggregation: wave per node, fp16 h, x4-unrolled gather, fp32 accumulate.
// ---------------------------------------------------------------------------

// FO=128: epilogue relu(agg*inrm + b) * onrm -> bf16 hi/lo split.
__global__ __launch_bounds__(256) void k_agg128_split(const __half* __restrict__ h,
                                                      const int* __restrict__ row_ptr,
                                                      const int* __restrict__ eidx,
                                                      const float* __restrict__ inrm,
                                                      const float* __restrict__ onrm,
                                                      const float* __restrict__ bias,
                                                      unsigned short* __restrict__ Ah,
                                                      unsigned short* __restrict__ Al, int n) {
    int node = blockIdx.x * 4 + (threadIdx.x >> 6);
    int lane = threadIdx.x & 63;
    if (node >= n) return;
    int beg = row_ptr[node], end = row_ptr[node + 1];
    const __half2* h2 = (const __half2*)h;

    float ax0 = 0.f, ay0 = 0.f, ax1 = 0.f, ay1 = 0.f;
    float ax2 = 0.f, ay2 = 0.f, ax3 = 0.f, ay3 = 0.f;
    int j = beg;
    for (; j + 4 <= end; j += 4) {
        int s0 = eidx[j], s1 = eidx[j + 1], s2 = eidx[j + 2], s3 = eidx[j + 3];
        __half2 v0 = h2[(size_t)s0 * 64 + lane];
        __half2 v1 = h2[(size_t)s1 * 64 + lane];
        __half2 v2 = h2[(size_t)s2 * 64 + lane];
        __half2 v3 = h2[(size_t)s3 * 64 + lane];
        float2 f0 = __half22float2(v0), f1 = __half22float2(v1);
        float2 f2 = __half22float2(v2), f3 = __half22float2(v3);
        ax0 += f0.x; ay0 += f0.y;
        ax1 += f1.x; ay1 += f1.y;
        ax2 += f2.x; ay2 += f2.y;
        ax3 += f3.x; ay3 += f3.y;
    }
    for (; j < end; ++j) {
        float2 f = __half22float2(h2[(size_t)eidx[j] * 64 + lane]);
        ax0 += f.x; ay0 += f.y;
    }
    float ax = (ax0 + ax1) + (ax2 + ax3);
    float ay = (ay0 + ay1) + (ay2 + ay3);

    float nrm = inrm[node];
    float on = onrm[node];
    float2 b2 = ((const float2*)bias)[lane];
    float ox = fmaxf(ax * nrm + b2.x, 0.f) * on;
    float oy = fmaxf(ay * nrm + b2.y, 0.f) * on;
    unsigned short hx, lx, hy, ly;
    split_bf16(ox, hx, lx);
    split_bf16(oy, hy, ly);
    ushort2 hv, lv;
    hv.x = hx; hv.y = hy;
    lv.x = lx; lv.y = ly;
    ((ushort2*)Ah)[(size_t)node * 64 + lane] = hv;
    ((ushort2*)Al)[(size_t)node * 64 + lane] = lv;
}

// FO=64 final layer: fp16 h, fp32 out to d_out.
__global__ __launch_bounds__(256) void k_agg64(const __half* __restrict__ h,
                                               const int* __restrict__ row_ptr,
                                               const int* __restrict__ eidx,
                                               const float* __restrict__ inrm,
                                               const float* __restrict__ bias,
                                               float* __restrict__ out, int n) {
    int node = blockIdx.x * 4 + (threadIdx.x >> 6);
    int lane = threadIdx.x & 63;
    if (node >= n) return;
    int beg = row_ptr[node], end = row_ptr[node + 1];
    float a0 = 0.f, a1 = 0.f, a2 = 0.f, a3 = 0.f;
    int j = beg;
    for (; j + 4 <= end; j += 4) {
        int s0 = eidx[j], s1 = eidx[j + 1], s2 = eidx[j + 2], s3 = eidx[j + 3];
        float v0 = __half2float(h[(size_t)s0 * 64 + lane]);
        float v1 = __half2float(h[(size_t)s1 * 64 + lane]);
        float v2 = __half2float(h[(size_t)s2 * 64 + lane]);
        float v3 = __half2float(h[(size_t)s3 * 64 + lane]);
        a0 += v0; a1 += v1; a2 += v2; a3 += v3;
    }
    for (; j < end; ++j) a0 += __half2float(h[(size_t)eidx[j] * 64 + lane]);
    float acc = (a0 + a1) + (a2 + a3);
    out[(size_t)node * 64 + lane] = acc * inrm[node] + bias[lane];
}

// ---------------------------------------------------------------------------
// Fallback fp32 path (round-1, known-good)
// ---------------------------------------------------------------------------
template <int K, int FO, int TX, int TY, int RPT>
__global__ __launch_bounds__(256) void k_matmul(const float* __restrict__ X,
                                                const float* __restrict__ W,
                                                const float* __restrict__ onrm,
                                                float* __restrict__ H, int n) {
    constexpr int BROWS = TY * RPT;
    constexpr int LDK = K + 1;
    __shared__ float xs[BROWS * LDK];
    int tx = threadIdx.x, ty = threadIdx.y;
    int tid = ty * TX + tx;
    int row0 = blockIdx.x * BROWS;

    for (int idx = tid; idx < BROWS * K; idx += 256) {
        int r = idx / K;
        int k = idx - r * K;
        int row = row0 + r;
        xs[r * LDK + k] = (row < n) ? X[(size_t)row * K + k] : 0.f;
    }
    __syncthreads();

    float4 acc[RPT];
#pragma unroll
    for (int r = 0; r < RPT; ++r) acc[r] = make_float4(0.f, 0.f, 0.f, 0.f);

    const float4* W4 = (const float4*)W;
#pragma unroll 4
    for (int k = 0; k < K; ++k) {
        float4 w = W4[k * (FO / 4) + tx];
#pragma unroll
        for (int r = 0; r < RPT; ++r) {
            float xv = xs[(ty * RPT + r) * LDK + k];
            acc[r].x += xv * w.x;
            acc[r].y += xv * w.y;
            acc[r].z += xv * w.z;
            acc[r].w += xv * w.w;
        }
    }

#pragma unroll
    for (int r = 0; r < RPT; ++r) {
        int row = row0 + ty * RPT + r;
        if (row < n) {
            float s = onrm[row];
            float4 o = make_float4(acc[r].x * s, acc[r].y * s, acc[r].z * s, acc[r].w * s);
            ((float4*)H)[(size_t)row * (FO / 4) + tx] = o;
        }
    }
}

__global__ __launch_bounds__(256) void k_agg128f(const float* __restrict__ h,
                                                 const int* __restrict__ row_ptr,
                                                 const int* __restrict__ eidx,
                                                 const float* __restrict__ inrm,
                                                 const float* __restrict__ bias,
                                                 float* __restrict__ out, int n, int relu) {
    int node = blockIdx.x * 4 + (threadIdx.x >> 6);
    int lane = threadIdx.x & 63;
    if (node >= n) return;
    int beg = row_ptr[node], end = row_ptr[node + 1];
    const float2* h2 = (const float2*)h;
    float ax = 0.f, ay = 0.f;
    for (int j = beg; j < end; ++j) {
        int s = eidx[j];
        float2 v = h2[(size_t)s * 64 + lane];
        ax += v.x;
        ay += v.y;
    }
    float nrm = inrm[node];
    float2 b2 = ((const float2*)bias)[lane];
    float ox = ax * nrm + b2.x;
    float oy = ay * nrm + b2.y;
    if (relu) { ox = fmaxf(ox, 0.f); oy = fmaxf(oy, 0.f); }
    float2 o; o.x = ox; o.y = oy;
    ((float2*)out)[(size_t)node * 64 + lane] = o;
}

__global__ __launch_bounds__(256) void k_agg64f(const float* __restrict__ h,
                                                const int* __restrict__ row_ptr,
                                                const int* __restrict__ eidx,
                                                const float* __restrict__ inrm,
                                                const float* __restrict__ bias,
                                                float* __restrict__ out, int n) {
    int node = blockIdx.x * 4 + (threadIdx.x >> 6);
    int lane = threadIdx.x & 63;
    if (node >= n) return;
    int beg = row_ptr[node], end = row_ptr[node + 1];
    float acc = 0.f;
    for (int j = beg; j < end; ++j) {
        int s = eidx[j];
        acc += h[(size_t)s * 64 + lane];
    }
    out[(size_t)node * 64 + lane] = acc * inrm[node] + bias[lane];
}

static inline size_t align_up(size_t v, size_t a) { return (v + a - 1) & ~(a - 1); }

extern "C" void kernel_launch(void* const* d_in, const int* in_sizes, int n_in,
                              void* d_out, int out_size, void* d_ws, size_t ws_size,
                              hipStream_t stream) {
    const float* x  = (const float*)d_in[0];
    const int* ei   = (const int*)d_in[1];
    const float* W0 = (const float*)d_in[2];
    const float* b0 = (const float*)d_in[3];
    const float* W1 = (const float*)d_in[4];
    const float* b1 = (const float*)d_in[5];
    const float* W2 = (const float*)d_in[6];
    const float* b2 = (const float*)d_in[7];
    const float* W3 = (const float*)d_in[8];
    const float* b3 = (const float*)d_in[9];

    const int n  = in_sizes[0] / 256;   // 50000
    const int ne = in_sizes[1] / 2;     // 800000
    const int n_pad = (n + 63) & ~63;
    const int* src = ei;
    const int* dst = ei + ne;

    // ---- shared preprocessing layout ----
    char* ws = (char*)d_ws;
    size_t off = 0;
    auto take = [&](size_t bytes) { void* p = ws + off; off = align_up(off + bytes, 256); return p; };
    int* deg_s   = (int*)take((size_t)n_pad * 4);
    int* deg_d   = (int*)take((size_t)n_pad * 4);
    int* row_ptr = (int*)take((size_t)(n_pad + 4) * 4);
    int* cursor  = (int*)take((size_t)n_pad * 4);
    int* eidx    = (int*)take((size_t)ne * 4);
    float* onrm  = (float*)take((size_t)n * 4);
    float* inrm  = (float*)take((size_t)n * 4);

    // ---- MFMA-path layout ----
    size_t off_save = off;
    unsigned short* Ah  = (unsigned short*)take((size_t)n_pad * 256 * 2);
    unsigned short* Al  = (unsigned short*)take((size_t)n_pad * 256 * 2);
    __half* hbuf        = (__half*)take((size_t)n * 128 * 2);
    unsigned short* Wh0 = (unsigned short*)take(256 * 128 * 2);
    unsigned short* Wl0 = (unsigned short*)take(256 * 128 * 2);
    unsigned short* Wh1 = (unsigned short*)take(128 * 128 * 2);
    unsigned short* Wl1 = (unsigned short*)take(128 * 128 * 2);
    unsigned short* Wh2 = (unsigned short*)take(128 * 128 * 2);
    unsigned short* Wl2 = (unsigned short*)take(128 * 128 * 2);
    unsigned short* Wh3 = (unsigned short*)take(128 * 64 * 2);
    unsigned short* Wl3 = (unsigned short*)take(128 * 64 * 2);
    bool use_mfma = (off <= ws_size);

    // ---- preprocessing (both paths) ----
    hipMemsetAsync(deg_s, 0, (size_t)n_pad * 4, stream);
    hipMemsetAsync(deg_d, 0, (size_t)n_pad * 4, stream);
    k_degrees<<<(ne + 255) / 256, 256, 0, stream>>>(src, dst, ne, deg_s, deg_d);
    k_norms<<<(n + 255) / 256, 256, 0, stream>>>(deg_s, deg_d, onrm, inrm, n);
    k_scan<<<1, 1024, 0, stream>>>(deg_d, n, row_ptr, cursor);
    k_build_csr<<<(ne + 255) / 256, 256, 0, stream>>>(src, dst, ne, cursor, eidx);

    const int aggGrid = (n + 3) / 4;

    if (use_mfma) {
        k_split_w_all<<<(73728 + 255) / 256, 256, 0, stream>>>(
            W0, W1, W2, W3, Wh0, Wl0, Wh1, Wl1, Wh2, Wl2, Wh3, Wl3);
        k_split_x<<<((n * 64) + 255) / 256, 256, 0, stream>>>(x, onrm, Ah, Al, n);

        const int mmGrid = n_pad / 64;
        // L0: 256 -> 128
        k_mm<256, 128><<<mmGrid, 256, 0, stream>>>(Ah, Al, Wh0, Wl0, hbuf, n);
        k_agg128_split<<<aggGrid, 256, 0, stream>>>(hbuf, row_ptr, eidx, inrm, onrm, b0, Ah, Al, n);
        // L1
        k_mm<128, 128><<<mmGrid, 256, 0, stream>>>(Ah, Al, Wh1, Wl1, hbuf, n);
        k_agg128_split<<<aggGrid, 256, 0, stream>>>(hbuf, row_ptr, eidx, inrm, onrm, b1, Ah, Al, n);
        // L2
        k_mm<128, 128><<<mmGrid, 256, 0, stream>>>(Ah, Al, Wh2, Wl2, hbuf, n);
        k_agg128_split<<<aggGrid, 256, 0, stream>>>(hbuf, row_ptr, eidx, inrm, onrm, b2, Ah, Al, n);
        // L3: 128 -> 64
        k_mm<128, 64><<<mmGrid, 256, 0, stream>>>(Ah, Al, Wh3, Wl3, hbuf, n);
        k_agg64<<<aggGrid, 256, 0, stream>>>(hbuf, row_ptr, eidx, inrm, b3, (float*)d_out, n);
    } else {
        // fp32 fallback (round-1 structure)
        off = off_save;
        float* hbufF  = (float*)take((size_t)n * 128 * 4);
        float* xnextF = (float*)take((size_t)n * 128 * 4);

        k_matmul<256, 128, 32, 8, 4><<<(n + 31) / 32, dim3(32, 8), 0, stream>>>(x, W0, onrm, hbufF, n);
        k_agg128f<<<aggGrid, 256, 0, stream>>>(hbufF, row_ptr, eidx, inrm, b0, xnextF, n, 1);
        k_matmul<128, 128, 32, 8, 4><<<(n + 31) / 32, dim3(32, 8), 0, stream>>>(xnextF, W1, onrm, hbufF, n);
        k_agg128f<<<aggGrid, 256, 0, stream>>>(hbufF, row_ptr, eidx, inrm, b1, xnextF, n, 1);
        k_matmul<128, 128, 32, 8, 4><<<(n + 31) / 32, dim3(32, 8), 0, stream>>>(xnextF, W2, onrm, hbufF, n);
        k_agg128f<<<aggGrid, 256, 0, stream>>>(hbufF, row_ptr, eidx, inrm, b2, xnextF, n, 1);
        k_matmul<128, 64, 16, 16, 4><<<(n + 63) / 64, dim3(16, 16), 0, stream>>>(xnextF, W3, onrm, hbufF, n);
        k_agg64f<<<aggGrid, 256, 0, stream>>>(hbufF, row_ptr, eidx, inrm, b3, (float*)d_out, n);
    }
}

// Round 4
// 458.187 us; speedup vs baseline: 1.7414x; 1.2272x over previous
//
#include <hip/hip_runtime.h>
#include <hip/hip_fp16.h>

// ---------------------------------------------------------------------------
// GCN 4-layer forward on MI355X (gfx950).
//   Preprocess: degree histogram -> norms -> scan -> CSR (by dst).
//   Per layer : bf16-split MFMA GEMM (3-term, ~fp32 precision), B staged in
//               LDS (XOR-swizzled, 64KB) -> h in fp16
//               -> wave-per-node CSR gather-sum (x4 unrolled, fp32 accum),
//                  epilogue fused: *in_norm + bias, relu, *out_norm,
//                  bf16 hi/lo split for next layer's MFMA A operand.
// Fallback fp32 path (round-1 kernels) if workspace is too small.
// ---------------------------------------------------------------------------

typedef __attribute__((ext_vector_type(8))) short short8;
typedef __attribute__((ext_vector_type(4))) float f32x4;

__device__ inline unsigned short bf16_rne(float v) {
    union { float f; unsigned u; } c; c.f = v;
    unsigned u = c.u;
    unsigned lsb = (u >> 16) & 1u;
    u += 0x7fffu + lsb;
    return (unsigned short)(u >> 16);
}
__device__ inline float bf16_to_f(unsigned short h) {
    union { unsigned u; float f; } c; c.u = ((unsigned)h) << 16;
    return c.f;
}
__device__ inline void split_bf16(float v, unsigned short& hi, unsigned short& lo) {
    hi = bf16_rne(v);
    lo = bf16_rne(v - bf16_to_f(hi));
}

// ---------------------------------------------------------------------------
// Preprocessing
// ---------------------------------------------------------------------------

__global__ void k_degrees(const int* __restrict__ src, const int* __restrict__ dst,
                          int ne, int* __restrict__ degs, int* __restrict__ degd) {
    int i = blockIdx.x * blockDim.x + threadIdx.x;
    if (i < ne) {
        atomicAdd(&degs[src[i]], 1);
        atomicAdd(&degd[dst[i]], 1);
    }
}

__global__ void k_norms(const int* __restrict__ degs, const int* __restrict__ degd,
                        float* __restrict__ onrm, float* __restrict__ inrm, int n) {
    int i = blockIdx.x * blockDim.x + threadIdx.x;
    if (i < n) {
        onrm[i] = rsqrtf((float)max(degs[i], 1));
        inrm[i] = rsqrtf((float)max(degd[i], 1));
    }
}

// Single-block exclusive scan, int4 per thread.
__global__ __launch_bounds__(1024) void k_scan(const int* __restrict__ deg, int n,
                                               int* __restrict__ row_ptr,
                                               int* __restrict__ cursor) {
    __shared__ int wsum[16];
    __shared__ int carry;
    int tid = threadIdx.x;
    int lane = tid & 63;
    int wid = tid >> 6;
    if (tid == 0) carry = 0;
    __syncthreads();
    int n4 = (n + 3) >> 2;
    for (int base = 0; base < n4; base += 1024) {
        int i4 = base + tid;
        int4 v = make_int4(0, 0, 0, 0);
        if (i4 < n4) v = ((const int4*)deg)[i4];
        int s = v.x + v.y + v.z + v.w;
        int x = s;
#pragma unroll
        for (int off = 1; off < 64; off <<= 1) {
            int y = __shfl_up(x, off, 64);
            if (lane >= off) x += y;
        }
        if (lane == 63) wsum[wid] = x;
        __syncthreads();
        if (wid == 0 && lane < 16) {
            int w = wsum[lane];
#pragma unroll
            for (int off = 1; off < 16; off <<= 1) {
                int y = __shfl_up(w, off, 16);
                if (lane >= off) w += y;
            }
            wsum[lane] = w;
        }
        __syncthreads();
        int excl = x - s + carry + (wid > 0 ? wsum[wid - 1] : 0);
        if (i4 < n4) {
            int e0 = excl, e1 = e0 + v.x, e2 = e1 + v.y, e3 = e2 + v.z;
            int4 o = make_int4(e0, e1, e2, e3);
            ((int4*)row_ptr)[i4] = o;
            ((int4*)cursor)[i4] = o;
        }
        __syncthreads();
        if (tid == 0) carry += wsum[15];
        __syncthreads();
    }
    if (tid == 0) row_ptr[n] = carry;
}

__global__ void k_build_csr(const int* __restrict__ src, const int* __restrict__ dst,
                            int ne, int* __restrict__ cursor, int* __restrict__ eidx) {
    int i = blockIdx.x * blockDim.x + threadIdx.x;
    if (i < ne) {
        int p = atomicAdd(&cursor[dst[i]], 1);
        eidx[p] = src[i];
    }
}

// ---------------------------------------------------------------------------
// bf16 split helpers (MFMA path)
// ---------------------------------------------------------------------------

__global__ __launch_bounds__(256) void k_split_x(const float* __restrict__ x,
                                                 const float* __restrict__ onrm,
                                                 unsigned short* __restrict__ Ah,
                                                 unsigned short* __restrict__ Al, int n) {
    int i4 = blockIdx.x * blockDim.x + threadIdx.x;  // float4 index, 64 per row
    int row = i4 >> 6;
    if (row >= n) return;
    float4 v = ((const float4*)x)[i4];
    float s = onrm[row];
    unsigned short h0, l0, h1, l1, h2, l2, h3, l3;
    split_bf16(v.x * s, h0, l0);
    split_bf16(v.y * s, h1, l1);
    split_bf16(v.z * s, h2, l2);
    split_bf16(v.w * s, h3, l3);
    ushort4 hv, lv;
    hv.x = h0; hv.y = h1; hv.z = h2; hv.w = h3;
    lv.x = l0; lv.y = l1; lv.z = l2; lv.w = l3;
    ((ushort4*)Ah)[i4] = hv;
    ((ushort4*)Al)[i4] = lv;
}

__global__ void k_split_w_all(const float* __restrict__ W0, const float* __restrict__ W1,
                              const float* __restrict__ W2, const float* __restrict__ W3,
                              unsigned short* __restrict__ Wh0, unsigned short* __restrict__ Wl0,
                              unsigned short* __restrict__ Wh1, unsigned short* __restrict__ Wl1,
                              unsigned short* __restrict__ Wh2, unsigned short* __restrict__ Wl2,
                              unsigned short* __restrict__ Wh3, unsigned short* __restrict__ Wl3) {
    int i = blockIdx.x * blockDim.x + threadIdx.x;
    const float* W; unsigned short *Wh, *Wl; int K, F, off;
    if (i < 32768)                    { W = W0; Wh = Wh0; Wl = Wl0; K = 256; F = 128; off = i; }
    else if (i < 32768 + 16384)       { W = W1; Wh = Wh1; Wl = Wl1; K = 128; F = 128; off = i - 32768; }
    else if (i < 32768 + 32768)       { W = W2; Wh = Wh2; Wl = Wl2; K = 128; F = 128; off = i - 49152; }
    else if (i < 32768 + 32768 + 8192){ W = W3; Wh = Wh3; Wl = Wl3; K = 128; F = 64;  off = i - 65536; }
    else return;
    int k = off / F, c = off % F;
    unsigned short h, l;
    split_bf16(W[k * F + c], h, l);
    Wh[c * K + k] = h;
    Wl[c * K + k] = l;
}

// ---------------------------------------------------------------------------
// MFMA GEMM: H[m][c] = sum_k A[m][k]*W[k][c]; H stored fp16.
// Block = 256 threads / 4 waves = 128 rows; wave = 2 m-tiles x all N cols.
// B (hi+lo, transposed [c][k]) staged in LDS per 128-wide K-tile,
// XOR-swizzled in short8 granules (2-way bank conflict max = free).
// ---------------------------------------------------------------------------
template <int K, int N>
__global__ __launch_bounds__(256) void k_mm(const unsigned short* __restrict__ Ah,
                                            const unsigned short* __restrict__ Al,
                                            const unsigned short* __restrict__ Bh,
                                            const unsigned short* __restrict__ Bl,
                                            __half* __restrict__ H, int n) {
    constexpr int KT = 128;          // K tile staged in LDS
    constexpr int NT = N / 16;       // MFMA col tiles
    constexpr int NKT = K / KT;      // K tiles
    __shared__ unsigned short sBh[N * KT];
    __shared__ unsigned short sBl[N * KT];

    int tid = threadIdx.x;
    int w = tid >> 6, lane = tid & 63;
    int quad = lane >> 4, l16 = lane & 15;
    int row_base = blockIdx.x * 128 + w * 32;

    int ar0 = row_base + l16;
    int ar1 = row_base + 16 + l16;
    if (ar0 >= n) ar0 = n - 1;
    if (ar1 >= n) ar1 = n - 1;

    f32x4 acc[2][NT];
#pragma unroll
    for (int m = 0; m < 2; ++m)
#pragma unroll
        for (int t = 0; t < NT; ++t) acc[m][t] = (f32x4){0.f, 0.f, 0.f, 0.f};

    for (int kt = 0; kt < NKT; ++kt) {
        if (kt) __syncthreads();
        // stage B k-tile: N cols x 16 granules of short8
        for (int idx = tid; idx < N * 16; idx += 256) {
            int c = idx >> 4;
            int g = idx & 15;
            short8 vh = *(const short8*)(Bh + (size_t)c * K + kt * KT + g * 8);
            short8 vl = *(const short8*)(Bl + (size_t)c * K + kt * KT + g * 8);
            int sg = g ^ (c & 15);
            *(short8*)(&sBh[c * KT + sg * 8]) = vh;
            *(short8*)(&sBl[c * KT + sg * 8]) = vl;
        }
        __syncthreads();

        const unsigned short* a0h = Ah + (size_t)ar0 * K + kt * KT;
        const unsigned short* a0l = Al + (size_t)ar0 * K + kt * KT;
        const unsigned short* a1h = Ah + (size_t)ar1 * K + kt * KT;
        const unsigned short* a1l = Al + (size_t)ar1 * K + kt * KT;

#pragma unroll
        for (int k0 = 0; k0 < KT; k0 += 32) {
            int eoff = k0 + quad * 8;
            short8 a0hv = *(const short8*)(a0h + eoff);
            short8 a0lv = *(const short8*)(a0l + eoff);
            short8 a1hv = *(const short8*)(a1h + eoff);
            short8 a1lv = *(const short8*)(a1l + eoff);
            int g = (k0 >> 3) + quad;
            int sg8 = (g ^ l16) * 8;
#pragma unroll
            for (int t = 0; t < NT; ++t) {
                int cb = (t * 16 + l16) * KT;
                short8 bh = *(const short8*)(&sBh[cb + sg8]);
                short8 bl = *(const short8*)(&sBl[cb + sg8]);
                acc[0][t] = __builtin_amdgcn_mfma_f32_16x16x32_bf16(a0hv, bh, acc[0][t], 0, 0, 0);
                acc[0][t] = __builtin_amdgcn_mfma_f32_16x16x32_bf16(a0lv, bh, acc[0][t], 0, 0, 0);
                acc[0][t] = __builtin_amdgcn_mfma_f32_16x16x32_bf16(a0hv, bl, acc[0][t], 0, 0, 0);
                acc[1][t] = __builtin_amdgcn_mfma_f32_16x16x32_bf16(a1hv, bh, acc[1][t], 0, 0, 0);
                acc[1][t] = __builtin_amdgcn_mfma_f32_16x16x32_bf16(a1lv, bh, acc[1][t], 0, 0, 0);
                acc[1][t] = __builtin_amdgcn_mfma_f32_16x16x32_bf16(a1hv, bl, acc[1][t], 0, 0, 0);
            }
        }
    }

#pragma unroll
    for (int m = 0; m < 2; ++m) {
#pragma unroll
        for (int t = 0; t < NT; ++t) {
#pragma unroll
            for (int r = 0; r < 4; ++r) {
                int grow = row_base + m * 16 + quad * 4 + r;
                if (grow < n) H[(size_t)grow * N + t * 16 + l16] = __float2half(acc[m][t][r]);
            }
        }
    }
}

// ---------------------------------------------------------------------------
// Aggregation: wave per node, fp16 h, x4-unrolled gather, fp32 accumulate.
// ---------------------------------------------------------------------------

// FO=128: epilogue relu(agg*inrm + b) * onrm -> bf16 hi/lo split.
__global__ __launch_bounds__(256) void k_agg128_split(const __half* __restrict__ h,
                                                      const int* __restrict__ row_ptr,
                                                      const int* __restrict__ eidx,
                                                      const float* __restrict__ inrm,
                                                      const float* __restrict__ onrm,
                                                      const float* __restrict__ bias,
                                                      unsigned short* __restrict__ Ah,
                                                      unsigned short* __restrict__ Al, int n) {
    int node = blockIdx.x * 4 + (threadIdx.x >> 6);
    int lane = threadIdx.x & 63;
    if (node >= n) return;
    int beg = row_ptr[node], end = row_ptr[node + 1];
    const __half2* h2 = (const __half2*)h;

    float ax0 = 0.f, ay0 = 0.f, ax1 = 0.f, ay1 = 0.f;
    float ax2 = 0.f, ay2 = 0.f, ax3 = 0.f, ay3 = 0.f;
    int j = beg;
    for (; j + 4 <= end; j += 4) {
        int s0 = eidx[j], s1 = eidx[j + 1], s2 = eidx[j + 2], s3 = eidx[j + 3];
        __half2 v0 = h2[(size_t)s0 * 64 + lane];
        __half2 v1 = h2[(size_t)s1 * 64 + lane];
        __half2 v2 = h2[(size_t)s2 * 64 + lane];
        __half2 v3 = h2[(size_t)s3 * 64 + lane];
        float2 f0 = __half22float2(v0), f1 = __half22float2(v1);
        float2 f2 = __half22float2(v2), f3 = __half22float2(v3);
        ax0 += f0.x; ay0 += f0.y;
        ax1 += f1.x; ay1 += f1.y;
        ax2 += f2.x; ay2 += f2.y;
        ax3 += f3.x; ay3 += f3.y;
    }
    for (; j < end; ++j) {
        float2 f = __half22float2(h2[(size_t)eidx[j] * 64 + lane]);
        ax0 += f.x; ay0 += f.y;
    }
    float ax = (ax0 + ax1) + (ax2 + ax3);
    float ay = (ay0 + ay1) + (ay2 + ay3);

    float nrm = inrm[node];
    float on = onrm[node];
    float2 b2 = ((const float2*)bias)[lane];
    float ox = fmaxf(ax * nrm + b2.x, 0.f) * on;
    float oy = fmaxf(ay * nrm + b2.y, 0.f) * on;
    unsigned short hx, lx, hy, ly;
    split_bf16(ox, hx, lx);
    split_bf16(oy, hy, ly);
    ushort2 hv, lv;
    hv.x = hx; hv.y = hy;
    lv.x = lx; lv.y = ly;
    ((ushort2*)Ah)[(size_t)node * 64 + lane] = hv;
    ((ushort2*)Al)[(size_t)node * 64 + lane] = lv;
}

// FO=64 final layer: fp16 h, fp32 out to d_out.
__global__ __launch_bounds__(256) void k_agg64(const __half* __restrict__ h,
                                               const int* __restrict__ row_ptr,
                                               const int* __restrict__ eidx,
                                               const float* __restrict__ inrm,
                                               const float* __restrict__ bias,
                                               float* __restrict__ out, int n) {
    int node = blockIdx.x * 4 + (threadIdx.x >> 6);
    int lane = threadIdx.x & 63;
    if (node >= n) return;
    int beg = row_ptr[node], end = row_ptr[node + 1];
    float a0 = 0.f, a1 = 0.f, a2 = 0.f, a3 = 0.f;
    int j = beg;
    for (; j + 4 <= end; j += 4) {
        int s0 = eidx[j], s1 = eidx[j + 1], s2 = eidx[j + 2], s3 = eidx[j + 3];
        float v0 = __half2float(h[(size_t)s0 * 64 + lane]);
        float v1 = __half2float(h[(size_t)s1 * 64 + lane]);
        float v2 = __half2float(h[(size_t)s2 * 64 + lane]);
        float v3 = __half2float(h[(size_t)s3 * 64 + lane]);
        a0 += v0; a1 += v1; a2 += v2; a3 += v3;
    }
    for (; j < end; ++j) a0 += __half2float(h[(size_t)eidx[j] * 64 + lane]);
    float acc = (a0 + a1) + (a2 + a3);
    out[(size_t)node * 64 + lane] = acc * inrm[node] + bias[lane];
}

// ---------------------------------------------------------------------------
// Fallback fp32 path (round-1, known-good)
// ---------------------------------------------------------------------------
template <int K, int FO, int TX, int TY, int RPT>
__global__ __launch_bounds__(256) void k_matmul(const float* __restrict__ X,
                                                const float* __restrict__ W,
                                                const float* __restrict__ onrm,
                                                float* __restrict__ H, int n) {
    constexpr int BROWS = TY * RPT;
    constexpr int LDK = K + 1;
    __shared__ float xs[BROWS * LDK];
    int tx = threadIdx.x, ty = threadIdx.y;
    int tid = ty * TX + tx;
    int row0 = blockIdx.x * BROWS;

    for (int idx = tid; idx < BROWS * K; idx += 256) {
        int r = idx / K;
        int k = idx - r * K;
        int row = row0 + r;
        xs[r * LDK + k] = (row < n) ? X[(size_t)row * K + k] : 0.f;
    }
    __syncthreads();

    float4 acc[RPT];
#pragma unroll
    for (int r = 0; r < RPT; ++r) acc[r] = make_float4(0.f, 0.f, 0.f, 0.f);

    const float4* W4 = (const float4*)W;
#pragma unroll 4
    for (int k = 0; k < K; ++k) {
        float4 w = W4[k * (FO / 4) + tx];
#pragma unroll
        for (int r = 0; r < RPT; ++r) {
            float xv = xs[(ty * RPT + r) * LDK + k];
            acc[r].x += xv * w.x;
            acc[r].y += xv * w.y;
            acc[r].z += xv * w.z;
            acc[r].w += xv * w.w;
        }
    }

#pragma unroll
    for (int r = 0; r < RPT; ++r) {
        int row = row0 + ty * RPT + r;
        if (row < n) {
            float s = onrm[row];
            float4 o = make_float4(acc[r].x * s, acc[r].y * s, acc[r].z * s, acc[r].w * s);
            ((float4*)H)[(size_t)row * (FO / 4) + tx] = o;
        }
    }
}

__global__ __launch_bounds__(256) void k_agg128f(const float* __restrict__ h,
                                                 const int* __restrict__ row_ptr,
                                                 const int* __restrict__ eidx,
                                                 const float* __restrict__ inrm,
                                                 const float* __restrict__ bias,
                                                 float* __restrict__ out, int n, int relu) {
    int node = blockIdx.x * 4 + (threadIdx.x >> 6);
    int lane = threadIdx.x & 63;
    if (node >= n) return;
    int beg = row_ptr[node], end = row_ptr[node + 1];
    const float2* h2 = (const float2*)h;
    float ax = 0.f, ay = 0.f;
    for (int j = beg; j < end; ++j) {
        int s = eidx[j];
        float2 v = h2[(size_t)s * 64 + lane];
        ax += v.x;
        ay += v.y;
    }
    float nrm = inrm[node];
    float2 b2 = ((const float2*)bias)[lane];
    float ox = ax * nrm + b2.x;
    float oy = ay * nrm + b2.y;
    if (relu) { ox = fmaxf(ox, 0.f); oy = fmaxf(oy, 0.f); }
    float2 o; o.x = ox; o.y = oy;
    ((float2*)out)[(size_t)node * 64 + lane] = o;
}

__global__ __launch_bounds__(256) void k_agg64f(const float* __restrict__ h,
                                                const int* __restrict__ row_ptr,
                                                const int* __restrict__ eidx,
                                                const float* __restrict__ inrm,
                                                const float* __restrict__ bias,
                                                float* __restrict__ out, int n) {
    int node = blockIdx.x * 4 + (threadIdx.x >> 6);
    int lane = threadIdx.x & 63;
    if (node >= n) return;
    int beg = row_ptr[node], end = row_ptr[node + 1];
    float acc = 0.f;
    for (int j = beg; j < end; ++j) {
        int s = eidx[j];
        acc += h[(size_t)s * 64 + lane];
    }
    out[(size_t)node * 64 + lane] = acc * inrm[node] + bias[lane];
}

static inline size_t align_up(size_t v, size_t a) { return (v + a - 1) & ~(a - 1); }

extern "C" void kernel_launch(void* const* d_in, const int* in_sizes, int n_in,
                              void* d_out, int out_size, void* d_ws, size_t ws_size,
                              hipStream_t stream) {
    const float* x  = (const float*)d_in[0];
    const int* ei   = (const int*)d_in[1];
    const float* W0 = (const float*)d_in[2];
    const float* b0 = (const float*)d_in[3];
    const float* W1 = (const float*)d_in[4];
    const float* b1 = (const float*)d_in[5];
    const float* W2 = (const float*)d_in[6];
    const float* b2 = (const float*)d_in[7];
    const float* W3 = (const float*)d_in[8];
    const float* b3 = (const float*)d_in[9];

    const int n  = in_sizes[0] / 256;   // 50000
    const int ne = in_sizes[1] / 2;     // 800000
    const int n_pad = (n + 127) & ~127;
    const int* src = ei;
    const int* dst = ei + ne;

    // ---- shared preprocessing layout ----
    char* ws = (char*)d_ws;
    size_t off = 0;
    auto take = [&](size_t bytes) { void* p = ws + off; off = align_up(off + bytes, 256); return p; };
    int* deg_s   = (int*)take((size_t)n_pad * 4);
    int* deg_d   = (int*)take((size_t)n_pad * 4);
    int* row_ptr = (int*)take((size_t)(n_pad + 4) * 4);
    int* cursor  = (int*)take((size_t)n_pad * 4);
    int* eidx    = (int*)take((size_t)ne * 4);
    float* onrm  = (float*)take((size_t)n * 4);
    float* inrm  = (float*)take((size_t)n * 4);

    // ---- MFMA-path layout ----
    size_t off_save = off;
    unsigned short* Ah  = (unsigned short*)take((size_t)n_pad * 256 * 2);
    unsigned short* Al  = (unsigned short*)take((size_t)n_pad * 256 * 2);
    __half* hbuf        = (__half*)take((size_t)n * 128 * 2);
    unsigned short* Wh0 = (unsigned short*)take(256 * 128 * 2);
    unsigned short* Wl0 = (unsigned short*)take(256 * 128 * 2);
    unsigned short* Wh1 = (unsigned short*)take(128 * 128 * 2);
    unsigned short* Wl1 = (unsigned short*)take(128 * 128 * 2);
    unsigned short* Wh2 = (unsigned short*)take(128 * 128 * 2);
    unsigned short* Wl2 = (unsigned short*)take(128 * 128 * 2);
    unsigned short* Wh3 = (unsigned short*)take(128 * 64 * 2);
    unsigned short* Wl3 = (unsigned short*)take(128 * 64 * 2);
    bool use_mfma = (off <= ws_size);

    // ---- preprocessing (both paths) ----
    hipMemsetAsync(deg_s, 0, (size_t)n_pad * 4, stream);
    hipMemsetAsync(deg_d, 0, (size_t)n_pad * 4, stream);
    k_degrees<<<(ne + 255) / 256, 256, 0, stream>>>(src, dst, ne, deg_s, deg_d);
    k_norms<<<(n + 255) / 256, 256, 0, stream>>>(deg_s, deg_d, onrm, inrm, n);
    k_scan<<<1, 1024, 0, stream>>>(deg_d, n, row_ptr, cursor);
    k_build_csr<<<(ne + 255) / 256, 256, 0, stream>>>(src, dst, ne, cursor, eidx);

    const int aggGrid = (n + 3) / 4;

    if (use_mfma) {
        k_split_w_all<<<(73728 + 255) / 256, 256, 0, stream>>>(
            W0, W1, W2, W3, Wh0, Wl0, Wh1, Wl1, Wh2, Wl2, Wh3, Wl3);
        k_split_x<<<((n * 64) + 255) / 256, 256, 0, stream>>>(x, onrm, Ah, Al, n);

        const int mmGrid = n_pad / 128;
        // L0: 256 -> 128
        k_mm<256, 128><<<mmGrid, 256, 0, stream>>>(Ah, Al, Wh0, Wl0, hbuf, n);
        k_agg128_split<<<aggGrid, 256, 0, stream>>>(hbuf, row_ptr, eidx, inrm, onrm, b0, Ah, Al, n);
        // L1
        k_mm<128, 128><<<mmGrid, 256, 0, stream>>>(Ah, Al, Wh1, Wl1, hbuf, n);
        k_agg128_split<<<aggGrid, 256, 0, stream>>>(hbuf, row_ptr, eidx, inrm, onrm, b1, Ah, Al, n);
        // L2
        k_mm<128, 128><<<mmGrid, 256, 0, stream>>>(Ah, Al, Wh2, Wl2, hbuf, n);
        k_agg128_split<<<aggGrid, 256, 0, stream>>>(hbuf, row_ptr, eidx, inrm, onrm, b2, Ah, Al, n);
        // L3: 128 -> 64
        k_mm<128, 64><<<mmGrid, 256, 0, stream>>>(Ah, Al, Wh3, Wl3, hbuf, n);
        k_agg64<<<aggGrid, 256, 0, stream>>>(hbuf, row_ptr, eidx, inrm, b3, (float*)d_out, n);
    } else {
        // fp32 fallback (round-1 structure)
        off = off_save;
        float* hbufF  = (float*)take((size_t)n * 128 * 4);
        float* xnextF = (float*)take((size_t)n * 128 * 4);

        k_matmul<256, 128, 32, 8, 4><<<(n + 31) / 32, dim3(32, 8), 0, stream>>>(x, W0, onrm, hbufF, n);
        k_agg128f<<<aggGrid, 256, 0, stream>>>(hbufF, row_ptr, eidx, inrm, b0, xnextF, n, 1);
        k_matmul<128, 128, 32, 8, 4><<<(n + 31) / 32, dim3(32, 8), 0, stream>>>(xnextF, W1, onrm, hbufF, n);
        k_agg128f<<<aggGrid, 256, 0, stream>>>(hbufF, row_ptr, eidx, inrm, b1, xnextF, n, 1);
        k_matmul<128, 128, 32, 8, 4><<<(n + 31) / 32, dim3(32, 8), 0, stream>>>(xnextF, W2, onrm, hbufF, n);
        k_agg128f<<<aggGrid, 256, 0, stream>>>(hbufF, row_ptr, eidx, inrm, b2, xnextF, n, 1);
        k_matmul<128, 64, 16, 16, 4><<<(n + 63) / 64, dim3(16, 16), 0, stream>>>(xnextF, W3, onrm, hbufF, n);
        k_agg64f<<<aggGrid, 256, 0, stream>>>(hbufF, row_ptr, eidx, inrm, b3, (float*)d_out, n);
    }
}

// Round 5
// 450.547 us; speedup vs baseline: 1.7709x; 1.0170x over previous
//
#include <hip/hip_runtime.h>
#include <hip/hip_fp16.h>

// ---------------------------------------------------------------------------
// GCN 4-layer forward on MI355X (gfx950).
//   Preprocess: XCD-partitioned (8-copy) degree histograms -> fused reduce+norms
//               -> scan -> per-copy cursors -> CSR build (copy-local atomics).
//   Per layer : bf16-split MFMA GEMM (3-term, ~fp32 precision), B staged in
//               LDS (XOR-swizzled) -> h in fp16
//               -> wave-per-node CSR gather-sum (x4 unrolled, fp32 accum),
//                  epilogue fused: *in_norm + bias, relu, *out_norm,
//                  bf16 hi/lo split for next layer's MFMA A operand.
// ---------------------------------------------------------------------------

typedef __attribute__((ext_vector_type(8))) short short8;
typedef __attribute__((ext_vector_type(4))) float f32x4;

__device__ inline unsigned short bf16_rne(float v) {
    union { float f; unsigned u; } c; c.f = v;
    unsigned u = c.u;
    unsigned lsb = (u >> 16) & 1u;
    u += 0x7fffu + lsb;
    return (unsigned short)(u >> 16);
}
__device__ inline float bf16_to_f(unsigned short h) {
    union { unsigned u; float f; } c; c.u = ((unsigned)h) << 16;
    return c.f;
}
__device__ inline void split_bf16(float v, unsigned short& hi, unsigned short& lo) {
    hi = bf16_rne(v);
    lo = bf16_rne(v - bf16_to_f(hi));
}

// ---------------------------------------------------------------------------
// Preprocessing — 8-copy histograms so atomics stay XCD(L2)-local.
// Block->copy mapping (blockIdx & 7) MUST be identical in k_degrees8 and
// k_build_csr8 (same grid shape) so per-copy counts match per-copy cursors.
// ---------------------------------------------------------------------------

__global__ void k_degrees8(const int* __restrict__ src, const int* __restrict__ dst,
                           int ne, int np,
                           int* __restrict__ degs_part, int* __restrict__ degd_part) {
    int i = blockIdx.x * blockDim.x + threadIdx.x;
    int c = blockIdx.x & 7;
    if (i < ne) {
        atomicAdd(&degs_part[c * np + src[i]], 1);
        atomicAdd(&degd_part[c * np + dst[i]], 1);
    }
}

// Reduce 8 partials -> norms + summed dst-degree (for the scan).
__global__ void k_norms_reduce(const int* __restrict__ degs_part,
                               const int* __restrict__ degd_part, int np, int n,
                               float* __restrict__ onrm, float* __restrict__ inrm,
                               int* __restrict__ degd_sum) {
    int i = blockIdx.x * blockDim.x + threadIdx.x;
    if (i >= np) return;
    int ds = 0, dd = 0;
#pragma unroll
    for (int c = 0; c < 8; ++c) {
        ds += degs_part[c * np + i];
        dd += degd_part[c * np + i];
    }
    degd_sum[i] = dd;   // zero beyond n (partials untouched there)
    if (i < n) {
        onrm[i] = rsqrtf((float)max(ds, 1));
        inrm[i] = rsqrtf((float)max(dd, 1));
    }
}

// Single-block exclusive scan, int4 per thread.
__global__ __launch_bounds__(1024) void k_scan(const int* __restrict__ deg, int n,
                                               int* __restrict__ row_ptr) {
    __shared__ int wsum[16];
    __shared__ int carry;
    int tid = threadIdx.x;
    int lane = tid & 63;
    int wid = tid >> 6;
    if (tid == 0) carry = 0;
    __syncthreads();
    int n4 = (n + 3) >> 2;
    for (int base = 0; base < n4; base += 1024) {
        int i4 = base + tid;
        int4 v = make_int4(0, 0, 0, 0);
        if (i4 < n4) v = ((const int4*)deg)[i4];
        int s = v.x + v.y + v.z + v.w;
        int x = s;
#pragma unroll
        for (int off = 1; off < 64; off <<= 1) {
            int y = __shfl_up(x, off, 64);
            if (lane >= off) x += y;
        }
        if (lane == 63) wsum[wid] = x;
        __syncthreads();
        if (wid == 0 && lane < 16) {
            int w = wsum[lane];
#pragma unroll
            for (int off = 1; off < 16; off <<= 1) {
                int y = __shfl_up(w, off, 16);
                if (lane >= off) w += y;
            }
            wsum[lane] = w;
        }
        __syncthreads();
        int excl = x - s + carry + (wid > 0 ? wsum[wid - 1] : 0);
        if (i4 < n4) {
            int e0 = excl, e1 = e0 + v.x, e2 = e1 + v.y, e3 = e2 + v.z;
            ((int4*)row_ptr)[i4] = make_int4(e0, e1, e2, e3);
        }
        __syncthreads();
        if (tid == 0) carry += wsum[15];
        __syncthreads();
    }
    if (tid == 0) row_ptr[n] = carry;
}

// Per-copy cursor bases: cursor[c][v] = row_ptr[v] + sum_{c'<c} count[c'][v].
__global__ void k_cursors(const int* __restrict__ row_ptr,
                          const int* __restrict__ degd_part, int np, int n,
                          int* __restrict__ cursor_part) {
    int i = blockIdx.x * blockDim.x + threadIdx.x;
    if (i >= n) return;
    int run = row_ptr[i];
#pragma unroll
    for (int c = 0; c < 8; ++c) {
        cursor_part[c * np + i] = run;
        run += degd_part[c * np + i];
    }
}

__global__ void k_build_csr8(const int* __restrict__ src, const int* __restrict__ dst,
                             int ne, int np,
                             int* __restrict__ cursor_part, int* __restrict__ eidx) {
    int i = blockIdx.x * blockDim.x + threadIdx.x;
    int c = blockIdx.x & 7;
    if (i < ne) {
        int p = atomicAdd(&cursor_part[c * np + dst[i]], 1);
        eidx[p] = src[i];
    }
}

// ---------------------------------------------------------------------------
// bf16 split helpers (MFMA path)
// ---------------------------------------------------------------------------

__global__ __launch_bounds__(256) void k_split_x(const float* __restrict__ x,
                                                 const float* __restrict__ onrm,
                                                 unsigned short* __restrict__ Ah,
                                                 unsigned short* __restrict__ Al, int n) {
    int i4 = blockIdx.x * blockDim.x + threadIdx.x;  // float4 index, 64 per row
    int row = i4 >> 6;
    if (row >= n) return;
    float4 v = ((const float4*)x)[i4];
    float s = onrm[row];
    unsigned short h0, l0, h1, l1, h2, l2, h3, l3;
    split_bf16(v.x * s, h0, l0);
    split_bf16(v.y * s, h1, l1);
    split_bf16(v.z * s, h2, l2);
    split_bf16(v.w * s, h3, l3);
    ushort4 hv, lv;
    hv.x = h0; hv.y = h1; hv.z = h2; hv.w = h3;
    lv.x = l0; lv.y = l1; lv.z = l2; lv.w = l3;
    ((ushort4*)Ah)[i4] = hv;
    ((ushort4*)Al)[i4] = lv;
}

__global__ void k_split_w_all(const float* __restrict__ W0, const float* __restrict__ W1,
                              const float* __restrict__ W2, const float* __restrict__ W3,
                              unsigned short* __restrict__ Wh0, unsigned short* __restrict__ Wl0,
                              unsigned short* __restrict__ Wh1, unsigned short* __restrict__ Wl1,
                              unsigned short* __restrict__ Wh2, unsigned short* __restrict__ Wl2,
                              unsigned short* __restrict__ Wh3, unsigned short* __restrict__ Wl3) {
    int i = blockIdx.x * blockDim.x + threadIdx.x;
    const float* W; unsigned short *Wh, *Wl; int K, F, off;
    if (i < 32768)                    { W = W0; Wh = Wh0; Wl = Wl0; K = 256; F = 128; off = i; }
    else if (i < 32768 + 16384)       { W = W1; Wh = Wh1; Wl = Wl1; K = 128; F = 128; off = i - 32768; }
    else if (i < 32768 + 32768)       { W = W2; Wh = Wh2; Wl = Wl2; K = 128; F = 128; off = i - 49152; }
    else if (i < 32768 + 32768 + 8192){ W = W3; Wh = Wh3; Wl = Wl3; K = 128; F = 64;  off = i - 65536; }
    else return;
    int k = off / F, c = off % F;
    unsigned short h, l;
    split_bf16(W[k * F + c], h, l);
    Wh[c * K + k] = h;
    Wl[c * K + k] = l;
}

// ---------------------------------------------------------------------------
// MFMA GEMM: H[m][c] = sum_k A[m][k]*W[k][c]; H stored fp16.
// Block = 256 threads / 4 waves = 128 rows; wave = 2 m-tiles x all N cols.
// B (hi+lo, transposed [c][k]) staged in LDS per 128-wide K-tile,
// XOR-swizzled in short8 granules (2-way bank conflict max = free).
// ---------------------------------------------------------------------------
template <int K, int N>
__global__ __launch_bounds__(256) void k_mm(const unsigned short* __restrict__ Ah,
                                            const unsigned short* __restrict__ Al,
                                            const unsigned short* __restrict__ Bh,
                                            const unsigned short* __restrict__ Bl,
                                            __half* __restrict__ H, int n) {
    constexpr int KT = 128;
    constexpr int NT = N / 16;
    constexpr int NKT = K / KT;
    __shared__ unsigned short sBh[N * KT];
    __shared__ unsigned short sBl[N * KT];

    int tid = threadIdx.x;
    int w = tid >> 6, lane = tid & 63;
    int quad = lane >> 4, l16 = lane & 15;
    int row_base = blockIdx.x * 128 + w * 32;

    int ar0 = row_base + l16;
    int ar1 = row_base + 16 + l16;
    if (ar0 >= n) ar0 = n - 1;
    if (ar1 >= n) ar1 = n - 1;

    f32x4 acc[2][NT];
#pragma unroll
    for (int m = 0; m < 2; ++m)
#pragma unroll
        for (int t = 0; t < NT; ++t) acc[m][t] = (f32x4){0.f, 0.f, 0.f, 0.f};

    for (int kt = 0; kt < NKT; ++kt) {
        if (kt) __syncthreads();
        for (int idx = tid; idx < N * 16; idx += 256) {
            int c = idx >> 4;
            int g = idx & 15;
            short8 vh = *(const short8*)(Bh + (size_t)c * K + kt * KT + g * 8);
            short8 vl = *(const short8*)(Bl + (size_t)c * K + kt * KT + g * 8);
            int sg = g ^ (c & 15);
            *(short8*)(&sBh[c * KT + sg * 8]) = vh;
            *(short8*)(&sBl[c * KT + sg * 8]) = vl;
        }
        __syncthreads();

        const unsigned short* a0h = Ah + (size_t)ar0 * K + kt * KT;
        const unsigned short* a0l = Al + (size_t)ar0 * K + kt * KT;
        const unsigned short* a1h = Ah + (size_t)ar1 * K + kt * KT;
        const unsigned short* a1l = Al + (size_t)ar1 * K + kt * KT;

#pragma unroll
        for (int k0 = 0; k0 < KT; k0 += 32) {
            int eoff = k0 + quad * 8;
            short8 a0hv = *(const short8*)(a0h + eoff);
            short8 a0lv = *(const short8*)(a0l + eoff);
            short8 a1hv = *(const short8*)(a1h + eoff);
            short8 a1lv = *(const short8*)(a1l + eoff);
            int g = (k0 >> 3) + quad;
            int sg8 = (g ^ l16) * 8;
#pragma unroll
            for (int t = 0; t < NT; ++t) {
                int cb = (t * 16 + l16) * KT;
                short8 bh = *(const short8*)(&sBh[cb + sg8]);
                short8 bl = *(const short8*)(&sBl[cb + sg8]);
                acc[0][t] = __builtin_amdgcn_mfma_f32_16x16x32_bf16(a0hv, bh, acc[0][t], 0, 0, 0);
                acc[0][t] = __builtin_amdgcn_mfma_f32_16x16x32_bf16(a0lv, bh, acc[0][t], 0, 0, 0);
                acc[0][t] = __builtin_amdgcn_mfma_f32_16x16x32_bf16(a0hv, bl, acc[0][t], 0, 0, 0);
                acc[1][t] = __builtin_amdgcn_mfma_f32_16x16x32_bf16(a1hv, bh, acc[1][t], 0, 0, 0);
                acc[1][t] = __builtin_amdgcn_mfma_f32_16x16x32_bf16(a1lv, bh, acc[1][t], 0, 0, 0);
                acc[1][t] = __builtin_amdgcn_mfma_f32_16x16x32_bf16(a1hv, bl, acc[1][t], 0, 0, 0);
            }
        }
    }

#pragma unroll
    for (int m = 0; m < 2; ++m) {
#pragma unroll
        for (int t = 0; t < NT; ++t) {
#pragma unroll
            for (int r = 0; r < 4; ++r) {
                int grow = row_base + m * 16 + quad * 4 + r;
                if (grow < n) H[(size_t)grow * N + t * 16 + l16] = __float2half(acc[m][t][r]);
            }
        }
    }
}

// ---------------------------------------------------------------------------
// Aggregation: wave per node, fp16 h, x4-unrolled gather, fp32 accumulate.
// ---------------------------------------------------------------------------

__global__ __launch_bounds__(256) void k_agg128_split(const __half* __restrict__ h,
                                                      const int* __restrict__ row_ptr,
                                                      const int* __restrict__ eidx,
                                                      const float* __restrict__ inrm,
                                                      const float* __restrict__ onrm,
                                                      const float* __restrict__ bias,
                                                      unsigned short* __restrict__ Ah,
                                                      unsigned short* __restrict__ Al, int n) {
    int node = blockIdx.x * 4 + (threadIdx.x >> 6);
    int lane = threadIdx.x & 63;
    if (node >= n) return;
    int beg = row_ptr[node], end = row_ptr[node + 1];
    const __half2* h2 = (const __half2*)h;

    float ax0 = 0.f, ay0 = 0.f, ax1 = 0.f, ay1 = 0.f;
    float ax2 = 0.f, ay2 = 0.f, ax3 = 0.f, ay3 = 0.f;
    int j = beg;
    for (; j + 4 <= end; j += 4) {
        int s0 = eidx[j], s1 = eidx[j + 1], s2 = eidx[j + 2], s3 = eidx[j + 3];
        __half2 v0 = h2[(size_t)s0 * 64 + lane];
        __half2 v1 = h2[(size_t)s1 * 64 + lane];
        __half2 v2 = h2[(size_t)s2 * 64 + lane];
        __half2 v3 = h2[(size_t)s3 * 64 + lane];
        float2 f0 = __half22float2(v0), f1 = __half22float2(v1);
        float2 f2 = __half22float2(v2), f3 = __half22float2(v3);
        ax0 += f0.x; ay0 += f0.y;
        ax1 += f1.x; ay1 += f1.y;
        ax2 += f2.x; ay2 += f2.y;
        ax3 += f3.x; ay3 += f3.y;
    }
    for (; j < end; ++j) {
        float2 f = __half22float2(h2[(size_t)eidx[j] * 64 + lane]);
        ax0 += f.x; ay0 += f.y;
    }
    float ax = (ax0 + ax1) + (ax2 + ax3);
    float ay = (ay0 + ay1) + (ay2 + ay3);

    float nrm = inrm[node];
    float on = onrm[node];
    float2 b2 = ((const float2*)bias)[lane];
    float ox = fmaxf(ax * nrm + b2.x, 0.f) * on;
    float oy = fmaxf(ay * nrm + b2.y, 0.f) * on;
    unsigned short hx, lx, hy, ly;
    split_bf16(ox, hx, lx);
    split_bf16(oy, hy, ly);
    ushort2 hv, lv;
    hv.x = hx; hv.y = hy;
    lv.x = lx; lv.y = ly;
    ((ushort2*)Ah)[(size_t)node * 64 + lane] = hv;
    ((ushort2*)Al)[(size_t)node * 64 + lane] = lv;
}

__global__ __launch_bounds__(256) void k_agg64(const __half* __restrict__ h,
                                               const int* __restrict__ row_ptr,
                                               const int* __restrict__ eidx,
                                               const float* __restrict__ inrm,
                                               const float* __restrict__ bias,
                                               float* __restrict__ out, int n) {
    int node = blockIdx.x * 4 + (threadIdx.x >> 6);
    int lane = threadIdx.x & 63;
    if (node >= n) return;
    int beg = row_ptr[node], end = row_ptr[node + 1];
    float a0 = 0.f, a1 = 0.f, a2 = 0.f, a3 = 0.f;
    int j = beg;
    for (; j + 4 <= end; j += 4) {
        int s0 = eidx[j], s1 = eidx[j + 1], s2 = eidx[j + 2], s3 = eidx[j + 3];
        float v0 = __half2float(h[(size_t)s0 * 64 + lane]);
        float v1 = __half2float(h[(size_t)s1 * 64 + lane]);
        float v2 = __half2float(h[(size_t)s2 * 64 + lane]);
        float v3 = __half2float(h[(size_t)s3 * 64 + lane]);
        a0 += v0; a1 += v1; a2 += v2; a3 += v3;
    }
    for (; j < end; ++j) a0 += __half2float(h[(size_t)eidx[j] * 64 + lane]);
    float acc = (a0 + a1) + (a2 + a3);
    out[(size_t)node * 64 + lane] = acc * inrm[node] + bias[lane];
}

// ---------------------------------------------------------------------------
// Fallback fp32 path (known-good)
// ---------------------------------------------------------------------------
template <int K, int FO, int TX, int TY, int RPT>
__global__ __launch_bounds__(256) void k_matmul(const float* __restrict__ X,
                                                const float* __restrict__ W,
                                                const float* __restrict__ onrm,
                                                float* __restrict__ H, int n) {
    constexpr int BROWS = TY * RPT;
    constexpr int LDK = K + 1;
    __shared__ float xs[BROWS * LDK];
    int tx = threadIdx.x, ty = threadIdx.y;
    int tid = ty * TX + tx;
    int row0 = blockIdx.x * BROWS;

    for (int idx = tid; idx < BROWS * K; idx += 256) {
        int r = idx / K;
        int k = idx - r * K;
        int row = row0 + r;
        xs[r * LDK + k] = (row < n) ? X[(size_t)row * K + k] : 0.f;
    }
    __syncthreads();

    float4 acc[RPT];
#pragma unroll
    for (int r = 0; r < RPT; ++r) acc[r] = make_float4(0.f, 0.f, 0.f, 0.f);

    const float4* W4 = (const float4*)W;
#pragma unroll 4
    for (int k = 0; k < K; ++k) {
        float4 w = W4[k * (FO / 4) + tx];
#pragma unroll
        for (int r = 0; r < RPT; ++r) {
            float xv = xs[(ty * RPT + r) * LDK + k];
            acc[r].x += xv * w.x;
            acc[r].y += xv * w.y;
            acc[r].z += xv * w.z;
            acc[r].w += xv * w.w;
        }
    }

#pragma unroll
    for (int r = 0; r < RPT; ++r) {
        int row = row0 + ty * RPT + r;
        if (row < n) {
            float s = onrm[row];
            float4 o = make_float4(acc[r].x * s, acc[r].y * s, acc[r].z * s, acc[r].w * s);
            ((float4*)H)[(size_t)row * (FO / 4) + tx] = o;
        }
    }
}

__global__ __launch_bounds__(256) void k_agg128f(const float* __restrict__ h,
                                                 const int* __restrict__ row_ptr,
                                                 const int* __restrict__ eidx,
                                                 const float* __restrict__ inrm,
                                                 const float* __restrict__ bias,
                                                 float* __restrict__ out, int n, int relu) {
    int node = blockIdx.x * 4 + (threadIdx.x >> 6);
    int lane = threadIdx.x & 63;
    if (node >= n) return;
    int beg = row_ptr[node], end = row_ptr[node + 1];
    const float2* h2 = (const float2*)h;
    float ax = 0.f, ay = 0.f;
    for (int j = beg; j < end; ++j) {
        int s = eidx[j];
        float2 v = h2[(size_t)s * 64 + lane];
        ax += v.x;
        ay += v.y;
    }
    float nrm = inrm[node];
    float2 b2 = ((const float2*)bias)[lane];
    float ox = ax * nrm + b2.x;
    float oy = ay * nrm + b2.y;
    if (relu) { ox = fmaxf(ox, 0.f); oy = fmaxf(oy, 0.f); }
    float2 o; o.x = ox; o.y = oy;
    ((float2*)out)[(size_t)node * 64 + lane] = o;
}

__global__ __launch_bounds__(256) void k_agg64f(const float* __restrict__ h,
                                                const int* __restrict__ row_ptr,
                                                const int* __restrict__ eidx,
                                                const float* __restrict__ inrm,
                                                const float* __restrict__ bias,
                                                float* __restrict__ out, int n) {
    int node = blockIdx.x * 4 + (threadIdx.x >> 6);
    int lane = threadIdx.x & 63;
    if (node >= n) return;
    int beg = row_ptr[node], end = row_ptr[node + 1];
    float acc = 0.f;
    for (int j = beg; j < end; ++j) {
        int s = eidx[j];
        acc += h[(size_t)s * 64 + lane];
    }
    out[(size_t)node * 64 + lane] = acc * inrm[node] + bias[lane];
}

static inline size_t align_up(size_t v, size_t a) { return (v + a - 1) & ~(a - 1); }

extern "C" void kernel_launch(void* const* d_in, const int* in_sizes, int n_in,
                              void* d_out, int out_size, void* d_ws, size_t ws_size,
                              hipStream_t stream) {
    const float* x  = (const float*)d_in[0];
    const int* ei   = (const int*)d_in[1];
    const float* W0 = (const float*)d_in[2];
    const float* b0 = (const float*)d_in[3];
    const float* W1 = (const float*)d_in[4];
    const float* b1 = (const float*)d_in[5];
    const float* W2 = (const float*)d_in[6];
    const float* b2 = (const float*)d_in[7];
    const float* W3 = (const float*)d_in[8];
    const float* b3 = (const float*)d_in[9];

    const int n  = in_sizes[0] / 256;   // 50000
    const int ne = in_sizes[1] / 2;     // 800000
    const int n_pad = (n + 127) & ~127;
    const int* src = ei;
    const int* dst = ei + ne;

    // ---- shared preprocessing layout ----
    char* ws = (char*)d_ws;
    size_t off = 0;
    auto take = [&](size_t bytes) { void* p = ws + off; off = align_up(off + bytes, 256); return p; };
    int* degs_part   = (int*)take((size_t)8 * n_pad * 4);   // 8 copies, src-degree
    int* degd_part   = (int*)take((size_t)8 * n_pad * 4);   // 8 copies, dst-degree
    int* cursor_part = (int*)take((size_t)8 * n_pad * 4);   // 8 copies, CSR cursors
    int* row_ptr     = (int*)take((size_t)(n_pad + 4) * 4);
    int* degd_sum    = (int*)take((size_t)n_pad * 4);
    int* eidx        = (int*)take((size_t)ne * 4);
    float* onrm      = (float*)take((size_t)n * 4);
    float* inrm      = (float*)take((size_t)n * 4);

    // ---- MFMA-path layout ----
    size_t off_save = off;
    unsigned short* Ah  = (unsigned short*)take((size_t)n_pad * 256 * 2);
    unsigned short* Al  = (unsigned short*)take((size_t)n_pad * 256 * 2);
    __half* hbuf        = (__half*)take((size_t)n * 128 * 2);
    unsigned short* Wh0 = (unsigned short*)take(256 * 128 * 2);
    unsigned short* Wl0 = (unsigned short*)take(256 * 128 * 2);
    unsigned short* Wh1 = (unsigned short*)take(128 * 128 * 2);
    unsigned short* Wl1 = (unsigned short*)take(128 * 128 * 2);
    unsigned short* Wh2 = (unsigned short*)take(128 * 128 * 2);
    unsigned short* Wl2 = (unsigned short*)take(128 * 128 * 2);
    unsigned short* Wh3 = (unsigned short*)take(128 * 64 * 2);
    unsigned short* Wl3 = (unsigned short*)take(128 * 64 * 2);
    bool use_mfma = (off <= ws_size);

    // ---- preprocessing ----
    // degs_part/degd_part adjacent -> one memset covers both (16 copies total)
    hipMemsetAsync(degs_part, 0, (size_t)16 * n_pad * 4, stream);
    const int edgeGrid = (ne + 255) / 256;
    k_degrees8<<<edgeGrid, 256, 0, stream>>>(src, dst, ne, n_pad, degs_part, degd_part);
    k_norms_reduce<<<(n_pad + 255) / 256, 256, 0, stream>>>(degs_part, degd_part, n_pad, n,
                                                            onrm, inrm, degd_sum);
    k_scan<<<1, 1024, 0, stream>>>(degd_sum, n, row_ptr);
    k_cursors<<<(n + 255) / 256, 256, 0, stream>>>(row_ptr, degd_part, n_pad, n, cursor_part);
    k_build_csr8<<<edgeGrid, 256, 0, stream>>>(src, dst, ne, n_pad, cursor_part, eidx);

    const int aggGrid = (n + 3) / 4;

    if (use_mfma) {
        k_split_w_all<<<(73728 + 255) / 256, 256, 0, stream>>>(
            W0, W1, W2, W3, Wh0, Wl0, Wh1, Wl1, Wh2, Wl2, Wh3, Wl3);
        k_split_x<<<((n * 64) + 255) / 256, 256, 0, stream>>>(x, onrm, Ah, Al, n);

        const int mmGrid = n_pad / 128;
        // L0: 256 -> 128
        k_mm<256, 128><<<mmGrid, 256, 0, stream>>>(Ah, Al, Wh0, Wl0, hbuf, n);
        k_agg128_split<<<aggGrid, 256, 0, stream>>>(hbuf, row_ptr, eidx, inrm, onrm, b0, Ah, Al, n);
        // L1
        k_mm<128, 128><<<mmGrid, 256, 0, stream>>>(Ah, Al, Wh1, Wl1, hbuf, n);
        k_agg128_split<<<aggGrid, 256, 0, stream>>>(hbuf, row_ptr, eidx, inrm, onrm, b1, Ah, Al, n);
        // L2
        k_mm<128, 128><<<mmGrid, 256, 0, stream>>>(Ah, Al, Wh2, Wl2, hbuf, n);
        k_agg128_split<<<aggGrid, 256, 0, stream>>>(hbuf, row_ptr, eidx, inrm, onrm, b2, Ah, Al, n);
        // L3: 128 -> 64
        k_mm<128, 64><<<mmGrid, 256, 0, stream>>>(Ah, Al, Wh3, Wl3, hbuf, n);
        k_agg64<<<aggGrid, 256, 0, stream>>>(hbuf, row_ptr, eidx, inrm, b3, (float*)d_out, n);
    } else {
        // fp32 fallback
        off = off_save;
        float* hbufF  = (float*)take((size_t)n * 128 * 4);
        float* xnextF = (float*)take((size_t)n * 128 * 4);

        k_matmul<256, 128, 32, 8, 4><<<(n + 31) / 32, dim3(32, 8), 0, stream>>>(x, W0, onrm, hbufF, n);
        k_agg128f<<<aggGrid, 256, 0, stream>>>(hbufF, row_ptr, eidx, inrm, b0, xnextF, n, 1);
        k_matmul<128, 128, 32, 8, 4><<<(n + 31) / 32, dim3(32, 8), 0, stream>>>(xnextF, W1, onrm, hbufF, n);
        k_agg128f<<<aggGrid, 256, 0, stream>>>(hbufF, row_ptr, eidx, inrm, b1, xnextF, n, 1);
        k_matmul<128, 128, 32, 8, 4><<<(n + 31) / 32, dim3(32, 8), 0, stream>>>(xnextF, W2, onrm, hbufF, n);
        k_agg128f<<<aggGrid, 256, 0, stream>>>(hbufF, row_ptr, eidx, inrm, b2, xnextF, n, 1);
        k_matmul<128, 64, 16, 16, 4><<<(n + 63) / 64, dim3(16, 16), 0, stream>>>(xnextF, W3, onrm, hbufF, n);
        k_agg64f<<<aggGrid, 256, 0, stream>>>(hbufF, row_ptr, eidx, inrm, b3, (float*)d_out, n);
    }
}

// Round 6
// 441.494 us; speedup vs baseline: 1.8072x; 1.0205x over previous
//
#include <hip/hip_runtime.h>
#include <hip/hip_fp16.h>

// ---------------------------------------------------------------------------
// GCN 4-layer forward on MI355X (gfx950).
//   Preprocess (ZERO global atomics): LDS-privatized range histograms
//     (8 ranges x 32 chunks) -> coalesced per-(range,chunk) count dumps ->
//     reduce+norms -> scan -> per-chunk cursor bases -> CSR scatter with
//     LDS cursors.  Rationale: device-scope atomics execute at the memory-
//     side coherence point (~32B write-through each, ~27G/s ceiling) — the
//     round-5 8-copy split proved address spreading doesn't help.
//   Per layer : bf16-split MFMA GEMM (3-term, ~fp32 precision), B staged in
//               LDS (XOR-swizzled) -> h in fp16 -> wave-per-node CSR
//               gather-sum (x8 unrolled, fp32 accum), fused epilogue.
// ---------------------------------------------------------------------------

typedef __attribute__((ext_vector_type(8))) short short8;
typedef __attribute__((ext_vector_type(4))) float f32x4;

#define NRANGE 8
#define NCHUNK 32
#define RMAX   6272   // 8*6272 = 50176 >= 50000 nodes

__device__ inline unsigned short bf16_rne(float v) {
    union { float f; unsigned u; } c; c.f = v;
    unsigned u = c.u;
    unsigned lsb = (u >> 16) & 1u;
    u += 0x7fffu + lsb;
    return (unsigned short)(u >> 16);
}
__device__ inline float bf16_to_f(unsigned short h) {
    union { unsigned u; float f; } c; c.u = ((unsigned)h) << 16;
    return c.f;
}
__device__ inline void split_bf16(float v, unsigned short& hi, unsigned short& lo) {
    hi = bf16_rne(v);
    lo = bf16_rne(v - bf16_to_f(hi));
}

// ---------------------------------------------------------------------------
// Preprocessing — LDS-privatized histograms, no global atomics.
// block (r,c): r = blockIdx&7, c = blockIdx>>3. Same mapping in k_hist/k_csr.
// ---------------------------------------------------------------------------

__global__ __launch_bounds__(256) void k_hist(const int* __restrict__ src,
                                              const int* __restrict__ dst,
                                              int ne, int R, int E,
                                              int* __restrict__ cnt_s,
                                              int* __restrict__ cnt_d) {
    __shared__ int hs[RMAX];
    __shared__ int hd[RMAX];
    int r = blockIdx.x & (NRANGE - 1);
    int c = blockIdx.x >> 3;
    int tid = threadIdx.x;
    for (int i = tid; i < R; i += 256) { hs[i] = 0; hd[i] = 0; }
    __syncthreads();
    int lo = r * R, hi = lo + R;
    int e0 = c * E, e1 = min(e0 + E, ne);
    for (int i = e0 + tid; i < e1; i += 256) {
        int s = src[i], d = dst[i];
        if (s >= lo && s < hi) atomicAdd(&hs[s - lo], 1);
        if (d >= lo && d < hi) atomicAdd(&hd[d - lo], 1);
    }
    __syncthreads();
    int base = (r * NCHUNK + c) * R;
    for (int i = tid; i < R; i += 256) {
        cnt_s[base + i] = hs[i];
        cnt_d[base + i] = hd[i];
    }
}

// Reduce chunk counts -> norms + dst-degree array for the scan.
__global__ void k_reduce_norms(const int* __restrict__ cnt_s,
                               const int* __restrict__ cnt_d, int R, int n,
                               float* __restrict__ onrm, float* __restrict__ inrm,
                               int* __restrict__ degd_sum) {
    int i = blockIdx.x * blockDim.x + threadIdx.x;
    if (i >= NRANGE * R) return;
    int r = i / R, ip = i - r * R;
    int ds = 0, dd = 0;
    for (int c = 0; c < NCHUNK; ++c) {
        ds += cnt_s[(r * NCHUNK + c) * R + ip];
        dd += cnt_d[(r * NCHUNK + c) * R + ip];
    }
    degd_sum[i] = dd;
    if (i < n) {
        onrm[i] = rsqrtf((float)max(ds, 1));
        inrm[i] = rsqrtf((float)max(dd, 1));
    }
}

// Single-block exclusive scan, int4 per thread.
__global__ __launch_bounds__(1024) void k_scan(const int* __restrict__ deg, int n,
                                               int* __restrict__ row_ptr) {
    __shared__ int wsum[16];
    __shared__ int carry;
    int tid = threadIdx.x;
    int lane = tid & 63;
    int wid = tid >> 6;
    if (tid == 0) carry = 0;
    __syncthreads();
    int n4 = (n + 3) >> 2;
    for (int base = 0; base < n4; base += 1024) {
        int i4 = base + tid;
        int4 v = make_int4(0, 0, 0, 0);
        if (i4 < n4) v = ((const int4*)deg)[i4];
        int s = v.x + v.y + v.z + v.w;
        int x = s;
#pragma unroll
        for (int off = 1; off < 64; off <<= 1) {
            int y = __shfl_up(x, off, 64);
            if (lane >= off) x += y;
        }
        if (lane == 63) wsum[wid] = x;
        __syncthreads();
        if (wid == 0 && lane < 16) {
            int w = wsum[lane];
#pragma unroll
            for (int off = 1; off < 16; off <<= 1) {
                int y = __shfl_up(w, off, 16);
                if (lane >= off) w += y;
            }
            wsum[lane] = w;
        }
        __syncthreads();
        int excl = x - s + carry + (wid > 0 ? wsum[wid - 1] : 0);
        if (i4 < n4) {
            int e0 = excl, e1 = e0 + v.x, e2 = e1 + v.y, e3 = e2 + v.z;
            ((int4*)row_ptr)[i4] = make_int4(e0, e1, e2, e3);
        }
        __syncthreads();
        if (tid == 0) carry += wsum[15];
        __syncthreads();
    }
    if (tid == 0) row_ptr[n] = carry;
}

// Per-(node,chunk) cursor base: cbase[r][c][ip] = row_ptr + prefix of counts.
__global__ void k_cursors(const int* __restrict__ row_ptr,
                          const int* __restrict__ cnt_d, int R, int n,
                          int* __restrict__ cbase) {
    int i = blockIdx.x * blockDim.x + threadIdx.x;
    if (i >= NRANGE * R) return;
    int r = i / R, ip = i - r * R;
    int run = (i < n) ? row_ptr[i] : 0;
    for (int c = 0; c < NCHUNK; ++c) {
        int idx = (r * NCHUNK + c) * R + ip;
        cbase[idx] = run;
        run += cnt_d[idx];
    }
}

// CSR scatter: LDS cursors (workgroup-scope atomics only).
__global__ __launch_bounds__(256) void k_csr(const int* __restrict__ src,
                                             const int* __restrict__ dst,
                                             int ne, int R, int E,
                                             const int* __restrict__ cbase,
                                             int* __restrict__ eidx) {
    __shared__ int cur[RMAX];
    int r = blockIdx.x & (NRANGE - 1);
    int c = blockIdx.x >> 3;
    int tid = threadIdx.x;
    int base = (r * NCHUNK + c) * R;
    for (int i = tid; i < R; i += 256) cur[i] = cbase[base + i];
    __syncthreads();
    int lo = r * R, hi = lo + R;
    int e0 = c * E, e1 = min(e0 + E, ne);
    for (int i = e0 + tid; i < e1; i += 256) {
        int d = dst[i];
        if (d >= lo && d < hi) {
            int p = atomicAdd(&cur[d - lo], 1);
            eidx[p] = src[i];
        }
    }
}

// ---------------------------------------------------------------------------
// bf16 split helpers (MFMA path)
// ---------------------------------------------------------------------------

__global__ __launch_bounds__(256) void k_split_x(const float* __restrict__ x,
                                                 const float* __restrict__ onrm,
                                                 unsigned short* __restrict__ Ah,
                                                 unsigned short* __restrict__ Al, int n) {
    int i4 = blockIdx.x * blockDim.x + threadIdx.x;  // float4 index, 64 per row
    int row = i4 >> 6;
    if (row >= n) return;
    float4 v = ((const float4*)x)[i4];
    float s = onrm[row];
    unsigned short h0, l0, h1, l1, h2, l2, h3, l3;
    split_bf16(v.x * s, h0, l0);
    split_bf16(v.y * s, h1, l1);
    split_bf16(v.z * s, h2, l2);
    split_bf16(v.w * s, h3, l3);
    ushort4 hv, lv;
    hv.x = h0; hv.y = h1; hv.z = h2; hv.w = h3;
    lv.x = l0; lv.y = l1; lv.z = l2; lv.w = l3;
    ((ushort4*)Ah)[i4] = hv;
    ((ushort4*)Al)[i4] = lv;
}

__global__ void k_split_w_all(const float* __restrict__ W0, const float* __restrict__ W1,
                              const float* __restrict__ W2, const float* __restrict__ W3,
                              unsigned short* __restrict__ Wh0, unsigned short* __restrict__ Wl0,
                              unsigned short* __restrict__ Wh1, unsigned short* __restrict__ Wl1,
                              unsigned short* __restrict__ Wh2, unsigned short* __restrict__ Wl2,
                              unsigned short* __restrict__ Wh3, unsigned short* __restrict__ Wl3) {
    int i = blockIdx.x * blockDim.x + threadIdx.x;
    const float* W; unsigned short *Wh, *Wl; int K, F, off;
    if (i < 32768)                    { W = W0; Wh = Wh0; Wl = Wl0; K = 256; F = 128; off = i; }
    else if (i < 32768 + 16384)       { W = W1; Wh = Wh1; Wl = Wl1; K = 128; F = 128; off = i - 32768; }
    else if (i < 32768 + 32768)       { W = W2; Wh = Wh2; Wl = Wl2; K = 128; F = 128; off = i - 49152; }
    else if (i < 32768 + 32768 + 8192){ W = W3; Wh = Wh3; Wl = Wl3; K = 128; F = 64;  off = i - 65536; }
    else return;
    int k = off / F, c = off % F;
    unsigned short h, l;
    split_bf16(W[k * F + c], h, l);
    Wh[c * K + k] = h;
    Wl[c * K + k] = l;
}

// ---------------------------------------------------------------------------
// MFMA GEMM: H[m][c] = sum_k A[m][k]*W[k][c]; H stored fp16.
// ---------------------------------------------------------------------------
template <int K, int N>
__global__ __launch_bounds__(256) void k_mm(const unsigned short* __restrict__ Ah,
                                            const unsigned short* __restrict__ Al,
                                            const unsigned short* __restrict__ Bh,
                                            const unsigned short* __restrict__ Bl,
                                            __half* __restrict__ H, int n) {
    constexpr int KT = 128;
    constexpr int NT = N / 16;
    constexpr int NKT = K / KT;
    __shared__ unsigned short sBh[N * KT];
    __shared__ unsigned short sBl[N * KT];

    int tid = threadIdx.x;
    int w = tid >> 6, lane = tid & 63;
    int quad = lane >> 4, l16 = lane & 15;
    int row_base = blockIdx.x * 128 + w * 32;

    int ar0 = row_base + l16;
    int ar1 = row_base + 16 + l16;
    if (ar0 >= n) ar0 = n - 1;
    if (ar1 >= n) ar1 = n - 1;

    f32x4 acc[2][NT];
#pragma unroll
    for (int m = 0; m < 2; ++m)
#pragma unroll
        for (int t = 0; t < NT; ++t) acc[m][t] = (f32x4){0.f, 0.f, 0.f, 0.f};

    for (int kt = 0; kt < NKT; ++kt) {
        if (kt) __syncthreads();
        for (int idx = tid; idx < N * 16; idx += 256) {
            int c = idx >> 4;
            int g = idx & 15;
            short8 vh = *(const short8*)(Bh + (size_t)c * K + kt * KT + g * 8);
            short8 vl = *(const short8*)(Bl + (size_t)c * K + kt * KT + g * 8);
            int sg = g ^ (c & 15);
            *(short8*)(&sBh[c * KT + sg * 8]) = vh;
            *(short8*)(&sBl[c * KT + sg * 8]) = vl;
        }
        __syncthreads();

        const unsigned short* a0h = Ah + (size_t)ar0 * K + kt * KT;
        const unsigned short* a0l = Al + (size_t)ar0 * K + kt * KT;
        const unsigned short* a1h = Ah + (size_t)ar1 * K + kt * KT;
        const unsigned short* a1l = Al + (size_t)ar1 * K + kt * KT;

#pragma unroll
        for (int k0 = 0; k0 < KT; k0 += 32) {
            int eoff = k0 + quad * 8;
            short8 a0hv = *(const short8*)(a0h + eoff);
            short8 a0lv = *(const short8*)(a0l + eoff);
            short8 a1hv = *(const short8*)(a1h + eoff);
            short8 a1lv = *(const short8*)(a1l + eoff);
            int g = (k0 >> 3) + quad;
            int sg8 = (g ^ l16) * 8;
#pragma unroll
            for (int t = 0; t < NT; ++t) {
                int cb = (t * 16 + l16) * KT;
                short8 bh = *(const short8*)(&sBh[cb + sg8]);
                short8 bl = *(const short8*)(&sBl[cb + sg8]);
                acc[0][t] = __builtin_amdgcn_mfma_f32_16x16x32_bf16(a0hv, bh, acc[0][t], 0, 0, 0);
                acc[0][t] = __builtin_amdgcn_mfma_f32_16x16x32_bf16(a0lv, bh, acc[0][t], 0, 0, 0);
                acc[0][t] = __builtin_amdgcn_mfma_f32_16x16x32_bf16(a0hv, bl, acc[0][t], 0, 0, 0);
                acc[1][t] = __builtin_amdgcn_mfma_f32_16x16x32_bf16(a1hv, bh, acc[1][t], 0, 0, 0);
                acc[1][t] = __builtin_amdgcn_mfma_f32_16x16x32_bf16(a1lv, bh, acc[1][t], 0, 0, 0);
                acc[1][t] = __builtin_amdgcn_mfma_f32_16x16x32_bf16(a1hv, bl, acc[1][t], 0, 0, 0);
            }
        }
    }

#pragma unroll
    for (int m = 0; m < 2; ++m) {
#pragma unroll
        for (int t = 0; t < NT; ++t) {
#pragma unroll
            for (int r = 0; r < 4; ++r) {
                int grow = row_base + m * 16 + quad * 4 + r;
                if (grow < n) H[(size_t)grow * N + t * 16 + l16] = __float2half(acc[m][t][r]);
            }
        }
    }
}

// ---------------------------------------------------------------------------
// Aggregation: wave per node, fp16 h, x8-unrolled gather, fp32 accumulate.
// ---------------------------------------------------------------------------

__global__ __launch_bounds__(256) void k_agg128_split(const __half* __restrict__ h,
                                                      const int* __restrict__ row_ptr,
                                                      const int* __restrict__ eidx,
                                                      const float* __restrict__ inrm,
                                                      const float* __restrict__ onrm,
                                                      const float* __restrict__ bias,
                                                      unsigned short* __restrict__ Ah,
                                                      unsigned short* __restrict__ Al, int n) {
    int node = blockIdx.x * 4 + (threadIdx.x >> 6);
    int lane = threadIdx.x & 63;
    if (node >= n) return;
    int beg = row_ptr[node], end = row_ptr[node + 1];
    const __half2* h2 = (const __half2*)h;

    float ax[8], ay[8];
#pragma unroll
    for (int u = 0; u < 8; ++u) { ax[u] = 0.f; ay[u] = 0.f; }
    int j = beg;
    for (; j + 8 <= end; j += 8) {
        int s[8];
#pragma unroll
        for (int u = 0; u < 8; ++u) s[u] = eidx[j + u];
        __half2 v[8];
#pragma unroll
        for (int u = 0; u < 8; ++u) v[u] = h2[(size_t)s[u] * 64 + lane];
#pragma unroll
        for (int u = 0; u < 8; ++u) {
            float2 f = __half22float2(v[u]);
            ax[u] += f.x; ay[u] += f.y;
        }
    }
    for (; j < end; ++j) {
        float2 f = __half22float2(h2[(size_t)eidx[j] * 64 + lane]);
        ax[0] += f.x; ay[0] += f.y;
    }
    float axs = ((ax[0] + ax[1]) + (ax[2] + ax[3])) + ((ax[4] + ax[5]) + (ax[6] + ax[7]));
    float ays = ((ay[0] + ay[1]) + (ay[2] + ay[3])) + ((ay[4] + ay[5]) + (ay[6] + ay[7]));

    float nrm = inrm[node];
    float on = onrm[node];
    float2 b2 = ((const float2*)bias)[lane];
    float ox = fmaxf(axs * nrm + b2.x, 0.f) * on;
    float oy = fmaxf(ays * nrm + b2.y, 0.f) * on;
    unsigned short hx, lx, hy, ly;
    split_bf16(ox, hx, lx);
    split_bf16(oy, hy, ly);
    ushort2 hv, lv;
    hv.x = hx; hv.y = hy;
    lv.x = lx; lv.y = ly;
    ((ushort2*)Ah)[(size_t)node * 64 + lane] = hv;
    ((ushort2*)Al)[(size_t)node * 64 + lane] = lv;
}

__global__ __launch_bounds__(256) void k_agg64(const __half* __restrict__ h,
                                               const int* __restrict__ row_ptr,
                                               const int* __restrict__ eidx,
                                               const float* __restrict__ inrm,
                                               const float* __restrict__ bias,
                                               float* __restrict__ out, int n) {
    int node = blockIdx.x * 4 + (threadIdx.x >> 6);
    int lane = threadIdx.x & 63;
    if (node >= n) return;
    int beg = row_ptr[node], end = row_ptr[node + 1];
    float a[8];
#pragma unroll
    for (int u = 0; u < 8; ++u) a[u] = 0.f;
    int j = beg;
    for (; j + 8 <= end; j += 8) {
        int s[8];
#pragma unroll
        for (int u = 0; u < 8; ++u) s[u] = eidx[j + u];
#pragma unroll
        for (int u = 0; u < 8; ++u) a[u] += __half2float(h[(size_t)s[u] * 64 + lane]);
    }
    for (; j < end; ++j) a[0] += __half2float(h[(size_t)eidx[j] * 64 + lane]);
    float acc = ((a[0] + a[1]) + (a[2] + a[3])) + ((a[4] + a[5]) + (a[6] + a[7]));
    out[(size_t)node * 64 + lane] = acc * inrm[node] + bias[lane];
}

// ---------------------------------------------------------------------------
// Fallback fp32 path (known-good) — used if workspace too small for MFMA path.
// ---------------------------------------------------------------------------
template <int K, int FO, int TX, int TY, int RPT>
__global__ __launch_bounds__(256) void k_matmul(const float* __restrict__ X,
                                                const float* __restrict__ W,
                                                const float* __restrict__ onrm,
                                                float* __restrict__ H, int n) {
    constexpr int BROWS = TY * RPT;
    constexpr int LDK = K + 1;
    __shared__ float xs[BROWS * LDK];
    int tx = threadIdx.x, ty = threadIdx.y;
    int tid = ty * TX + tx;
    int row0 = blockIdx.x * BROWS;

    for (int idx = tid; idx < BROWS * K; idx += 256) {
        int r = idx / K;
        int k = idx - r * K;
        int row = row0 + r;
        xs[r * LDK + k] = (row < n) ? X[(size_t)row * K + k] : 0.f;
    }
    __syncthreads();

    float4 acc[RPT];
#pragma unroll
    for (int r = 0; r < RPT; ++r) acc[r] = make_float4(0.f, 0.f, 0.f, 0.f);

    const float4* W4 = (const float4*)W;
#pragma unroll 4
    for (int k = 0; k < K; ++k) {
        float4 w = W4[k * (FO / 4) + tx];
#pragma unroll
        for (int r = 0; r < RPT; ++r) {
            float xv = xs[(ty * RPT + r) * LDK + k];
            acc[r].x += xv * w.x;
            acc[r].y += xv * w.y;
            acc[r].z += xv * w.z;
            acc[r].w += xv * w.w;
        }
    }

#pragma unroll
    for (int r = 0; r < RPT; ++r) {
        int row = row0 + ty * RPT + r;
        if (row < n) {
            float s = onrm[row];
            float4 o = make_float4(acc[r].x * s, acc[r].y * s, acc[r].z * s, acc[r].w * s);
            ((float4*)H)[(size_t)row * (FO / 4) + tx] = o;
        }
    }
}

__global__ __launch_bounds__(256) void k_agg128f(const float* __restrict__ h,
                                                 const int* __restrict__ row_ptr,
                                                 const int* __restrict__ eidx,
                                                 const float* __restrict__ inrm,
                                                 const float* __restrict__ bias,
                                                 float* __restrict__ out, int n, int relu) {
    int node = blockIdx.x * 4 + (threadIdx.x >> 6);
    int lane = threadIdx.x & 63;
    if (node >= n) return;
    int beg = row_ptr[node], end = row_ptr[node + 1];
    const float2* h2 = (const float2*)h;
    float ax = 0.f, ay = 0.f;
    for (int j = beg; j < end; ++j) {
        int s = eidx[j];
        float2 v = h2[(size_t)s * 64 + lane];
        ax += v.x;
        ay += v.y;
    }
    float nrm = inrm[node];
    float2 b2 = ((const float2*)bias)[lane];
    float ox = ax * nrm + b2.x;
    float oy = ay * nrm + b2.y;
    if (relu) { ox = fmaxf(ox, 0.f); oy = fmaxf(oy, 0.f); }
    float2 o; o.x = ox; o.y = oy;
    ((float2*)out)[(size_t)node * 64 + lane] = o;
}

__global__ __launch_bounds__(256) void k_agg64f(const float* __restrict__ h,
                                                const int* __restrict__ row_ptr,
                                                const int* __restrict__ eidx,
                                                const float* __restrict__ inrm,
                                                const float* __restrict__ bias,
                                                float* __restrict__ out, int n) {
    int node = blockIdx.x * 4 + (threadIdx.x >> 6);
    int lane = threadIdx.x & 63;
    if (node >= n) return;
    int beg = row_ptr[node], end = row_ptr[node + 1];
    float acc = 0.f;
    for (int j = beg; j < end; ++j) {
        int s = eidx[j];
        acc += h[(size_t)s * 64 + lane];
    }
    out[(size_t)node * 64 + lane] = acc * inrm[node] + bias[lane];
}

// Legacy atomic preprocessing (only if n > NRANGE*RMAX; never for this problem)
__global__ void k_degrees_leg(const int* __restrict__ src, const int* __restrict__ dst,
                              int ne, int* __restrict__ degs, int* __restrict__ degd) {
    int i = blockIdx.x * blockDim.x + threadIdx.x;
    if (i < ne) {
        atomicAdd(&degs[src[i]], 1);
        atomicAdd(&degd[dst[i]], 1);
    }
}
__global__ void k_norms_leg(const int* __restrict__ degs, const int* __restrict__ degd,
                            float* __restrict__ onrm, float* __restrict__ inrm,
                            int* __restrict__ degd_sum, int n) {
    int i = blockIdx.x * blockDim.x + threadIdx.x;
    if (i < n) {
        degd_sum[i] = degd[i];
        onrm[i] = rsqrtf((float)max(degs[i], 1));
        inrm[i] = rsqrtf((float)max(degd[i], 1));
    }
}
__global__ void k_copy_int(const int* __restrict__ a, int* __restrict__ b, int n) {
    int i = blockIdx.x * blockDim.x + threadIdx.x;
    if (i < n) b[i] = a[i];
}
__global__ void k_build_csr_leg(const int* __restrict__ src, const int* __restrict__ dst,
                                int ne, int* __restrict__ cursor, int* __restrict__ eidx) {
    int i = blockIdx.x * blockDim.x + threadIdx.x;
    if (i < ne) {
        int p = atomicAdd(&cursor[dst[i]], 1);
        eidx[p] = src[i];
    }
}

static inline size_t align_up(size_t v, size_t a) { return (v + a - 1) & ~(a - 1); }

extern "C" void kernel_launch(void* const* d_in, const int* in_sizes, int n_in,
                              void* d_out, int out_size, void* d_ws, size_t ws_size,
                              hipStream_t stream) {
    const float* x  = (const float*)d_in[0];
    const int* ei   = (const int*)d_in[1];
    const float* W0 = (const float*)d_in[2];
    const float* b0 = (const float*)d_in[3];
    const float* W1 = (const float*)d_in[4];
    const float* b1 = (const float*)d_in[5];
    const float* W2 = (const float*)d_in[6];
    const float* b2 = (const float*)d_in[7];
    const float* W3 = (const float*)d_in[8];
    const float* b3 = (const float*)d_in[9];

    const int n  = in_sizes[0] / 256;   // 50000
    const int ne = in_sizes[1] / 2;     // 800000
    const int n_pad = (n + 127) & ~127;
    const int* src = ei;
    const int* dst = ei + ne;

    // ---- shared layout ----
    char* ws = (char*)d_ws;
    size_t off = 0;
    auto take = [&](size_t bytes) { void* p = ws + off; off = align_up(off + bytes, 256); return p; };
    int* row_ptr  = (int*)take((size_t)(n_pad + 4) * 4);
    int* degd_sum = (int*)take((size_t)n_pad * 4);
    int* eidx     = (int*)take((size_t)ne * 4);
    float* onrm   = (float*)take((size_t)n * 4);
    float* inrm   = (float*)take((size_t)n * 4);

    // ---- MFMA-path layout ----
    size_t off_save = off;
    unsigned short* Ah  = (unsigned short*)take((size_t)n_pad * 256 * 2);
    unsigned short* Al  = (unsigned short*)take((size_t)n_pad * 256 * 2);
    __half* hbuf        = (__half*)take((size_t)n * 128 * 2);
    unsigned short* Wh0 = (unsigned short*)take(256 * 128 * 2);
    unsigned short* Wl0 = (unsigned short*)take(256 * 128 * 2);
    unsigned short* Wh1 = (unsigned short*)take(128 * 128 * 2);
    unsigned short* Wl1 = (unsigned short*)take(128 * 128 * 2);
    unsigned short* Wh2 = (unsigned short*)take(128 * 128 * 2);
    unsigned short* Wl2 = (unsigned short*)take(128 * 128 * 2);
    unsigned short* Wh3 = (unsigned short*)take(128 * 64 * 2);
    unsigned short* Wl3 = (unsigned short*)take(128 * 64 * 2);
    bool use_mfma = (off <= ws_size);

    // ---- preprocessing scratch ALIASED onto the Ah/Al region (dead until
    //      k_split_x / first matmul, which run after preprocessing) ----
    char* pre = (char*)Ah;  // >= 19.5 MB available in Ah alone (25.6 MB)
    const int R = ((n + NRANGE * 64 - 1) / (NRANGE * 64)) * 64;     // 6272 for n=50000
    const size_t cntSz = (size_t)NRANGE * NCHUNK * R * 4;           // 6.4 MB
    int* cnt_s = (int*)pre;
    int* cnt_d = (int*)(pre + align_up(cntSz, 256));
    int* cbase = (int*)(pre + 2 * align_up(cntSz, 256));

    const int aggGrid = (n + 3) / 4;

    if (R <= RMAX) {
        // ---- LDS-privatized preprocessing: zero global atomics ----
        const int E = (ne + NCHUNK - 1) / NCHUNK;
        k_hist<<<NRANGE * NCHUNK, 256, 0, stream>>>(src, dst, ne, R, E, cnt_s, cnt_d);
        k_reduce_norms<<<(NRANGE * R + 255) / 256, 256, 0, stream>>>(cnt_s, cnt_d, R, n,
                                                                     onrm, inrm, degd_sum);
        k_scan<<<1, 1024, 0, stream>>>(degd_sum, n, row_ptr);
        k_cursors<<<(NRANGE * R + 255) / 256, 256, 0, stream>>>(row_ptr, cnt_d, R, n, cbase);
        k_csr<<<NRANGE * NCHUNK, 256, 0, stream>>>(src, dst, ne, R, E, cbase, eidx);
    } else {
        // legacy atomic preprocessing (robustness only)
        int* degs   = cnt_s;          // reuse alias region
        int* degd   = cnt_s + n_pad;
        int* cursor = cnt_s + 2 * n_pad;
        hipMemsetAsync(degs, 0, (size_t)2 * n_pad * 4, stream);
        k_degrees_leg<<<(ne + 255) / 256, 256, 0, stream>>>(src, dst, ne, degs, degd);
        k_norms_leg<<<(n + 255) / 256, 256, 0, stream>>>(degs, degd, onrm, inrm, degd_sum, n);
        k_scan<<<1, 1024, 0, stream>>>(degd_sum, n, row_ptr);
        k_copy_int<<<(n + 255) / 256, 256, 0, stream>>>(row_ptr, cursor, n);
        k_build_csr_leg<<<(ne + 255) / 256, 256, 0, stream>>>(src, dst, ne, cursor, eidx);
    }

    if (use_mfma) {
        k_split_w_all<<<(73728 + 255) / 256, 256, 0, stream>>>(
            W0, W1, W2, W3, Wh0, Wl0, Wh1, Wl1, Wh2, Wl2, Wh3, Wl3);
        k_split_x<<<((n * 64) + 255) / 256, 256, 0, stream>>>(x, onrm, Ah, Al, n);

        const int mmGrid = n_pad / 128;
        // L0: 256 -> 128
        k_mm<256, 128><<<mmGrid, 256, 0, stream>>>(Ah, Al, Wh0, Wl0, hbuf, n);
        k_agg128_split<<<aggGrid, 256, 0, stream>>>(hbuf, row_ptr, eidx, inrm, onrm, b0, Ah, Al, n);
        // L1
        k_mm<128, 128><<<mmGrid, 256, 0, stream>>>(Ah, Al, Wh1, Wl1, hbuf, n);
        k_agg128_split<<<aggGrid, 256, 0, stream>>>(hbuf, row_ptr, eidx, inrm, onrm, b1, Ah, Al, n);
        // L2
        k_mm<128, 128><<<mmGrid, 256, 0, stream>>>(Ah, Al, Wh2, Wl2, hbuf, n);
        k_agg128_split<<<aggGrid, 256, 0, stream>>>(hbuf, row_ptr, eidx, inrm, onrm, b2, Ah, Al, n);
        // L3: 128 -> 64
        k_mm<128, 64><<<mmGrid, 256, 0, stream>>>(Ah, Al, Wh3, Wl3, hbuf, n);
        k_agg64<<<aggGrid, 256, 0, stream>>>(hbuf, row_ptr, eidx, inrm, b3, (float*)d_out, n);
    } else {
        // fp32 fallback
        off = off_save;
        float* hbufF  = (float*)take((size_t)n * 128 * 4);
        float* xnextF = (float*)take((size_t)n * 128 * 4);

        k_matmul<256, 128, 32, 8, 4><<<(n + 31) / 32, dim3(32, 8), 0, stream>>>(x, W0, onrm, hbufF, n);
        k_agg128f<<<aggGrid, 256, 0, stream>>>(hbufF, row_ptr, eidx, inrm, b0, xnextF, n, 1);
        k_matmul<128, 128, 32, 8, 4><<<(n + 31) / 32, dim3(32, 8), 0, stream>>>(xnextF, W1, onrm, hbufF, n);
        k_agg128f<<<aggGrid, 256, 0, stream>>>(hbufF, row_ptr, eidx, inrm, b1, xnextF, n, 1);
        k_matmul<128, 128, 32, 8, 4><<<(n + 31) / 32, dim3(32, 8), 0, stream>>>(xnextF, W2, onrm, hbufF, n);
        k_agg128f<<<aggGrid, 256, 0, stream>>>(hbufF, row_ptr, eidx, inrm, b2, xnextF, n, 1);
        k_matmul<128, 64, 16, 16, 4><<<(n + 63) / 64, dim3(16, 16), 0, stream>>>(xnextF, W3, onrm, hbufF, n);
        k_agg64f<<<aggGrid, 256, 0, stream>>>(hbufF, row_ptr, eidx, inrm, b3, (float*)d_out, n);
    }
}

// Round 7
// 382.399 us; speedup vs baseline: 2.0865x; 1.1545x over previous
//
#include <hip/hip_runtime.h>
#include <hip/hip_fp16.h>

// ---------------------------------------------------------------------------
// GCN 4-layer forward on MI355X (gfx950).
//   Preprocess (ZERO global atomics): LDS range histograms (8 ranges x 64
//     chunks) + per-edge bucket rank (pos = LDS atomic return) ->
//     reduce+norms -> scan -> per-(range,chunk) cursor bases ->
//     SINGLE-PASS CSR scatter (eidx[cbase+pos] = src, no re-read, no cursors).
//   Per layer : bf16-split MFMA GEMM (3-term, ~fp32 precision), B staged in
//               LDS (XOR-swizzled) -> h in fp16 -> CSR gather-sum with
//               2 nodes/wave, 32-lane rows (ushort4: one vmem instr = 2 rows),
//               x8 unrolled, fp32 accum, fused epilogue + bf16 hi/lo split.
// ---------------------------------------------------------------------------

typedef __attribute__((ext_vector_type(8))) short short8;
typedef __attribute__((ext_vector_type(4))) float f32x4;

#define NRANGE 8
#define NCHUNK 64
#define RMAX   6272   // 8*6272 = 50176 >= 50000 nodes

__device__ inline unsigned short bf16_rne(float v) {
    union { float f; unsigned u; } c; c.f = v;
    unsigned u = c.u;
    unsigned lsb = (u >> 16) & 1u;
    u += 0x7fffu + lsb;
    return (unsigned short)(u >> 16);
}
__device__ inline float bf16_to_f(unsigned short h) {
    union { unsigned u; float f; } c; c.u = ((unsigned)h) << 16;
    return c.f;
}
__device__ inline void split_bf16(float v, unsigned short& hi, unsigned short& lo) {
    hi = bf16_rne(v);
    lo = bf16_rne(v - bf16_to_f(hi));
}

// ---------------------------------------------------------------------------
// Preprocessing — LDS-privatized histograms + per-edge bucket rank.
// ---------------------------------------------------------------------------

__global__ __launch_bounds__(256) void k_hist(const int* __restrict__ src,
                                              const int* __restrict__ dst,
                                              int ne, int R, int E,
                                              int* __restrict__ cnt_s,
                                              int* __restrict__ cnt_d,
                                              int* __restrict__ pos) {
    __shared__ int hs[RMAX];
    __shared__ int hd[RMAX];
    int r = blockIdx.x & (NRANGE - 1);
    int c = blockIdx.x >> 3;
    int tid = threadIdx.x;
    for (int i = tid; i < R; i += 256) { hs[i] = 0; hd[i] = 0; }
    __syncthreads();
    int lo = r * R, hi = lo + R;
    int e0 = c * E, e1 = min(e0 + E, ne);
    for (int i = e0 + tid; i < e1; i += 256) {
        int s = src[i], d = dst[i];
        if (s >= lo && s < hi) atomicAdd(&hs[s - lo], 1);
        if (d >= lo && d < hi) {
            int p = atomicAdd(&hd[d - lo], 1);
            pos[i] = p;                     // rank within (r,c,node) bucket
        }
    }
    __syncthreads();
    int base = (r * NCHUNK + c) * R;
    for (int i = tid; i < R; i += 256) {
        cnt_s[base + i] = hs[i];
        cnt_d[base + i] = hd[i];
    }
}

// Reduce chunk counts -> norms + dst-degree array for the scan.
__global__ void k_reduce_norms(const int* __restrict__ cnt_s,
                               const int* __restrict__ cnt_d, int R, int n,
                               float* __restrict__ onrm, float* __restrict__ inrm,
                               int* __restrict__ degd_sum) {
    int i = blockIdx.x * blockDim.x + threadIdx.x;
    if (i >= NRANGE * R) return;
    int r = i / R, ip = i - r * R;
    int ds = 0, dd = 0;
    for (int c = 0; c < NCHUNK; ++c) {
        ds += cnt_s[(r * NCHUNK + c) * R + ip];
        dd += cnt_d[(r * NCHUNK + c) * R + ip];
    }
    degd_sum[i] = dd;
    if (i < n) {
        onrm[i] = rsqrtf((float)max(ds, 1));
        inrm[i] = rsqrtf((float)max(dd, 1));
    }
}

// Single-block exclusive scan, int4 per thread.
__global__ __launch_bounds__(1024) void k_scan(const int* __restrict__ deg, int n,
                                               int* __restrict__ row_ptr) {
    __shared__ int wsum[16];
    __shared__ int carry;
    int tid = threadIdx.x;
    int lane = tid & 63;
    int wid = tid >> 6;
    if (tid == 0) carry = 0;
    __syncthreads();
    int n4 = (n + 3) >> 2;
    for (int base = 0; base < n4; base += 1024) {
        int i4 = base + tid;
        int4 v = make_int4(0, 0, 0, 0);
        if (i4 < n4) v = ((const int4*)deg)[i4];
        int s = v.x + v.y + v.z + v.w;
        int x = s;
#pragma unroll
        for (int off = 1; off < 64; off <<= 1) {
            int y = __shfl_up(x, off, 64);
            if (lane >= off) x += y;
        }
        if (lane == 63) wsum[wid] = x;
        __syncthreads();
        if (wid == 0 && lane < 16) {
            int w = wsum[lane];
#pragma unroll
            for (int off = 1; off < 16; off <<= 1) {
                int y = __shfl_up(w, off, 16);
                if (lane >= off) w += y;
            }
            wsum[lane] = w;
        }
        __syncthreads();
        int excl = x - s + carry + (wid > 0 ? wsum[wid - 1] : 0);
        if (i4 < n4) {
            int e0 = excl, e1 = e0 + v.x, e2 = e1 + v.y, e3 = e2 + v.z;
            ((int4*)row_ptr)[i4] = make_int4(e0, e1, e2, e3);
        }
        __syncthreads();
        if (tid == 0) carry += wsum[15];
        __syncthreads();
    }
    if (tid == 0) row_ptr[n] = carry;
}

// Per-(node,chunk) cursor base: cbase[r][c][ip] = row_ptr + prefix of counts.
__global__ void k_cursors(const int* __restrict__ row_ptr,
                          const int* __restrict__ cnt_d, int R, int n,
                          int* __restrict__ cbase) {
    int i = blockIdx.x * blockDim.x + threadIdx.x;
    if (i >= NRANGE * R) return;
    int r = i / R, ip = i - r * R;
    int run = (i < n) ? row_ptr[i] : 0;
    for (int c = 0; c < NCHUNK; ++c) {
        int idx = (r * NCHUNK + c) * R + ip;
        cbase[idx] = run;
        run += cnt_d[idx];
    }
}

// Single-pass CSR scatter: eidx[cbase + pos] = src. No re-read, no cursors.
__global__ void k_csr_scatter(const int* __restrict__ src,
                              const int* __restrict__ dst,
                              const int* __restrict__ pos,
                              const int* __restrict__ cbase,
                              int ne, int R, int E,
                              int* __restrict__ eidx) {
    int i = blockIdx.x * blockDim.x + threadIdx.x;
    if (i >= ne) return;
    int d = dst[i];
    int r = d / R, ip = d - r * R;
    int c = i / E;
    eidx[cbase[(r * NCHUNK + c) * R + ip] + pos[i]] = src[i];
}

// ---------------------------------------------------------------------------
// bf16 split helpers (MFMA path)
// ---------------------------------------------------------------------------

__global__ __launch_bounds__(256) void k_split_x(const float* __restrict__ x,
                                                 const float* __restrict__ onrm,
                                                 unsigned short* __restrict__ Ah,
                                                 unsigned short* __restrict__ Al, int n) {
    int i4 = blockIdx.x * blockDim.x + threadIdx.x;  // float4 index, 64 per row
    int row = i4 >> 6;
    if (row >= n) return;
    float4 v = ((const float4*)x)[i4];
    float s = onrm[row];
    unsigned short h0, l0, h1, l1, h2, l2, h3, l3;
    split_bf16(v.x * s, h0, l0);
    split_bf16(v.y * s, h1, l1);
    split_bf16(v.z * s, h2, l2);
    split_bf16(v.w * s, h3, l3);
    ushort4 hv, lv;
    hv.x = h0; hv.y = h1; hv.z = h2; hv.w = h3;
    lv.x = l0; lv.y = l1; lv.z = l2; lv.w = l3;
    ((ushort4*)Ah)[i4] = hv;
    ((ushort4*)Al)[i4] = lv;
}

__global__ void k_split_w_all(const float* __restrict__ W0, const float* __restrict__ W1,
                              const float* __restrict__ W2, const float* __restrict__ W3,
                              unsigned short* __restrict__ Wh0, unsigned short* __restrict__ Wl0,
                              unsigned short* __restrict__ Wh1, unsigned short* __restrict__ Wl1,
                              unsigned short* __restrict__ Wh2, unsigned short* __restrict__ Wl2,
                              unsigned short* __restrict__ Wh3, unsigned short* __restrict__ Wl3) {
    int i = blockIdx.x * blockDim.x + threadIdx.x;
    const float* W; unsigned short *Wh, *Wl; int K, F, off;
    if (i < 32768)                    { W = W0; Wh = Wh0; Wl = Wl0; K = 256; F = 128; off = i; }
    else if (i < 32768 + 16384)       { W = W1; Wh = Wh1; Wl = Wl1; K = 128; F = 128; off = i - 32768; }
    else if (i < 32768 + 32768)       { W = W2; Wh = Wh2; Wl = Wl2; K = 128; F = 128; off = i - 49152; }
    else if (i < 32768 + 32768 + 8192){ W = W3; Wh = Wh3; Wl = Wl3; K = 128; F = 64;  off = i - 65536; }
    else return;
    int k = off / F, c = off % F;
    unsigned short h, l;
    split_bf16(W[k * F + c], h, l);
    Wh[c * K + k] = h;
    Wl[c * K + k] = l;
}

// ---------------------------------------------------------------------------
// MFMA GEMM: H[m][c] = sum_k A[m][k]*W[k][c]; H stored fp16.
// ---------------------------------------------------------------------------
template <int K, int N>
__global__ __launch_bounds__(256) void k_mm(const unsigned short* __restrict__ Ah,
                                            const unsigned short* __restrict__ Al,
                                            const unsigned short* __restrict__ Bh,
                                            const unsigned short* __restrict__ Bl,
                                            __half* __restrict__ H, int n) {
    constexpr int KT = 128;
    constexpr int NT = N / 16;
    constexpr int NKT = K / KT;
    __shared__ unsigned short sBh[N * KT];
    __shared__ unsigned short sBl[N * KT];

    int tid = threadIdx.x;
    int w = tid >> 6, lane = tid & 63;
    int quad = lane >> 4, l16 = lane & 15;
    int row_base = blockIdx.x * 128 + w * 32;

    int ar0 = row_base + l16;
    int ar1 = row_base + 16 + l16;
    if (ar0 >= n) ar0 = n - 1;
    if (ar1 >= n) ar1 = n - 1;

    f32x4 acc[2][NT];
#pragma unroll
    for (int m = 0; m < 2; ++m)
#pragma unroll
        for (int t = 0; t < NT; ++t) acc[m][t] = (f32x4){0.f, 0.f, 0.f, 0.f};

    for (int kt = 0; kt < NKT; ++kt) {
        if (kt) __syncthreads();
        for (int idx = tid; idx < N * 16; idx += 256) {
            int c = idx >> 4;
            int g = idx & 15;
            short8 vh = *(const short8*)(Bh + (size_t)c * K + kt * KT + g * 8);
            short8 vl = *(const short8*)(Bl + (size_t)c * K + kt * KT + g * 8);
            int sg = g ^ (c & 15);
            *(short8*)(&sBh[c * KT + sg * 8]) = vh;
            *(short8*)(&sBl[c * KT + sg * 8]) = vl;
        }
        __syncthreads();

        const unsigned short* a0h = Ah + (size_t)ar0 * K + kt * KT;
        const unsigned short* a0l = Al + (size_t)ar0 * K + kt * KT;
        const unsigned short* a1h = Ah + (size_t)ar1 * K + kt * KT;
        const unsigned short* a1l = Al + (size_t)ar1 * K + kt * KT;

#pragma unroll
        for (int k0 = 0; k0 < KT; k0 += 32) {
            int eoff = k0 + quad * 8;
            short8 a0hv = *(const short8*)(a0h + eoff);
            short8 a0lv = *(const short8*)(a0l + eoff);
            short8 a1hv = *(const short8*)(a1h + eoff);
            short8 a1lv = *(const short8*)(a1l + eoff);
            int g = (k0 >> 3) + quad;
            int sg8 = (g ^ l16) * 8;
#pragma unroll
            for (int t = 0; t < NT; ++t) {
                int cb = (t * 16 + l16) * KT;
                short8 bh = *(const short8*)(&sBh[cb + sg8]);
                short8 bl = *(const short8*)(&sBl[cb + sg8]);
                acc[0][t] = __builtin_amdgcn_mfma_f32_16x16x32_bf16(a0hv, bh, acc[0][t], 0, 0, 0);
                acc[0][t] = __builtin_amdgcn_mfma_f32_16x16x32_bf16(a0lv, bh, acc[0][t], 0, 0, 0);
                acc[0][t] = __builtin_amdgcn_mfma_f32_16x16x32_bf16(a0hv, bl, acc[0][t], 0, 0, 0);
                acc[1][t] = __builtin_amdgcn_mfma_f32_16x16x32_bf16(a1hv, bh, acc[1][t], 0, 0, 0);
                acc[1][t] = __builtin_amdgcn_mfma_f32_16x16x32_bf16(a1lv, bh, acc[1][t], 0, 0, 0);
                acc[1][t] = __builtin_amdgcn_mfma_f32_16x16x32_bf16(a1hv, bl, acc[1][t], 0, 0, 0);
            }
        }
    }

#pragma unroll
    for (int m = 0; m < 2; ++m) {
#pragma unroll
        for (int t = 0; t < NT; ++t) {
#pragma unroll
            for (int r = 0; r < 4; ++r) {
                int grow = row_base + m * 16 + quad * 4 + r;
                if (grow < n) H[(size_t)grow * N + t * 16 + l16] = __float2half(acc[m][t][r]);
            }
        }
    }
}

// ---------------------------------------------------------------------------
// Aggregation: 2 nodes per wave (32 lanes each), 8B/lane row loads so one
// vmem instruction covers two 256B rows. x8 unrolled, fp32 accumulate.
// ---------------------------------------------------------------------------

__global__ __launch_bounds__(256) void k_agg128_split(const __half* __restrict__ h,
                                                      const int* __restrict__ row_ptr,
                                                      const int* __restrict__ eidx,
                                                      const float* __restrict__ inrm,
                                                      const float* __restrict__ onrm,
                                                      const float* __restrict__ bias,
                                                      unsigned short* __restrict__ Ah,
                                                      unsigned short* __restrict__ Al, int n) {
    int wave = threadIdx.x >> 6;
    int lane = threadIdx.x & 63;
    int half = lane >> 5;
    int l = lane & 31;
    int node = blockIdx.x * 8 + wave * 2 + half;
    bool valid = node < n;
    int nd = valid ? node : n - 1;
    int beg = row_ptr[nd], end = row_ptr[nd + 1];
    const ushort4* h4 = (const ushort4*)h;   // row = 32 ushort4 granules

    float a0[8], a1[8], a2[8], a3[8];
#pragma unroll
    for (int u = 0; u < 8; ++u) { a0[u] = 0.f; a1[u] = 0.f; a2[u] = 0.f; a3[u] = 0.f; }
    int j = beg;
    for (; j + 8 <= end; j += 8) {
        int s[8];
#pragma unroll
        for (int u = 0; u < 8; ++u) s[u] = eidx[j + u];
        ushort4 v[8];
#pragma unroll
        for (int u = 0; u < 8; ++u) v[u] = h4[(size_t)s[u] * 32 + l];
#pragma unroll
        for (int u = 0; u < 8; ++u) {
            __half2* ph = reinterpret_cast<__half2*>(&v[u]);
            float2 f0 = __half22float2(ph[0]);
            float2 f1 = __half22float2(ph[1]);
            a0[u] += f0.x; a1[u] += f0.y; a2[u] += f1.x; a3[u] += f1.y;
        }
    }
    for (; j < end; ++j) {
        ushort4 v = h4[(size_t)eidx[j] * 32 + l];
        __half2* ph = reinterpret_cast<__half2*>(&v);
        float2 f0 = __half22float2(ph[0]);
        float2 f1 = __half22float2(ph[1]);
        a0[0] += f0.x; a1[0] += f0.y; a2[0] += f1.x; a3[0] += f1.y;
    }
    float s0 = ((a0[0] + a0[1]) + (a0[2] + a0[3])) + ((a0[4] + a0[5]) + (a0[6] + a0[7]));
    float s1 = ((a1[0] + a1[1]) + (a1[2] + a1[3])) + ((a1[4] + a1[5]) + (a1[6] + a1[7]));
    float s2 = ((a2[0] + a2[1]) + (a2[2] + a2[3])) + ((a2[4] + a2[5]) + (a2[6] + a2[7]));
    float s3 = ((a3[0] + a3[1]) + (a3[2] + a3[3])) + ((a3[4] + a3[5]) + (a3[6] + a3[7]));

    float nrm = inrm[nd];
    float on = onrm[nd];
    float4 b4 = ((const float4*)bias)[l];
    float o0 = fmaxf(s0 * nrm + b4.x, 0.f) * on;
    float o1 = fmaxf(s1 * nrm + b4.y, 0.f) * on;
    float o2 = fmaxf(s2 * nrm + b4.z, 0.f) * on;
    float o3 = fmaxf(s3 * nrm + b4.w, 0.f) * on;
    ushort4 hv, lv;
    split_bf16(o0, hv.x, lv.x);
    split_bf16(o1, hv.y, lv.y);
    split_bf16(o2, hv.z, lv.z);
    split_bf16(o3, hv.w, lv.w);
    if (valid) {
        ((ushort4*)Ah)[(size_t)node * 32 + l] = hv;
        ((ushort4*)Al)[(size_t)node * 32 + l] = lv;
    }
}

__global__ __launch_bounds__(256) void k_agg64(const __half* __restrict__ h,
                                               const int* __restrict__ row_ptr,
                                               const int* __restrict__ eidx,
                                               const float* __restrict__ inrm,
                                               const float* __restrict__ bias,
                                               float* __restrict__ out, int n) {
    int wave = threadIdx.x >> 6;
    int lane = threadIdx.x & 63;
    int half = lane >> 5;
    int l = lane & 31;
    int node = blockIdx.x * 8 + wave * 2 + half;
    bool valid = node < n;
    int nd = valid ? node : n - 1;
    int beg = row_ptr[nd], end = row_ptr[nd + 1];
    const __half2* h2 = (const __half2*)h;   // row = 32 half2 granules

    float a0[8], a1[8];
#pragma unroll
    for (int u = 0; u < 8; ++u) { a0[u] = 0.f; a1[u] = 0.f; }
    int j = beg;
    for (; j + 8 <= end; j += 8) {
        int s[8];
#pragma unroll
        for (int u = 0; u < 8; ++u) s[u] = eidx[j + u];
        __half2 v[8];
#pragma unroll
        for (int u = 0; u < 8; ++u) v[u] = h2[(size_t)s[u] * 32 + l];
#pragma unroll
        for (int u = 0; u < 8; ++u) {
            float2 f = __half22float2(v[u]);
            a0[u] += f.x; a1[u] += f.y;
        }
    }
    for (; j < end; ++j) {
        float2 f = __half22float2(h2[(size_t)eidx[j] * 32 + l]);
        a0[0] += f.x; a1[0] += f.y;
    }
    float s0 = ((a0[0] + a0[1]) + (a0[2] + a0[3])) + ((a0[4] + a0[5]) + (a0[6] + a0[7]));
    float s1 = ((a1[0] + a1[1]) + (a1[2] + a1[3])) + ((a1[4] + a1[5]) + (a1[6] + a1[7]));

    float nrm = inrm[nd];
    float2 b2 = ((const float2*)bias)[l];
    float2 o;
    o.x = s0 * nrm + b2.x;
    o.y = s1 * nrm + b2.y;
    if (valid) ((float2*)out)[(size_t)node * 32 + l] = o;
}

// ---------------------------------------------------------------------------
// Fallback fp32 path (known-good) — used if workspace too small for MFMA path.
// ---------------------------------------------------------------------------
template <int K, int FO, int TX, int TY, int RPT>
__global__ __launch_bounds__(256) void k_matmul(const float* __restrict__ X,
                                                const float* __restrict__ W,
                                                const float* __restrict__ onrm,
                                                float* __restrict__ H, int n) {
    constexpr int BROWS = TY * RPT;
    constexpr int LDK = K + 1;
    __shared__ float xs[BROWS * LDK];
    int tx = threadIdx.x, ty = threadIdx.y;
    int tid = ty * TX + tx;
    int row0 = blockIdx.x * BROWS;

    for (int idx = tid; idx < BROWS * K; idx += 256) {
        int r = idx / K;
        int k = idx - r * K;
        int row = row0 + r;
        xs[r * LDK + k] = (row < n) ? X[(size_t)row * K + k] : 0.f;
    }
    __syncthreads();

    float4 acc[RPT];
#pragma unroll
    for (int r = 0; r < RPT; ++r) acc[r] = make_float4(0.f, 0.f, 0.f, 0.f);

    const float4* W4 = (const float4*)W;
#pragma unroll 4
    for (int k = 0; k < K; ++k) {
        float4 w = W4[k * (FO / 4) + tx];
#pragma unroll
        for (int r = 0; r < RPT; ++r) {
            float xv = xs[(ty * RPT + r) * LDK + k];
            acc[r].x += xv * w.x;
            acc[r].y += xv * w.y;
            acc[r].z += xv * w.z;
            acc[r].w += xv * w.w;
        }
    }

#pragma unroll
    for (int r = 0; r < RPT; ++r) {
        int row = row0 + ty * RPT + r;
        if (row < n) {
            float s = onrm[row];
            float4 o = make_float4(acc[r].x * s, acc[r].y * s, acc[r].z * s, acc[r].w * s);
            ((float4*)H)[(size_t)row * (FO / 4) + tx] = o;
        }
    }
}

__global__ __launch_bounds__(256) void k_agg128f(const float* __restrict__ h,
                                                 const int* __restrict__ row_ptr,
                                                 const int* __restrict__ eidx,
                                                 const float* __restrict__ inrm,
                                                 const float* __restrict__ bias,
                                                 float* __restrict__ out, int n, int relu) {
    int node = blockIdx.x * 4 + (threadIdx.x >> 6);
    int lane = threadIdx.x & 63;
    if (node >= n) return;
    int beg = row_ptr[node], end = row_ptr[node + 1];
    const float2* h2 = (const float2*)h;
    float ax = 0.f, ay = 0.f;
    for (int j = beg; j < end; ++j) {
        int s = eidx[j];
        float2 v = h2[(size_t)s * 64 + lane];
        ax += v.x;
        ay += v.y;
    }
    float nrm = inrm[node];
    float2 b2 = ((const float2*)bias)[lane];
    float ox = ax * nrm + b2.x;
    float oy = ay * nrm + b2.y;
    if (relu) { ox = fmaxf(ox, 0.f); oy = fmaxf(oy, 0.f); }
    float2 o; o.x = ox; o.y = oy;
    ((float2*)out)[(size_t)node * 64 + lane] = o;
}

__global__ __launch_bounds__(256) void k_agg64f(const float* __restrict__ h,
                                                const int* __restrict__ row_ptr,
                                                const int* __restrict__ eidx,
                                                const float* __restrict__ inrm,
                                                const float* __restrict__ bias,
                                                float* __restrict__ out, int n) {
    int node = blockIdx.x * 4 + (threadIdx.x >> 6);
    int lane = threadIdx.x & 63;
    if (node >= n) return;
    int beg = row_ptr[node], end = row_ptr[node + 1];
    float acc = 0.f;
    for (int j = beg; j < end; ++j) {
        int s = eidx[j];
        acc += h[(size_t)s * 64 + lane];
    }
    out[(size_t)node * 64 + lane] = acc * inrm[node] + bias[lane];
}

// Legacy atomic preprocessing (only if n > NRANGE*RMAX; never for this problem)
__global__ void k_degrees_leg(const int* __restrict__ src, const int* __restrict__ dst,
                              int ne, int* __restrict__ degs, int* __restrict__ degd) {
    int i = blockIdx.x * blockDim.x + threadIdx.x;
    if (i < ne) {
        atomicAdd(&degs[src[i]], 1);
        atomicAdd(&degd[dst[i]], 1);
    }
}
__global__ void k_norms_leg(const int* __restrict__ degs, const int* __restrict__ degd,
                            float* __restrict__ onrm, float* __restrict__ inrm,
                            int* __restrict__ degd_sum, int n) {
    int i = blockIdx.x * blockDim.x + threadIdx.x;
    if (i < n) {
        degd_sum[i] = degd[i];
        onrm[i] = rsqrtf((float)max(degs[i], 1));
        inrm[i] = rsqrtf((float)max(degd[i], 1));
    }
}
__global__ void k_copy_int(const int* __restrict__ a, int* __restrict__ b, int n) {
    int i = blockIdx.x * blockDim.x + threadIdx.x;
    if (i < n) b[i] = a[i];
}
__global__ void k_build_csr_leg(const int* __restrict__ src, const int* __restrict__ dst,
                                int ne, int* __restrict__ cursor, int* __restrict__ eidx) {
    int i = blockIdx.x * blockDim.x + threadIdx.x;
    if (i < ne) {
        int p = atomicAdd(&cursor[dst[i]], 1);
        eidx[p] = src[i];
    }
}

static inline size_t align_up(size_t v, size_t a) { return (v + a - 1) & ~(a - 1); }

extern "C" void kernel_launch(void* const* d_in, const int* in_sizes, int n_in,
                              void* d_out, int out_size, void* d_ws, size_t ws_size,
                              hipStream_t stream) {
    const float* x  = (const float*)d_in[0];
    const int* ei   = (const int*)d_in[1];
    const float* W0 = (const float*)d_in[2];
    const float* b0 = (const float*)d_in[3];
    const float* W1 = (const float*)d_in[4];
    const float* b1 = (const float*)d_in[5];
    const float* W2 = (const float*)d_in[6];
    const float* b2 = (const float*)d_in[7];
    const float* W3 = (const float*)d_in[8];
    const float* b3 = (const float*)d_in[9];

    const int n  = in_sizes[0] / 256;   // 50000
    const int ne = in_sizes[1] / 2;     // 800000
    const int n_pad = (n + 127) & ~127;
    const int* src = ei;
    const int* dst = ei + ne;

    // ---- shared layout ----
    char* ws = (char*)d_ws;
    size_t off = 0;
    auto take = [&](size_t bytes) { void* p = ws + off; off = align_up(off + bytes, 256); return p; };
    int* row_ptr  = (int*)take((size_t)(n_pad + 4) * 4);
    int* degd_sum = (int*)take((size_t)n_pad * 4);
    int* eidx     = (int*)take((size_t)ne * 4);
    float* onrm   = (float*)take((size_t)n * 4);
    float* inrm   = (float*)take((size_t)n * 4);

    // ---- MFMA-path layout ----
    size_t off_save = off;
    unsigned short* Ah  = (unsigned short*)take((size_t)n_pad * 256 * 2);
    unsigned short* Al  = (unsigned short*)take((size_t)n_pad * 256 * 2);
    __half* hbuf        = (__half*)take((size_t)n * 128 * 2);
    unsigned short* Wh0 = (unsigned short*)take(256 * 128 * 2);
    unsigned short* Wl0 = (unsigned short*)take(256 * 128 * 2);
    unsigned short* Wh1 = (unsigned short*)take(128 * 128 * 2);
    unsigned short* Wl1 = (unsigned short*)take(128 * 128 * 2);
    unsigned short* Wh2 = (unsigned short*)take(128 * 128 * 2);
    unsigned short* Wl2 = (unsigned short*)take(128 * 128 * 2);
    unsigned short* Wh3 = (unsigned short*)take(128 * 64 * 2);
    unsigned short* Wl3 = (unsigned short*)take(128 * 64 * 2);
    bool use_mfma = (off <= ws_size);

    // ---- preprocessing scratch ALIASED onto Ah/Al (51.2 MB; dead until
    //      k_split_x, which runs after preprocessing) ----
    char* pre = (char*)Ah;
    const int R = ((n + NRANGE * 64 - 1) / (NRANGE * 64)) * 64;     // 6272 for n=50000
    const size_t cntSz = align_up((size_t)NRANGE * NCHUNK * R * 4, 256);  // 12.85 MB
    int* cnt_s = (int*)pre;
    int* cnt_d = (int*)(pre + cntSz);
    int* cbase = (int*)(pre + 2 * cntSz);
    int* pos   = (int*)(pre + 3 * cntSz);

    const int aggGrid = (n + 7) / 8;

    if (R <= RMAX) {
        // ---- LDS-privatized preprocessing: zero global atomics ----
        const int E = (ne + NCHUNK - 1) / NCHUNK;
        k_hist<<<NRANGE * NCHUNK, 256, 0, stream>>>(src, dst, ne, R, E, cnt_s, cnt_d, pos);
        k_reduce_norms<<<(NRANGE * R + 255) / 256, 256, 0, stream>>>(cnt_s, cnt_d, R, n,
                                                                     onrm, inrm, degd_sum);
        k_scan<<<1, 1024, 0, stream>>>(degd_sum, n, row_ptr);
        k_cursors<<<(NRANGE * R + 255) / 256, 256, 0, stream>>>(row_ptr, cnt_d, R, n, cbase);
        k_csr_scatter<<<(ne + 255) / 256, 256, 0, stream>>>(src, dst, pos, cbase, ne, R, E, eidx);
    } else {
        // legacy atomic preprocessing (robustness only)
        int* degs   = cnt_s;
        int* degd   = cnt_s + n_pad;
        int* cursor = cnt_s + 2 * n_pad;
        hipMemsetAsync(degs, 0, (size_t)2 * n_pad * 4, stream);
        k_degrees_leg<<<(ne + 255) / 256, 256, 0, stream>>>(src, dst, ne, degs, degd);
        k_norms_leg<<<(n + 255) / 256, 256, 0, stream>>>(degs, degd, onrm, inrm, degd_sum, n);
        k_scan<<<1, 1024, 0, stream>>>(degd_sum, n, row_ptr);
        k_copy_int<<<(n + 255) / 256, 256, 0, stream>>>(row_ptr, cursor, n);
        k_build_csr_leg<<<(ne + 255) / 256, 256, 0, stream>>>(src, dst, ne, cursor, eidx);
    }

    if (use_mfma) {
        k_split_w_all<<<(73728 + 255) / 256, 256, 0, stream>>>(
            W0, W1, W2, W3, Wh0, Wl0, Wh1, Wl1, Wh2, Wl2, Wh3, Wl3);
        k_split_x<<<((n * 64) + 255) / 256, 256, 0, stream>>>(x, onrm, Ah, Al, n);

        const int mmGrid = n_pad / 128;
        // L0: 256 -> 128
        k_mm<256, 128><<<mmGrid, 256, 0, stream>>>(Ah, Al, Wh0, Wl0, hbuf, n);
        k_agg128_split<<<aggGrid, 256, 0, stream>>>(hbuf, row_ptr, eidx, inrm, onrm, b0, Ah, Al, n);
        // L1
        k_mm<128, 128><<<mmGrid, 256, 0, stream>>>(Ah, Al, Wh1, Wl1, hbuf, n);
        k_agg128_split<<<aggGrid, 256, 0, stream>>>(hbuf, row_ptr, eidx, inrm, onrm, b1, Ah, Al, n);
        // L2
        k_mm<128, 128><<<mmGrid, 256, 0, stream>>>(Ah, Al, Wh2, Wl2, hbuf, n);
        k_agg128_split<<<aggGrid, 256, 0, stream>>>(hbuf, row_ptr, eidx, inrm, onrm, b2, Ah, Al, n);
        // L3: 128 -> 64
        k_mm<128, 64><<<mmGrid, 256, 0, stream>>>(Ah, Al, Wh3, Wl3, hbuf, n);
        k_agg64<<<aggGrid, 256, 0, stream>>>(hbuf, row_ptr, eidx, inrm, b3, (float*)d_out, n);
    } else {
        // fp32 fallback
        off = off_save;
        float* hbufF  = (float*)take((size_t)n * 128 * 4);
        float* xnextF = (float*)take((size_t)n * 128 * 4);
        const int aggGridF = (n + 3) / 4;

        k_matmul<256, 128, 32, 8, 4><<<(n + 31) / 32, dim3(32, 8), 0, stream>>>(x, W0, onrm, hbufF, n);
        k_agg128f<<<aggGridF, 256, 0, stream>>>(hbufF, row_ptr, eidx, inrm, b0, xnextF, n, 1);
        k_matmul<128, 128, 32, 8, 4><<<(n + 31) / 32, dim3(32, 8), 0, stream>>>(xnextF, W1, onrm, hbufF, n);
        k_agg128f<<<aggGridF, 256, 0, stream>>>(hbufF, row_ptr, eidx, inrm, b1, xnextF, n, 1);
        k_matmul<128, 128, 32, 8, 4><<<(n + 31) / 32, dim3(32, 8), 0, stream>>>(xnextF, W2, onrm, hbufF, n);
        k_agg128f<<<aggGridF, 256, 0, stream>>>(hbufF, row_ptr, eidx, inrm, b2, xnextF, n, 1);
        k_matmul<128, 64, 16, 16, 4><<<(n + 63) / 64, dim3(16, 16), 0, stream>>>(xnextF, W3, onrm, hbufF, n);
        k_agg64f<<<aggGridF, 256, 0, stream>>>(hbufF, row_ptr, eidx, inrm, b3, (float*)d_out, n);
    }
}

// Round 8
// 359.100 us; speedup vs baseline: 2.2219x; 1.0649x over previous
//
#include <hip/hip_runtime.h>
#include <hip/hip_fp16.h>

// ---------------------------------------------------------------------------
// GCN 4-layer forward on MI355X (gfx950).
//   Preprocess (ZERO global atomics): LDS range histograms (8 ranges x 64
//     chunks) + per-edge bucket rank -> reduce+norms -> scan -> cursor bases
//     -> single-pass CSR scatter.
//   Per layer : bf16-split MFMA GEMM (3-term, ~fp32 precision), B staged in
//     LDS (XOR-swizzled); L0 reads x fp32 directly (split fused into A-load).
//     h in fp16 -> CSR gather with 16-lane/16B row segments (4 nodes/wave,
//     4 rows per vmem instr), fused epilogue + bf16 hi/lo split.
// ---------------------------------------------------------------------------

typedef __attribute__((ext_vector_type(8))) short short8;
typedef __attribute__((ext_vector_type(4))) float f32x4;

#define NRANGE 8
#define NCHUNK 64
#define RMAX   6272   // 8*6272 = 50176 >= 50000 nodes

__device__ inline unsigned short bf16_rne(float v) {
    union { float f; unsigned u; } c; c.f = v;
    unsigned u = c.u;
    unsigned lsb = (u >> 16) & 1u;
    u += 0x7fffu + lsb;
    return (unsigned short)(u >> 16);
}
__device__ inline float bf16_to_f(unsigned short h) {
    union { unsigned u; float f; } c; c.u = ((unsigned)h) << 16;
    return c.f;
}
__device__ inline void split_bf16(float v, unsigned short& hi, unsigned short& lo) {
    hi = bf16_rne(v);
    lo = bf16_rne(v - bf16_to_f(hi));
}

// ---------------------------------------------------------------------------
// Preprocessing — LDS-privatized histograms + per-edge bucket rank.
// ---------------------------------------------------------------------------

__global__ __launch_bounds__(256) void k_hist(const int* __restrict__ src,
                                              const int* __restrict__ dst,
                                              int ne, int R, int E,
                                              int* __restrict__ cnt_s,
                                              int* __restrict__ cnt_d,
                                              int* __restrict__ pos) {
    __shared__ int hs[RMAX];
    __shared__ int hd[RMAX];
    int r = blockIdx.x & (NRANGE - 1);
    int c = blockIdx.x >> 3;
    int tid = threadIdx.x;
    for (int i = tid; i < R; i += 256) { hs[i] = 0; hd[i] = 0; }
    __syncthreads();
    int lo = r * R, hi = lo + R;
    int e0 = c * E, e1 = min(e0 + E, ne);
    for (int i = e0 + tid; i < e1; i += 256) {
        int s = src[i], d = dst[i];
        if (s >= lo && s < hi) atomicAdd(&hs[s - lo], 1);
        if (d >= lo && d < hi) {
            int p = atomicAdd(&hd[d - lo], 1);
            pos[i] = p;                     // rank within (r,c,node) bucket
        }
    }
    __syncthreads();
    int base = (r * NCHUNK + c) * R;
    for (int i = tid; i < R; i += 256) {
        cnt_s[base + i] = hs[i];
        cnt_d[base + i] = hd[i];
    }
}

__global__ void k_reduce_norms(const int* __restrict__ cnt_s,
                               const int* __restrict__ cnt_d, int R, int n,
                               float* __restrict__ onrm, float* __restrict__ inrm,
                               int* __restrict__ degd_sum) {
    int i = blockIdx.x * blockDim.x + threadIdx.x;
    if (i >= NRANGE * R) return;
    int r = i / R, ip = i - r * R;
    int ds = 0, dd = 0;
    for (int c = 0; c < NCHUNK; ++c) {
        ds += cnt_s[(r * NCHUNK + c) * R + ip];
        dd += cnt_d[(r * NCHUNK + c) * R + ip];
    }
    degd_sum[i] = dd;
    if (i < n) {
        onrm[i] = rsqrtf((float)max(ds, 1));
        inrm[i] = rsqrtf((float)max(dd, 1));
    }
}

// Single-block exclusive scan, int4 per thread.
__global__ __launch_bounds__(1024) void k_scan(const int* __restrict__ deg, int n,
                                               int* __restrict__ row_ptr) {
    __shared__ int wsum[16];
    __shared__ int carry;
    int tid = threadIdx.x;
    int lane = tid & 63;
    int wid = tid >> 6;
    if (tid == 0) carry = 0;
    __syncthreads();
    int n4 = (n + 3) >> 2;
    for (int base = 0; base < n4; base += 1024) {
        int i4 = base + tid;
        int4 v = make_int4(0, 0, 0, 0);
        if (i4 < n4) v = ((const int4*)deg)[i4];
        int s = v.x + v.y + v.z + v.w;
        int x = s;
#pragma unroll
        for (int off = 1; off < 64; off <<= 1) {
            int y = __shfl_up(x, off, 64);
            if (lane >= off) x += y;
        }
        if (lane == 63) wsum[wid] = x;
        __syncthreads();
        if (wid == 0 && lane < 16) {
            int w = wsum[lane];
#pragma unroll
            for (int off = 1; off < 16; off <<= 1) {
                int y = __shfl_up(w, off, 16);
                if (lane >= off) w += y;
            }
            wsum[lane] = w;
        }
        __syncthreads();
        int excl = x - s + carry + (wid > 0 ? wsum[wid - 1] : 0);
        if (i4 < n4) {
            int e0 = excl, e1 = e0 + v.x, e2 = e1 + v.y, e3 = e2 + v.z;
            ((int4*)row_ptr)[i4] = make_int4(e0, e1, e2, e3);
        }
        __syncthreads();
        if (tid == 0) carry += wsum[15];
        __syncthreads();
    }
    if (tid == 0) row_ptr[n] = carry;
}

__global__ void k_cursors(const int* __restrict__ row_ptr,
                          const int* __restrict__ cnt_d, int R, int n,
                          int* __restrict__ cbase) {
    int i = blockIdx.x * blockDim.x + threadIdx.x;
    if (i >= NRANGE * R) return;
    int r = i / R, ip = i - r * R;
    int run = (i < n) ? row_ptr[i] : 0;
    for (int c = 0; c < NCHUNK; ++c) {
        int idx = (r * NCHUNK + c) * R + ip;
        cbase[idx] = run;
        run += cnt_d[idx];
    }
}

__global__ void k_csr_scatter(const int* __restrict__ src,
                              const int* __restrict__ dst,
                              const int* __restrict__ pos,
                              const int* __restrict__ cbase,
                              int ne, int R, int E,
                              int* __restrict__ eidx) {
    int i = blockIdx.x * blockDim.x + threadIdx.x;
    if (i >= ne) return;
    int d = dst[i];
    int r = d / R, ip = d - r * R;
    int c = i / E;
    eidx[cbase[(r * NCHUNK + c) * R + ip] + pos[i]] = src[i];
}

// ---------------------------------------------------------------------------
// Weight split (transposed, bf16 hi/lo)
// ---------------------------------------------------------------------------

__global__ void k_split_w_all(const float* __restrict__ W0, const float* __restrict__ W1,
                              const float* __restrict__ W2, const float* __restrict__ W3,
                              unsigned short* __restrict__ Wh0, unsigned short* __restrict__ Wl0,
                              unsigned short* __restrict__ Wh1, unsigned short* __restrict__ Wl1,
                              unsigned short* __restrict__ Wh2, unsigned short* __restrict__ Wl2,
                              unsigned short* __restrict__ Wh3, unsigned short* __restrict__ Wl3) {
    int i = blockIdx.x * blockDim.x + threadIdx.x;
    const float* W; unsigned short *Wh, *Wl; int K, F, off;
    if (i < 32768)                    { W = W0; Wh = Wh0; Wl = Wl0; K = 256; F = 128; off = i; }
    else if (i < 32768 + 16384)       { W = W1; Wh = Wh1; Wl = Wl1; K = 128; F = 128; off = i - 32768; }
    else if (i < 32768 + 32768)       { W = W2; Wh = Wh2; Wl = Wl2; K = 128; F = 128; off = i - 49152; }
    else if (i < 32768 + 32768 + 8192){ W = W3; Wh = Wh3; Wl = Wl3; K = 128; F = 64;  off = i - 65536; }
    else return;
    int k = off / F, c = off % F;
    unsigned short h, l;
    split_bf16(W[k * F + c], h, l);
    Wh[c * K + k] = h;
    Wl[c * K + k] = l;
}

// ---------------------------------------------------------------------------
// MFMA GEMM: H[m][c] = sum_k A[m][k]*W[k][c]; H stored fp16.
// FA=true: A read from fp32 X, *onrm + bf16 split fused into fragment load.
// ---------------------------------------------------------------------------
template <int K, int N, bool FA>
__global__ __launch_bounds__(256) void k_mm(const unsigned short* __restrict__ Ah,
                                            const unsigned short* __restrict__ Al,
                                            const float* __restrict__ Xf,
                                            const float* __restrict__ onrm,
                                            const unsigned short* __restrict__ Bh,
                                            const unsigned short* __restrict__ Bl,
                                            __half* __restrict__ H, int n) {
    constexpr int KT = 128;
    constexpr int NT = N / 16;
    constexpr int NKT = K / KT;
    __shared__ unsigned short sBh[N * KT];
    __shared__ unsigned short sBl[N * KT];

    int tid = threadIdx.x;
    int w = tid >> 6, lane = tid & 63;
    int quad = lane >> 4, l16 = lane & 15;
    int row_base = blockIdx.x * 128 + w * 32;

    int ar0 = row_base + l16;
    int ar1 = row_base + 16 + l16;
    if (ar0 >= n) ar0 = n - 1;
    if (ar1 >= n) ar1 = n - 1;

    float on0 = 0.f, on1 = 0.f;
    if (FA) { on0 = onrm[ar0]; on1 = onrm[ar1]; }

    f32x4 acc[2][NT];
#pragma unroll
    for (int m = 0; m < 2; ++m)
#pragma unroll
        for (int t = 0; t < NT; ++t) acc[m][t] = (f32x4){0.f, 0.f, 0.f, 0.f};

    for (int kt = 0; kt < NKT; ++kt) {
        if (kt) __syncthreads();
        for (int idx = tid; idx < N * 16; idx += 256) {
            int c = idx >> 4;
            int g = idx & 15;
            short8 vh = *(const short8*)(Bh + (size_t)c * K + kt * KT + g * 8);
            short8 vl = *(const short8*)(Bl + (size_t)c * K + kt * KT + g * 8);
            int sg = g ^ (c & 15);
            *(short8*)(&sBh[c * KT + sg * 8]) = vh;
            *(short8*)(&sBl[c * KT + sg * 8]) = vl;
        }
        __syncthreads();

#pragma unroll
        for (int k0 = 0; k0 < KT; k0 += 32) {
            int eoff = k0 + quad * 8;
            short8 a0hv, a0lv, a1hv, a1lv;
            if (FA) {
                const float* x0 = Xf + (size_t)ar0 * K + kt * KT + eoff;
                const float* x1 = Xf + (size_t)ar1 * K + kt * KT + eoff;
                float4 p00 = *(const float4*)x0;
                float4 p01 = *(const float4*)(x0 + 4);
                float4 p10 = *(const float4*)x1;
                float4 p11 = *(const float4*)(x1 + 4);
                float e0[8] = {p00.x, p00.y, p00.z, p00.w, p01.x, p01.y, p01.z, p01.w};
                float e1[8] = {p10.x, p10.y, p10.z, p10.w, p11.x, p11.y, p11.z, p11.w};
#pragma unroll
                for (int q = 0; q < 8; ++q) {
                    unsigned short hh, ll;
                    split_bf16(e0[q] * on0, hh, ll);
                    a0hv[q] = (short)hh; a0lv[q] = (short)ll;
                    split_bf16(e1[q] * on1, hh, ll);
                    a1hv[q] = (short)hh; a1lv[q] = (short)ll;
                }
            } else {
                a0hv = *(const short8*)(Ah + (size_t)ar0 * K + kt * KT + eoff);
                a0lv = *(const short8*)(Al + (size_t)ar0 * K + kt * KT + eoff);
                a1hv = *(const short8*)(Ah + (size_t)ar1 * K + kt * KT + eoff);
                a1lv = *(const short8*)(Al + (size_t)ar1 * K + kt * KT + eoff);
            }
            int g = (k0 >> 3) + quad;
            int sg8 = (g ^ l16) * 8;
#pragma unroll
            for (int t = 0; t < NT; ++t) {
                int cb = (t * 16 + l16) * KT;
                short8 bh = *(const short8*)(&sBh[cb + sg8]);
                short8 bl = *(const short8*)(&sBl[cb + sg8]);
                acc[0][t] = __builtin_amdgcn_mfma_f32_16x16x32_bf16(a0hv, bh, acc[0][t], 0, 0, 0);
                acc[0][t] = __builtin_amdgcn_mfma_f32_16x16x32_bf16(a0lv, bh, acc[0][t], 0, 0, 0);
                acc[0][t] = __builtin_amdgcn_mfma_f32_16x16x32_bf16(a0hv, bl, acc[0][t], 0, 0, 0);
                acc[1][t] = __builtin_amdgcn_mfma_f32_16x16x32_bf16(a1hv, bh, acc[1][t], 0, 0, 0);
                acc[1][t] = __builtin_amdgcn_mfma_f32_16x16x32_bf16(a1lv, bh, acc[1][t], 0, 0, 0);
                acc[1][t] = __builtin_amdgcn_mfma_f32_16x16x32_bf16(a1hv, bl, acc[1][t], 0, 0, 0);
            }
        }
    }

#pragma unroll
    for (int m = 0; m < 2; ++m) {
#pragma unroll
        for (int t = 0; t < NT; ++t) {
#pragma unroll
            for (int r = 0; r < 4; ++r) {
                int grow = row_base + m * 16 + quad * 4 + r;
                if (grow < n) H[(size_t)grow * N + t * 16 + l16] = __float2half(acc[m][t][r]);
            }
        }
    }
}

// ---------------------------------------------------------------------------
// Aggregation: 16-lane row segments, 4 nodes/wave. FO=128: 16B/lane (one
// dwordx4 = 4 rows/wave-instr), unroll 4 -> 16 rows in flight per wave at
// half the instruction count of the 32-lane version.
// ---------------------------------------------------------------------------

__global__ __launch_bounds__(256) void k_agg128_split(const __half* __restrict__ h,
                                                      const int* __restrict__ row_ptr,
                                                      const int* __restrict__ eidx,
                                                      const float* __restrict__ inrm,
                                                      const float* __restrict__ onrm,
                                                      const float* __restrict__ bias,
                                                      unsigned short* __restrict__ Ah,
                                                      unsigned short* __restrict__ Al, int n) {
    int wave = threadIdx.x >> 6;
    int lane = threadIdx.x & 63;
    int g = lane >> 4;
    int l = lane & 15;
    int node = blockIdx.x * 16 + wave * 4 + g;
    bool valid = node < n;
    int nd = valid ? node : n - 1;
    int beg = row_ptr[nd], end = row_ptr[nd + 1];
    const short8* h8 = (const short8*)h;   // row = 16 granules of 16B

    float a[4][8];
#pragma unroll
    for (int u = 0; u < 4; ++u)
#pragma unroll
        for (int c = 0; c < 8; ++c) a[u][c] = 0.f;

    int j = beg;
    for (; j + 4 <= end; j += 4) {
        int s[4];
#pragma unroll
        for (int u = 0; u < 4; ++u) s[u] = eidx[j + u];
        short8 v[4];
#pragma unroll
        for (int u = 0; u < 4; ++u) v[u] = h8[(size_t)s[u] * 16 + l];
#pragma unroll
        for (int u = 0; u < 4; ++u) {
            const __half2* ph = reinterpret_cast<const __half2*>(&v[u]);
#pragma unroll
            for (int p = 0; p < 4; ++p) {
                float2 f = __half22float2(ph[p]);
                a[u][2 * p] += f.x;
                a[u][2 * p + 1] += f.y;
            }
        }
    }
    for (; j < end; ++j) {
        short8 v = h8[(size_t)eidx[j] * 16 + l];
        const __half2* ph = reinterpret_cast<const __half2*>(&v);
#pragma unroll
        for (int p = 0; p < 4; ++p) {
            float2 f = __half22float2(ph[p]);
            a[0][2 * p] += f.x;
            a[0][2 * p + 1] += f.y;
        }
    }

    float nrm = inrm[nd];
    float on = onrm[nd];
    float4 b0 = ((const float4*)bias)[l * 2];
    float4 b1 = ((const float4*)bias)[l * 2 + 1];
    float bb[8] = {b0.x, b0.y, b0.z, b0.w, b1.x, b1.y, b1.z, b1.w};
    short8 hv, lv;
#pragma unroll
    for (int c = 0; c < 8; ++c) {
        float s = (a[0][c] + a[1][c]) + (a[2][c] + a[3][c]);
        float o = fmaxf(s * nrm + bb[c], 0.f) * on;
        unsigned short hh, ll;
        split_bf16(o, hh, ll);
        hv[c] = (short)hh;
        lv[c] = (short)ll;
    }
    if (valid) {
        ((short8*)Ah)[(size_t)node * 16 + l] = hv;
        ((short8*)Al)[(size_t)node * 16 + l] = lv;
    }
}

// FO=64 final layer: 16-lane x 8B segments (4 nodes/wave), unroll 8, fp32 out.
__global__ __launch_bounds__(256) void k_agg64(const __half* __restrict__ h,
                                               const int* __restrict__ row_ptr,
                                               const int* __restrict__ eidx,
                                               const float* __restrict__ inrm,
                                               const float* __restrict__ bias,
                                               float* __restrict__ out, int n) {
    int wave = threadIdx.x >> 6;
    int lane = threadIdx.x & 63;
    int g = lane >> 4;
    int l = lane & 15;
    int node = blockIdx.x * 16 + wave * 4 + g;
    bool valid = node < n;
    int nd = valid ? node : n - 1;
    int beg = row_ptr[nd], end = row_ptr[nd + 1];
    const ushort4* h4 = (const ushort4*)h;  // row = 16 granules of 8B

    float a[8][4];
#pragma unroll
    for (int u = 0; u < 8; ++u)
#pragma unroll
        for (int c = 0; c < 4; ++c) a[u][c] = 0.f;

    int j = beg;
    for (; j + 8 <= end; j += 8) {
        int s[8];
#pragma unroll
        for (int u = 0; u < 8; ++u) s[u] = eidx[j + u];
        ushort4 v[8];
#pragma unroll
        for (int u = 0; u < 8; ++u) v[u] = h4[(size_t)s[u] * 16 + l];
#pragma unroll
        for (int u = 0; u < 8; ++u) {
            const __half2* ph = reinterpret_cast<const __half2*>(&v[u]);
            float2 f0 = __half22float2(ph[0]);
            float2 f1 = __half22float2(ph[1]);
            a[u][0] += f0.x; a[u][1] += f0.y; a[u][2] += f1.x; a[u][3] += f1.y;
        }
    }
    for (; j < end; ++j) {
        ushort4 v = h4[(size_t)eidx[j] * 16 + l];
        const __half2* ph = reinterpret_cast<const __half2*>(&v);
        float2 f0 = __half22float2(ph[0]);
        float2 f1 = __half22float2(ph[1]);
        a[0][0] += f0.x; a[0][1] += f0.y; a[0][2] += f1.x; a[0][3] += f1.y;
    }

    float nrm = inrm[nd];
    float4 b4 = ((const float4*)bias)[l];
    float4 o;
    float s0 = ((a[0][0] + a[1][0]) + (a[2][0] + a[3][0])) + ((a[4][0] + a[5][0]) + (a[6][0] + a[7][0]));
    float s1 = ((a[0][1] + a[1][1]) + (a[2][1] + a[3][1])) + ((a[4][1] + a[5][1]) + (a[6][1] + a[7][1]));
    float s2 = ((a[0][2] + a[1][2]) + (a[2][2] + a[3][2])) + ((a[4][2] + a[5][2]) + (a[6][2] + a[7][2]));
    float s3 = ((a[0][3] + a[1][3]) + (a[2][3] + a[3][3])) + ((a[4][3] + a[5][3]) + (a[6][3] + a[7][3]));
    o.x = s0 * nrm + b4.x;
    o.y = s1 * nrm + b4.y;
    o.z = s2 * nrm + b4.z;
    o.w = s3 * nrm + b4.w;
    if (valid) ((float4*)out)[(size_t)node * 16 + l] = o;
}

// ---------------------------------------------------------------------------
// Fallback fp32 path (known-good) — used if workspace too small for MFMA path.
// ---------------------------------------------------------------------------
template <int K, int FO, int TX, int TY, int RPT>
__global__ __launch_bounds__(256) void k_matmul(const float* __restrict__ X,
                                                const float* __restrict__ W,
                                                const float* __restrict__ onrm,
                                                float* __restrict__ H, int n) {
    constexpr int BROWS = TY * RPT;
    constexpr int LDK = K + 1;
    __shared__ float xs[BROWS * LDK];
    int tx = threadIdx.x, ty = threadIdx.y;
    int tid = ty * TX + tx;
    int row0 = blockIdx.x * BROWS;

    for (int idx = tid; idx < BROWS * K; idx += 256) {
        int r = idx / K;
        int k = idx - r * K;
        int row = row0 + r;
        xs[r * LDK + k] = (row < n) ? X[(size_t)row * K + k] : 0.f;
    }
    __syncthreads();

    float4 acc[RPT];
#pragma unroll
    for (int r = 0; r < RPT; ++r) acc[r] = make_float4(0.f, 0.f, 0.f, 0.f);

    const float4* W4 = (const float4*)W;
#pragma unroll 4
    for (int k = 0; k < K; ++k) {
        float4 w = W4[k * (FO / 4) + tx];
#pragma unroll
        for (int r = 0; r < RPT; ++r) {
            float xv = xs[(ty * RPT + r) * LDK + k];
            acc[r].x += xv * w.x;
            acc[r].y += xv * w.y;
            acc[r].z += xv * w.z;
            acc[r].w += xv * w.w;
        }
    }

#pragma unroll
    for (int r = 0; r < RPT; ++r) {
        int row = row0 + ty * RPT + r;
        if (row < n) {
            float s = onrm[row];
            float4 o = make_float4(acc[r].x * s, acc[r].y * s, acc[r].z * s, acc[r].w * s);
            ((float4*)H)[(size_t)row * (FO / 4) + tx] = o;
        }
    }
}

__global__ __launch_bounds__(256) void k_agg128f(const float* __restrict__ h,
                                                 const int* __restrict__ row_ptr,
                                                 const int* __restrict__ eidx,
                                                 const float* __restrict__ inrm,
                                                 const float* __restrict__ bias,
                                                 float* __restrict__ out, int n, int relu) {
    int node = blockIdx.x * 4 + (threadIdx.x >> 6);
    int lane = threadIdx.x & 63;
    if (node >= n) return;
    int beg = row_ptr[node], end = row_ptr[node + 1];
    const float2* h2 = (const float2*)h;
    float ax = 0.f, ay = 0.f;
    for (int j = beg; j < end; ++j) {
        int s = eidx[j];
        float2 v = h2[(size_t)s * 64 + lane];
        ax += v.x;
        ay += v.y;
    }
    float nrm = inrm[node];
    float2 b2 = ((const float2*)bias)[lane];
    float ox = ax * nrm + b2.x;
    float oy = ay * nrm + b2.y;
    if (relu) { ox = fmaxf(ox, 0.f); oy = fmaxf(oy, 0.f); }
    float2 o; o.x = ox; o.y = oy;
    ((float2*)out)[(size_t)node * 64 + lane] = o;
}

__global__ __launch_bounds__(256) void k_agg64f(const float* __restrict__ h,
                                                const int* __restrict__ row_ptr,
                                                const int* __restrict__ eidx,
                                                const float* __restrict__ inrm,
                                                const float* __restrict__ bias,
                                                float* __restrict__ out, int n) {
    int node = blockIdx.x * 4 + (threadIdx.x >> 6);
    int lane = threadIdx.x & 63;
    if (node >= n) return;
    int beg = row_ptr[node], end = row_ptr[node + 1];
    float acc = 0.f;
    for (int j = beg; j < end; ++j) {
        int s = eidx[j];
        acc += h[(size_t)s * 64 + lane];
    }
    out[(size_t)node * 64 + lane] = acc * inrm[node] + bias[lane];
}

// Legacy atomic preprocessing (only if n > NRANGE*RMAX; never for this problem)
__global__ void k_degrees_leg(const int* __restrict__ src, const int* __restrict__ dst,
                              int ne, int* __restrict__ degs, int* __restrict__ degd) {
    int i = blockIdx.x * blockDim.x + threadIdx.x;
    if (i < ne) {
        atomicAdd(&degs[src[i]], 1);
        atomicAdd(&degd[dst[i]], 1);
    }
}
__global__ void k_norms_leg(const int* __restrict__ degs, const int* __restrict__ degd,
                            float* __restrict__ onrm, float* __restrict__ inrm,
                            int* __restrict__ degd_sum, int n) {
    int i = blockIdx.x * blockDim.x + threadIdx.x;
    if (i < n) {
        degd_sum[i] = degd[i];
        onrm[i] = rsqrtf((float)max(degs[i], 1));
        inrm[i] = rsqrtf((float)max(degd[i], 1));
    }
}
__global__ void k_copy_int(const int* __restrict__ a, int* __restrict__ b, int n) {
    int i = blockIdx.x * blockDim.x + threadIdx.x;
    if (i < n) b[i] = a[i];
}
__global__ void k_build_csr_leg(const int* __restrict__ src, const int* __restrict__ dst,
                                int ne, int* __restrict__ cursor, int* __restrict__ eidx) {
    int i = blockIdx.x * blockDim.x + threadIdx.x;
    if (i < ne) {
        int p = atomicAdd(&cursor[dst[i]], 1);
        eidx[p] = src[i];
    }
}

static inline size_t align_up(size_t v, size_t a) { return (v + a - 1) & ~(a - 1); }

extern "C" void kernel_launch(void* const* d_in, const int* in_sizes, int n_in,
                              void* d_out, int out_size, void* d_ws, size_t ws_size,
                              hipStream_t stream) {
    const float* x  = (const float*)d_in[0];
    const int* ei   = (const int*)d_in[1];
    const float* W0 = (const float*)d_in[2];
    const float* b0 = (const float*)d_in[3];
    const float* W1 = (const float*)d_in[4];
    const float* b1 = (const float*)d_in[5];
    const float* W2 = (const float*)d_in[6];
    const float* b2 = (const float*)d_in[7];
    const float* W3 = (const float*)d_in[8];
    const float* b3 = (const float*)d_in[9];

    const int n  = in_sizes[0] / 256;   // 50000
    const int ne = in_sizes[1] / 2;     // 800000
    const int n_pad = (n + 127) & ~127;
    const int* src = ei;
    const int* dst = ei + ne;

    // ---- shared layout ----
    char* ws = (char*)d_ws;
    size_t off = 0;
    auto take = [&](size_t bytes) { void* p = ws + off; off = align_up(off + bytes, 256); return p; };
    int* row_ptr  = (int*)take((size_t)(n_pad + 4) * 4);
    int* degd_sum = (int*)take((size_t)n_pad * 4);
    int* eidx     = (int*)take((size_t)ne * 4);
    float* onrm   = (float*)take((size_t)n * 4);
    float* inrm   = (float*)take((size_t)n * 4);

    // ---- MFMA-path layout ----
    size_t off_save = off;
    unsigned short* Ah  = (unsigned short*)take((size_t)n_pad * 256 * 2);
    unsigned short* Al  = (unsigned short*)take((size_t)n_pad * 256 * 2);
    __half* hbuf        = (__half*)take((size_t)n * 128 * 2);
    unsigned short* Wh0 = (unsigned short*)take(256 * 128 * 2);
    unsigned short* Wl0 = (unsigned short*)take(256 * 128 * 2);
    unsigned short* Wh1 = (unsigned short*)take(128 * 128 * 2);
    unsigned short* Wl1 = (unsigned short*)take(128 * 128 * 2);
    unsigned short* Wh2 = (unsigned short*)take(128 * 128 * 2);
    unsigned short* Wl2 = (unsigned short*)take(128 * 128 * 2);
    unsigned short* Wh3 = (unsigned short*)take(128 * 64 * 2);
    unsigned short* Wl3 = (unsigned short*)take(128 * 64 * 2);
    bool use_mfma = (off <= ws_size);

    // ---- preprocessing scratch ALIASED onto Ah/Al/hbuf (dead until mm0) ----
    char* pre = (char*)Ah;
    const int R = ((n + NRANGE * 64 - 1) / (NRANGE * 64)) * 64;     // 6272 for n=50000
    const size_t cntSz = align_up((size_t)NRANGE * NCHUNK * R * 4, 256);  // 12.85 MB
    int* cnt_s = (int*)pre;
    int* cnt_d = (int*)(pre + cntSz);
    int* cbase = (int*)(pre + 2 * cntSz);
    int* pos   = (int*)(pre + 3 * cntSz);

    const int aggGrid = (n + 15) / 16;

    if (R <= RMAX) {
        // ---- LDS-privatized preprocessing: zero global atomics ----
        const int E = (ne + NCHUNK - 1) / NCHUNK;
        k_hist<<<NRANGE * NCHUNK, 256, 0, stream>>>(src, dst, ne, R, E, cnt_s, cnt_d, pos);
        k_reduce_norms<<<(NRANGE * R + 255) / 256, 256, 0, stream>>>(cnt_s, cnt_d, R, n,
                                                                     onrm, inrm, degd_sum);
        k_scan<<<1, 1024, 0, stream>>>(degd_sum, n, row_ptr);
        k_cursors<<<(NRANGE * R + 255) / 256, 256, 0, stream>>>(row_ptr, cnt_d, R, n, cbase);
        k_csr_scatter<<<(ne + 255) / 256, 256, 0, stream>>>(src, dst, pos, cbase, ne, R, E, eidx);
    } else {
        int* degs   = cnt_s;
        int* degd   = cnt_s + n_pad;
        int* cursor = cnt_s + 2 * n_pad;
        hipMemsetAsync(degs, 0, (size_t)2 * n_pad * 4, stream);
        k_degrees_leg<<<(ne + 255) / 256, 256, 0, stream>>>(src, dst, ne, degs, degd);
        k_norms_leg<<<(n + 255) / 256, 256, 0, stream>>>(degs, degd, onrm, inrm, degd_sum, n);
        k_scan<<<1, 1024, 0, stream>>>(degd_sum, n, row_ptr);
        k_copy_int<<<(n + 255) / 256, 256, 0, stream>>>(row_ptr, cursor, n);
        k_build_csr_leg<<<(ne + 255) / 256, 256, 0, stream>>>(src, dst, ne, cursor, eidx);
    }

    if (use_mfma) {
        k_split_w_all<<<(73728 + 255) / 256, 256, 0, stream>>>(
            W0, W1, W2, W3, Wh0, Wl0, Wh1, Wl1, Wh2, Wl2, Wh3, Wl3);

        const int mmGrid = n_pad / 128;
        // L0: 256 -> 128, A = x fp32 (split fused, onrm folded)
        k_mm<256, 128, true><<<mmGrid, 256, 0, stream>>>(nullptr, nullptr, x, onrm, Wh0, Wl0, hbuf, n);
        k_agg128_split<<<aggGrid, 256, 0, stream>>>(hbuf, row_ptr, eidx, inrm, onrm, b0, Ah, Al, n);
        // L1
        k_mm<128, 128, false><<<mmGrid, 256, 0, stream>>>(Ah, Al, nullptr, nullptr, Wh1, Wl1, hbuf, n);
        k_agg128_split<<<aggGrid, 256, 0, stream>>>(hbuf, row_ptr, eidx, inrm, onrm, b1, Ah, Al, n);
        // L2
        k_mm<128, 128, false><<<mmGrid, 256, 0, stream>>>(Ah, Al, nullptr, nullptr, Wh2, Wl2, hbuf, n);
        k_agg128_split<<<aggGrid, 256, 0, stream>>>(hbuf, row_ptr, eidx, inrm, onrm, b2, Ah, Al, n);
        // L3: 128 -> 64
        k_mm<128, 64, false><<<mmGrid, 256, 0, stream>>>(Ah, Al, nullptr, nullptr, Wh3, Wl3, hbuf, n);
        k_agg64<<<aggGrid, 256, 0, stream>>>(hbuf, row_ptr, eidx, inrm, b3, (float*)d_out, n);
    } else {
        // fp32 fallback
        off = off_save;
        float* hbufF  = (float*)take((size_t)n * 128 * 4);
        float* xnextF = (float*)take((size_t)n * 128 * 4);
        const int aggGridF = (n + 3) / 4;

        k_matmul<256, 128, 32, 8, 4><<<(n + 31) / 32, dim3(32, 8), 0, stream>>>(x, W0, onrm, hbufF, n);
        k_agg128f<<<aggGridF, 256, 0, stream>>>(hbufF, row_ptr, eidx, inrm, b0, xnextF, n, 1);
        k_matmul<128, 128, 32, 8, 4><<<(n + 31) / 32, dim3(32, 8), 0, stream>>>(xnextF, W1, onrm, hbufF, n);
        k_agg128f<<<aggGridF, 256, 0, stream>>>(hbufF, row_ptr, eidx, inrm, b1, xnextF, n, 1);
        k_matmul<128, 128, 32, 8, 4><<<(n + 31) / 32, dim3(32, 8), 0, stream>>>(xnextF, W2, onrm, hbufF, n);
        k_agg128f<<<aggGridF, 256, 0, stream>>>(hbufF, row_ptr, eidx, inrm, b2, xnextF, n, 1);
        k_matmul<128, 64, 16, 16, 4><<<(n + 63) / 64, dim3(16, 16), 0, stream>>>(xnextF, W3, onrm, hbufF, n);
        k_agg64f<<<aggGridF, 256, 0, stream>>>(hbufF, row_ptr, eidx, inrm, b3, (float*)d_out, n);
    }
}